// Round 1
// baseline (2429.800 us; speedup 1.0000x reference)
//
#include <hip/hip_runtime.h>
#include <math.h>

#define B_ 4
#define S_ 1024
#define D_ 1024
#define NH_ 16
#define HD_ 64
#define I_ 4096
#define M_ (B_*S_)   // 4096 token rows

// ---------------------------------------------------------------------------
// Generic fp32 GEMM: C[M,N] = act(A[M,K] @ W[K,N] + bias[N] (+ res[M,N]))
// M fixed = 4096. Tile 128x128, BK=16, 256 threads, 8x8 accum per thread.
// act: 0 = none, 1 = exact GELU
// ---------------------------------------------------------------------------
#define BM 128
#define BN 128
#define BK 16

__global__ __launch_bounds__(256) void gemm_kernel(
    const float* __restrict__ A, const float* __restrict__ W,
    const float* __restrict__ bias, const float* __restrict__ res,
    float* __restrict__ C, int K, int N, int act)
{
    __shared__ float As[BK][BM];   // transposed A tile: As[k][m]
    __shared__ float Bs[BK][BN];

    const int tid = threadIdx.x;
    const int tx = tid & 15, ty = tid >> 4;
    const int bm = blockIdx.y * BM, bn = blockIdx.x * BN;

    float acc[8][8];
#pragma unroll
    for (int i = 0; i < 8; ++i)
#pragma unroll
        for (int j = 0; j < 8; ++j) acc[i][j] = 0.f;

    for (int kt = 0; kt < K; kt += BK) {
        // stage A tile: 128 rows x 16 cols, float4 per thread x2
#pragma unroll
        for (int it = 0; it < 2; ++it) {
            int idx = tid + it * 256;          // 0..511
            int row = idx >> 2;
            int c4  = (idx & 3) * 4;
            const float4 v = *(const float4*)(A + (size_t)(bm + row) * K + kt + c4);
            As[c4 + 0][row] = v.x;
            As[c4 + 1][row] = v.y;
            As[c4 + 2][row] = v.z;
            As[c4 + 3][row] = v.w;
        }
        // stage B tile: 16 rows x 128 cols
#pragma unroll
        for (int it = 0; it < 2; ++it) {
            int idx = tid + it * 256;
            int row = idx >> 5;
            int c4  = (idx & 31) * 4;
            *(float4*)(&Bs[row][c4]) =
                *(const float4*)(W + (size_t)(kt + row) * N + bn + c4);
        }
        __syncthreads();

#pragma unroll
        for (int k = 0; k < BK; ++k) {
            float a[8], b[8];
            *(float4*)(a)     = *(const float4*)(&As[k][ty * 8]);
            *(float4*)(a + 4) = *(const float4*)(&As[k][ty * 8 + 4]);
            *(float4*)(b)     = *(const float4*)(&Bs[k][tx * 8]);
            *(float4*)(b + 4) = *(const float4*)(&Bs[k][tx * 8 + 4]);
#pragma unroll
            for (int i = 0; i < 8; ++i)
#pragma unroll
                for (int j = 0; j < 8; ++j) acc[i][j] += a[i] * b[j];
        }
        __syncthreads();
    }

    // epilogue
#pragma unroll
    for (int i = 0; i < 8; ++i) {
        const int r = bm + ty * 8 + i;
#pragma unroll
        for (int jj = 0; jj < 2; ++jj) {
            const int c = bn + tx * 8 + jj * 4;
            float v0 = acc[i][jj * 4 + 0] + bias[c + 0];
            float v1 = acc[i][jj * 4 + 1] + bias[c + 1];
            float v2 = acc[i][jj * 4 + 2] + bias[c + 2];
            float v3 = acc[i][jj * 4 + 3] + bias[c + 3];
            if (res) {
                const float4 rv = *(const float4*)(res + (size_t)r * N + c);
                v0 += rv.x; v1 += rv.y; v2 += rv.z; v3 += rv.w;
            }
            if (act == 1) {
                v0 = 0.5f * v0 * (1.0f + erff(v0 * 0.70710678118654752f));
                v1 = 0.5f * v1 * (1.0f + erff(v1 * 0.70710678118654752f));
                v2 = 0.5f * v2 * (1.0f + erff(v2 * 0.70710678118654752f));
                v3 = 0.5f * v3 * (1.0f + erff(v3 * 0.70710678118654752f));
            }
            float4 o; o.x = v0; o.y = v1; o.z = v2; o.w = v3;
            *(float4*)(C + (size_t)r * N + c) = o;
        }
    }
}

// ---------------------------------------------------------------------------
// LayerNorm over last dim (1024). One block (256 thr) per row, float4/thread.
// ---------------------------------------------------------------------------
__global__ __launch_bounds__(256) void ln_kernel(
    const float* __restrict__ X, const float* __restrict__ g,
    const float* __restrict__ b, float* __restrict__ O)
{
    const int row = blockIdx.x;
    const int tid = threadIdx.x;
    const float4 x = *(const float4*)(X + (size_t)row * D_ + tid * 4);

    float s  = x.x + x.y + x.z + x.w;
    float sq = x.x * x.x + x.y * x.y + x.z * x.z + x.w * x.w;
#pragma unroll
    for (int off = 32; off; off >>= 1) {
        s  += __shfl_down(s, off);
        sq += __shfl_down(sq, off);
    }
    __shared__ float red[8];
    const int wid = tid >> 6, lane = tid & 63;
    if (lane == 0) { red[wid] = s; red[4 + wid] = sq; }
    __syncthreads();
    const float ts = red[0] + red[1] + red[2] + red[3];
    const float tq = red[4] + red[5] + red[6] + red[7];
    const float mu  = ts * (1.0f / D_);
    const float var = tq * (1.0f / D_) - mu * mu;
    const float rs  = rsqrtf(var + 1e-12f);

    const float4 gv = *(const float4*)(g + tid * 4);
    const float4 bv = *(const float4*)(b + tid * 4);
    float4 o;
    o.x = (x.x - mu) * rs * gv.x + bv.x;
    o.y = (x.y - mu) * rs * gv.y + bv.y;
    o.z = (x.z - mu) * rs * gv.z + bv.z;
    o.w = (x.w - mu) * rs * gv.w + bv.w;
    *(float4*)(O + (size_t)row * D_ + tid * 4) = o;
}

// ---------------------------------------------------------------------------
// Flash-style attention, fp32. One thread per q-row. Grid (S/256, NH, B).
// K/V staged in LDS in tiles of KT=16 keys; wave-uniform broadcast reads.
// ---------------------------------------------------------------------------
#define KT 16

__global__ __launch_bounds__(256) void attn_kernel(
    const float* __restrict__ Q, const float* __restrict__ Km,
    const float* __restrict__ V, const float* __restrict__ mask,
    float* __restrict__ ctx)
{
    __shared__ float Kl[KT][HD_];
    __shared__ float Vl[KT][HD_];

    const int tid = threadIdx.x;
    const int qb = blockIdx.x;   // 0..3
    const int h  = blockIdx.y;   // 0..15
    const int b  = blockIdx.z;   // 0..3
    const int qi = qb * 256 + tid;
    const size_t rowQ = ((size_t)(b * S_ + qi)) * D_ + h * HD_;

    float4 q4[16];
#pragma unroll
    for (int d = 0; d < 16; ++d) q4[d] = *(const float4*)(Q + rowQ + d * 4);

    float4 a4[16];
#pragma unroll
    for (int d = 0; d < 16; ++d) { a4[d].x = 0; a4[d].y = 0; a4[d].z = 0; a4[d].w = 0; }
    float m = -1e30f, l = 0.f;

    for (int kt = 0; kt < S_; kt += KT) {
        {
            const int row = tid >> 4;
            const int c   = (tid & 15) * 4;
            const size_t off = ((size_t)(b * S_ + kt + row)) * D_ + h * HD_ + c;
            *(float4*)(&Kl[row][c]) = *(const float4*)(Km + off);
            *(float4*)(&Vl[row][c]) = *(const float4*)(V + off);
        }
        __syncthreads();

        float sc[KT];
        float tm = -1e30f;
#pragma unroll
        for (int j = 0; j < KT; ++j) {
            float s = 0.f;
#pragma unroll
            for (int d = 0; d < 16; ++d) {
                const float4 kv = *(const float4*)(&Kl[j][d * 4]);
                s += q4[d].x * kv.x + q4[d].y * kv.y + q4[d].z * kv.z + q4[d].w * kv.w;
            }
            s = s * 0.125f + mask[b * S_ + kt + j];
            sc[j] = s;
            tm = fmaxf(tm, s);
        }
        const float mn = fmaxf(m, tm);
        const float scale = __expf(m - mn);
        l *= scale;
#pragma unroll
        for (int d = 0; d < 16; ++d) {
            a4[d].x *= scale; a4[d].y *= scale; a4[d].z *= scale; a4[d].w *= scale;
        }
#pragma unroll
        for (int j = 0; j < KT; ++j) {
            const float p = __expf(sc[j] - mn);
            l += p;
#pragma unroll
            for (int d = 0; d < 16; ++d) {
                const float4 vv = *(const float4*)(&Vl[j][d * 4]);
                a4[d].x += p * vv.x; a4[d].y += p * vv.y;
                a4[d].z += p * vv.z; a4[d].w += p * vv.w;
            }
        }
        m = mn;
        __syncthreads();
    }

    const float inv = 1.f / l;
#pragma unroll
    for (int d = 0; d < 16; ++d) {
        float4 o;
        o.x = a4[d].x * inv; o.y = a4[d].y * inv;
        o.z = a4[d].z * inv; o.w = a4[d].w * inv;
        *(float4*)(ctx + rowQ + d * 4) = o;
    }
}

// ---------------------------------------------------------------------------
extern "C" void kernel_launch(void* const* d_in, const int* in_sizes, int n_in,
                              void* d_out, int out_size, void* d_ws, size_t ws_size,
                              hipStream_t stream)
{
    const float* h    = (const float*)d_in[0];
    const float* mask = (const float*)d_in[1];
    const float* Wq   = (const float*)d_in[2];
    const float* bq   = (const float*)d_in[3];
    const float* Wk   = (const float*)d_in[4];
    const float* bk   = (const float*)d_in[5];
    const float* Wv   = (const float*)d_in[6];
    const float* bv   = (const float*)d_in[7];
    const float* Wo   = (const float*)d_in[8];
    const float* bo   = (const float*)d_in[9];
    const float* ln1g = (const float*)d_in[10];
    const float* ln1b = (const float*)d_in[11];
    const float* Wi   = (const float*)d_in[12];
    const float* bi   = (const float*)d_in[13];
    const float* Wout = (const float*)d_in[14];
    const float* bout = (const float*)d_in[15];
    const float* ln2g = (const float*)d_in[16];
    const float* ln2b = (const float*)d_in[17];
    float* out = (float*)d_out;

    float* ws = (float*)d_ws;
    const size_t MD = (size_t)M_ * D_;         // 4,194,304
    float* Qw   = ws;
    float* Kw   = ws + MD;
    float* Vw   = ws + 2 * MD;
    float* ctx  = ws + 3 * MD;
    float* attn = ws + 4 * MD;
    float* inter= ws + 5 * MD;                 // M_ x I_ = 16,777,216 floats
    float* tmp1 = Qw;                          // reuse Q after attention
    float* tmp2 = Kw;                          // reuse K after attention

    const dim3 blk(256);
    const dim3 gD(D_ / BN, M_ / BM);           // (8, 32)
    const dim3 gI(I_ / BN, M_ / BM);           // (32, 32)

    // QKV projections
    gemm_kernel<<<gD, blk, 0, stream>>>(h, Wq, bq, nullptr, Qw, D_, D_, 0);
    gemm_kernel<<<gD, blk, 0, stream>>>(h, Wk, bk, nullptr, Kw, D_, D_, 0);
    gemm_kernel<<<gD, blk, 0, stream>>>(h, Wv, bv, nullptr, Vw, D_, D_, 0);

    // attention
    attn_kernel<<<dim3(S_ / 256, NH_, B_), blk, 0, stream>>>(Qw, Kw, Vw, mask, ctx);

    // self-output dense + residual, then LN1
    gemm_kernel<<<gD, blk, 0, stream>>>(ctx, Wo, bo, h, tmp1, D_, D_, 0);
    ln_kernel<<<dim3(M_), blk, 0, stream>>>(tmp1, ln1g, ln1b, attn);

    // FFN
    gemm_kernel<<<gI, blk, 0, stream>>>(attn, Wi, bi, nullptr, inter, D_, I_, 1);
    gemm_kernel<<<gD, blk, 0, stream>>>(inter, Wout, bout, attn, tmp2, I_, D_, 0);
    ln_kernel<<<dim3(M_), blk, 0, stream>>>(tmp2, ln2g, ln2b, out);
}

// Round 2
// 370.851 us; speedup vs baseline: 6.5520x; 6.5520x over previous
//
#include <hip/hip_runtime.h>
#include <hip/hip_bf16.h>
#include <math.h>

#define B_ 4
#define S_ 1024
#define D_ 1024
#define NH_ 16
#define HD_ 64
#define I_ 4096
#define M_ (B_*S_)

typedef __bf16 bf16_8 __attribute__((ext_vector_type(8)));
typedef float f32x4 __attribute__((ext_vector_type(4)));
typedef unsigned short u16;

__device__ __forceinline__ u16 f2b(float x) {
    __hip_bfloat16 h = __float2bfloat16(x);
    return *reinterpret_cast<u16*>(&h);
}

__device__ __forceinline__ void gload16(const void* g, void* l) {
    __builtin_amdgcn_global_load_lds(
        (const __attribute__((address_space(1))) void*)g,
        (__attribute__((address_space(3))) void*)l, 16, 0, 0);
}

// ---------------------------------------------------------------------------
// fp32 -> bf16 elementwise convert (h -> hb)
// ---------------------------------------------------------------------------
__global__ __launch_bounds__(256) void cvt_bf16(
    const float4* __restrict__ in, ushort4* __restrict__ out, int n4)
{
    int i = blockIdx.x * 256 + threadIdx.x;
    if (i < n4) {
        float4 v = in[i];
        ushort4 o;
        o.x = f2b(v.x); o.y = f2b(v.y); o.z = f2b(v.z); o.w = f2b(v.w);
        out[i] = o;
    }
}

// ---------------------------------------------------------------------------
// W[K][N] fp32 -> Wt[N][K] bf16 (32x32 LDS tile transpose)
// ---------------------------------------------------------------------------
__global__ __launch_bounds__(256) void transpose_cvt(
    const float* __restrict__ in, u16* __restrict__ out, int K, int N)
{
    __shared__ float t[32][33];
    const int tid = threadIdx.x;
    const int k0 = blockIdx.y * 32, n0 = blockIdx.x * 32;
#pragma unroll
    for (int i = 0; i < 4; ++i) {
        int idx = i * 256 + tid;
        int r = idx >> 5, c = idx & 31;
        t[r][c] = in[(size_t)(k0 + r) * N + n0 + c];
    }
    __syncthreads();
    const int rr = tid >> 3, cc0 = (tid & 7) * 4;
    ushort4 o;
    o.x = f2b(t[cc0 + 0][rr]);
    o.y = f2b(t[cc0 + 1][rr]);
    o.z = f2b(t[cc0 + 2][rr]);
    o.w = f2b(t[cc0 + 3][rr]);
    *(ushort4*)(out + (size_t)(n0 + rr) * K + k0 + cc0) = o;
}

// ---------------------------------------------------------------------------
// bf16 MFMA GEMM (m97 structure): C[M,N] = act(A[M,K] @ Bt[N,K]^T + bias
//                                             (+ res)), M=4096 rows.
// 128x128 tile, BK=32, 256 threads (4 waves, 2x2), 4x4 16x16x32 frags/wave.
// ---------------------------------------------------------------------------
template<int ACT, int RES, int OUTF, int OUTB>
__global__ __launch_bounds__(256) void gemm_bf16(
    const u16* __restrict__ A, const u16* __restrict__ Bt,
    const float* __restrict__ bias, const float* __restrict__ res,
    float* __restrict__ outF, u16* __restrict__ outB, int N, int K)
{
    __shared__ __align__(16) u16 As[128 * 32];
    __shared__ __align__(16) u16 Bs[128 * 32];

    const int tid  = threadIdx.x;
    const int lane = tid & 63, wid = tid >> 6;
    const int l15  = lane & 15, lg = lane >> 4;
    const int wm   = (wid >> 1) * 64, wn = (wid & 1) * 64;
    const int bm   = blockIdx.y * 128, bn = blockIdx.x * 128;
    const int wbase16 = (tid & ~63) * 16;      // wave-uniform LDS byte base

    const int r0 = tid >> 2;                   // staging rows / cols
    const int c0 = (tid & 3) * 8;

    f32x4 acc[4][4];
#pragma unroll
    for (int i = 0; i < 4; ++i)
#pragma unroll
        for (int j = 0; j < 4; ++j) {
            acc[i][j][0] = 0.f; acc[i][j][1] = 0.f;
            acc[i][j][2] = 0.f; acc[i][j][3] = 0.f;
        }

    for (int kt = 0; kt < K; kt += 32) {
        __syncthreads();
        gload16(A  + (size_t)(bm + r0)      * K + kt + c0, (char*)As + wbase16);
        gload16(A  + (size_t)(bm + r0 + 64) * K + kt + c0, (char*)As + wbase16 + 4096);
        gload16(Bt + (size_t)(bn + r0)      * K + kt + c0, (char*)Bs + wbase16);
        gload16(Bt + (size_t)(bn + r0 + 64) * K + kt + c0, (char*)Bs + wbase16 + 4096);
        __syncthreads();

        bf16_8 af[4], bfr[4];
#pragma unroll
        for (int f = 0; f < 4; ++f) {
            af[f]  = *(const bf16_8*)((const char*)As + (wm + f * 16 + l15) * 64 + lg * 16);
            bfr[f] = *(const bf16_8*)((const char*)Bs + (wn + f * 16 + l15) * 64 + lg * 16);
        }
#pragma unroll
        for (int i = 0; i < 4; ++i)
#pragma unroll
            for (int j = 0; j < 4; ++j)
                acc[i][j] = __builtin_amdgcn_mfma_f32_16x16x32_bf16(
                    af[i], bfr[j], acc[i][j], 0, 0, 0);
    }

    // epilogue: C layout col=lane&15, row=(lane>>4)*4+r
    float bs[4];
#pragma unroll
    for (int j = 0; j < 4; ++j) bs[j] = bias[bn + wn + j * 16 + l15];

#pragma unroll
    for (int i = 0; i < 4; ++i) {
#pragma unroll
        for (int r = 0; r < 4; ++r) {
            const int row = bm + wm + i * 16 + lg * 4 + r;
#pragma unroll
            for (int j = 0; j < 4; ++j) {
                const int col = bn + wn + j * 16 + l15;
                float v = acc[i][j][r] + bs[j];
                if (RES) v += res[(size_t)row * N + col];
                if (ACT) v = 0.5f * v * (1.0f + erff(v * 0.70710678118654752f));
                if (OUTF) outF[(size_t)row * N + col] = v;
                if (OUTB) outB[(size_t)row * N + col] = f2b(v);
            }
        }
    }
}

// ---------------------------------------------------------------------------
// LayerNorm over D=1024, fp32 in, fp32 out (+optional bf16 out)
// ---------------------------------------------------------------------------
__global__ __launch_bounds__(256) void ln_kernel(
    const float* __restrict__ X, const float* __restrict__ g,
    const float* __restrict__ b, float* __restrict__ O, u16* __restrict__ OB)
{
    const int row = blockIdx.x;
    const int tid = threadIdx.x;
    const float4 x = *(const float4*)(X + (size_t)row * D_ + tid * 4);

    float s  = x.x + x.y + x.z + x.w;
    float sq = x.x * x.x + x.y * x.y + x.z * x.z + x.w * x.w;
#pragma unroll
    for (int off = 32; off; off >>= 1) {
        s  += __shfl_down(s, off);
        sq += __shfl_down(sq, off);
    }
    __shared__ float red[8];
    const int wid = tid >> 6, lane = tid & 63;
    if (lane == 0) { red[wid] = s; red[4 + wid] = sq; }
    __syncthreads();
    const float ts = red[0] + red[1] + red[2] + red[3];
    const float tq = red[4] + red[5] + red[6] + red[7];
    const float mu  = ts * (1.0f / D_);
    const float var = tq * (1.0f / D_) - mu * mu;
    const float rs  = rsqrtf(var + 1e-12f);

    const float4 gv = *(const float4*)(g + tid * 4);
    const float4 bv = *(const float4*)(b + tid * 4);
    float4 o;
    o.x = (x.x - mu) * rs * gv.x + bv.x;
    o.y = (x.y - mu) * rs * gv.y + bv.y;
    o.z = (x.z - mu) * rs * gv.z + bv.z;
    o.w = (x.w - mu) * rs * gv.w + bv.w;
    *(float4*)(O + (size_t)row * D_ + tid * 4) = o;
    if (OB) {
        ushort4 ob;
        ob.x = f2b(o.x); ob.y = f2b(o.y); ob.z = f2b(o.z); ob.w = f2b(o.w);
        *(ushort4*)(OB + (size_t)row * D_ + tid * 4) = ob;
    }
}

// ---------------------------------------------------------------------------
// Flash attention, bf16 MFMA. Block = 64 q-rows of one (b,h); 4 waves x 16 q.
// K-tiles of 64 keys. K,V^T staged in XOR-swizzled LDS; P via wave-private
// swizzled LDS. Online softmax in registers (C layout col=l&15,row=lg*4+r).
// ---------------------------------------------------------------------------
__global__ __launch_bounds__(256) void attn_mfma(
    const u16* __restrict__ Qb, const u16* __restrict__ Kb,
    const u16* __restrict__ Vb, const float* __restrict__ mask,
    u16* __restrict__ ctxb)
{
    __shared__ __align__(16) char sm[24576];
    char* Ksm = sm;                 // [64 key][64 d] bf16, swizzled
    char* Vsm = sm + 8192;          // [64 d][64 key] bf16 (V^T), swizzled

    const int tid  = threadIdx.x;
    const int lane = tid & 63, wid = tid >> 6;
    char* Psm = sm + 16384 + wid * 2048;   // per-wave [16 q][64 key], swizzled
    const int l15 = lane & 15, lg = lane >> 4;
    const int h = blockIdx.y, b = blockIdx.z;
    const int q0 = blockIdx.x * 64 + wid * 16;
    const size_t headoff = ((size_t)b * S_) * D_ + (size_t)h * 64;

    // Q fragments (A operand): row=l15, k=lg*8+j (+32 for second)
    const u16* Qrow = Qb + headoff + (size_t)(q0 + l15) * D_;
    const bf16_8 qf0 = *(const bf16_8*)(Qrow + lg * 8);
    const bf16_8 qf1 = *(const bf16_8*)(Qrow + 32 + lg * 8);

    f32x4 ctx[4];
#pragma unroll
    for (int i = 0; i < 4; ++i) { ctx[i][0]=0.f; ctx[i][1]=0.f; ctx[i][2]=0.f; ctx[i][3]=0.f; }
    float m_r[4], l_r[4];
#pragma unroll
    for (int r = 0; r < 4; ++r) { m_r[r] = -1e30f; l_r[r] = 0.f; }

    const int skey = tid >> 2;           // staging: key row 0..63
    const int sd0  = (tid & 3) * 16;     // staging: d start

    for (int kt = 0; kt < S_; kt += 64) {
        __syncthreads();
        {
            const u16* ks = Kb + headoff + (size_t)(kt + skey) * D_ + sd0;
            const bf16_8 k0 = *(const bf16_8*)(ks);
            const bf16_8 k1 = *(const bf16_8*)(ks + 8);
            const int xo = (skey & 7) << 4;
            *(bf16_8*)(Ksm + skey * 128 + ((sd0 * 2)      ^ xo)) = k0;
            *(bf16_8*)(Ksm + skey * 128 + ((sd0 * 2 + 16) ^ xo)) = k1;

            const u16* vs = Vb + headoff + (size_t)(kt + skey) * D_ + sd0;
            const bf16_8 v0 = *(const bf16_8*)(vs);
            const bf16_8 v1 = *(const bf16_8*)(vs + 8);
#pragma unroll
            for (int j = 0; j < 8; ++j) {
                const int d = sd0 + j;
                *(__bf16*)(Vsm + d * 128 + ((skey * 2) ^ ((d & 7) << 4))) = v0[j];
            }
#pragma unroll
            for (int j = 0; j < 8; ++j) {
                const int d = sd0 + 8 + j;
                *(__bf16*)(Vsm + d * 128 + ((skey * 2) ^ ((d & 7) << 4))) = v1[j];
            }
        }
        __syncthreads();

        // QK^T: 4 key-frags x (k=64 = 2 MFMA)
        f32x4 sc[4];
#pragma unroll
        for (int kf = 0; kf < 4; ++kf) {
            const int key = kf * 16 + l15;
            const int xo = (key & 7) << 4;
            f32x4 a; a[0]=0.f; a[1]=0.f; a[2]=0.f; a[3]=0.f;
            const bf16_8 kA = *(const bf16_8*)(Ksm + key * 128 + ((lg * 16)      ^ xo));
            a = __builtin_amdgcn_mfma_f32_16x16x32_bf16(qf0, kA, a, 0, 0, 0);
            const bf16_8 kB = *(const bf16_8*)(Ksm + key * 128 + ((64 + lg * 16) ^ xo));
            a = __builtin_amdgcn_mfma_f32_16x16x32_bf16(qf1, kB, a, 0, 0, 0);
            sc[kf] = a;
        }

        // scale + mask
        float sv[4][4], mv[4];
#pragma unroll
        for (int kf = 0; kf < 4; ++kf)
            mv[kf] = mask[(size_t)b * S_ + kt + kf * 16 + l15];
#pragma unroll
        for (int kf = 0; kf < 4; ++kf)
#pragma unroll
            for (int r = 0; r < 4; ++r)
                sv[kf][r] = sc[kf][r] * 0.125f + mv[kf];

        // online softmax (row stats across the 16 lanes sharing lg)
        float mnew[4], scl[4], psum[4];
#pragma unroll
        for (int r = 0; r < 4; ++r) {
            float t = fmaxf(fmaxf(sv[0][r], sv[1][r]), fmaxf(sv[2][r], sv[3][r]));
            t = fmaxf(t, __shfl_xor(t, 1));
            t = fmaxf(t, __shfl_xor(t, 2));
            t = fmaxf(t, __shfl_xor(t, 4));
            t = fmaxf(t, __shfl_xor(t, 8));
            mnew[r] = fmaxf(m_r[r], t);
            scl[r]  = __expf(m_r[r] - mnew[r]);
            m_r[r]  = mnew[r];
            psum[r] = 0.f;
        }
#pragma unroll
        for (int kf = 0; kf < 4; ++kf)
#pragma unroll
            for (int r = 0; r < 4; ++r) {
                const float p = __expf(sv[kf][r] - mnew[r]);
                psum[r] += p;
                const int q = lg * 4 + r;
                *(u16*)(Psm + q * 128 + (((kf * 16 + l15) * 2) ^ ((q & 7) << 4))) = f2b(p);
            }
#pragma unroll
        for (int r = 0; r < 4; ++r) {
            float ps = psum[r];
            ps += __shfl_xor(ps, 1);
            ps += __shfl_xor(ps, 2);
            ps += __shfl_xor(ps, 4);
            ps += __shfl_xor(ps, 8);
            l_r[r] = l_r[r] * scl[r] + ps;
        }
#pragma unroll
        for (int fd = 0; fd < 4; ++fd)
#pragma unroll
            for (int r = 0; r < 4; ++r) ctx[fd][r] *= scl[r];

        asm volatile("s_waitcnt lgkmcnt(0)" ::: "memory");

        // PV: A=P (row=q=l15, k=key), B=V^T (col=d=l15, k=key)
#pragma unroll
        for (int s = 0; s < 2; ++s) {
            const bf16_8 pf = *(const bf16_8*)(Psm + l15 * 128 +
                                ((s * 64 + lg * 16) ^ ((l15 & 7) << 4)));
#pragma unroll
            for (int fd = 0; fd < 4; ++fd) {
                const int d = fd * 16 + l15;
                const bf16_8 vf = *(const bf16_8*)(Vsm + d * 128 +
                                    ((s * 64 + lg * 16) ^ ((d & 7) << 4)));
                ctx[fd] = __builtin_amdgcn_mfma_f32_16x16x32_bf16(pf, vf, ctx[fd], 0, 0, 0);
            }
        }
    }

    // normalize + write ctx (bf16)
#pragma unroll
    for (int r = 0; r < 4; ++r) {
        const float inv = 1.f / l_r[r];
        const size_t rowoff = headoff + (size_t)(q0 + lg * 4 + r) * D_;
#pragma unroll
        for (int fd = 0; fd < 4; ++fd)
            ctxb[rowoff + fd * 16 + l15] = f2b(ctx[fd][r] * inv);
    }
}

// ---------------------------------------------------------------------------
extern "C" void kernel_launch(void* const* d_in, const int* in_sizes, int n_in,
                              void* d_out, int out_size, void* d_ws, size_t ws_size,
                              hipStream_t stream)
{
    const float* h    = (const float*)d_in[0];
    const float* mask = (const float*)d_in[1];
    const float* Wq   = (const float*)d_in[2];
    const float* bq   = (const float*)d_in[3];
    const float* Wk   = (const float*)d_in[4];
    const float* bk   = (const float*)d_in[5];
    const float* Wv   = (const float*)d_in[6];
    const float* bv   = (const float*)d_in[7];
    const float* Wo   = (const float*)d_in[8];
    const float* bo   = (const float*)d_in[9];
    const float* ln1g = (const float*)d_in[10];
    const float* ln1b = (const float*)d_in[11];
    const float* Wi   = (const float*)d_in[12];
    const float* bi   = (const float*)d_in[13];
    const float* Wout = (const float*)d_in[14];
    const float* bout = (const float*)d_in[15];
    const float* ln2g = (const float*)d_in[16];
    const float* ln2b = (const float*)d_in[17];
    float* out = (float*)d_out;

    char* w = (char*)d_ws;
    const size_t MiB = 1ull << 20;
    u16*  hb     = (u16*)(w + 0);
    u16*  Wqt    = (u16*)(w + 8  * MiB);
    u16*  Wkt    = (u16*)(w + 10 * MiB);
    u16*  Wvt    = (u16*)(w + 12 * MiB);
    u16*  Wot    = (u16*)(w + 14 * MiB);
    u16*  Wit    = (u16*)(w + 16 * MiB);
    u16*  Woutt  = (u16*)(w + 24 * MiB);
    u16*  Qbuf   = (u16*)(w + 32 * MiB);
    u16*  Kbuf   = (u16*)(w + 40 * MiB);
    u16*  Vbuf   = (u16*)(w + 48 * MiB);
    u16*  ctxb   = (u16*)(w + 0);           // reuse hb (dead after QKV)
    float* tmp1  = (float*)(w + 40 * MiB);  // reuse K/V (dead after attn)
    float* attnF = (float*)(w + 56 * MiB);
    u16*  attnB  = (u16*)(w + 72 * MiB);
    u16*  interB = (u16*)(w + 80 * MiB);
    float* tmp2  = (float*)(w + 112 * MiB); // total 128 MiB

    const dim3 blk(256);

    // prep: h -> bf16; weights -> bf16 transposed [N][K]
    cvt_bf16<<<dim3((M_ * D_ / 4) / 256), blk, 0, stream>>>(
        (const float4*)h, (ushort4*)hb, M_ * D_ / 4);
    transpose_cvt<<<dim3(32, 32),  blk, 0, stream>>>(Wq,   Wqt,   D_, D_);
    transpose_cvt<<<dim3(32, 32),  blk, 0, stream>>>(Wk,   Wkt,   D_, D_);
    transpose_cvt<<<dim3(32, 32),  blk, 0, stream>>>(Wv,   Wvt,   D_, D_);
    transpose_cvt<<<dim3(32, 32),  blk, 0, stream>>>(Wo,   Wot,   D_, D_);
    transpose_cvt<<<dim3(128, 32), blk, 0, stream>>>(Wi,   Wit,   D_, I_);
    transpose_cvt<<<dim3(32, 128), blk, 0, stream>>>(Wout, Woutt, I_, D_);

    const dim3 gD(D_ / 128, M_ / 128);   // (8, 32)
    const dim3 gI(I_ / 128, M_ / 128);   // (32, 32)

    // QKV projections -> bf16
    gemm_bf16<0,0,0,1><<<gD, blk, 0, stream>>>(hb, Wqt, bq, nullptr, nullptr, Qbuf, D_, D_);
    gemm_bf16<0,0,0,1><<<gD, blk, 0, stream>>>(hb, Wkt, bk, nullptr, nullptr, Kbuf, D_, D_);
    gemm_bf16<0,0,0,1><<<gD, blk, 0, stream>>>(hb, Wvt, bv, nullptr, nullptr, Vbuf, D_, D_);

    // attention
    attn_mfma<<<dim3(S_ / 64, NH_, B_), blk, 0, stream>>>(Qbuf, Kbuf, Vbuf, mask, ctxb);

    // self-output dense + residual(h) -> LN1 (fp32 + bf16)
    gemm_bf16<0,1,1,0><<<gD, blk, 0, stream>>>(ctxb, Wot, bo, h, tmp1, nullptr, D_, D_);
    ln_kernel<<<dim3(M_), blk, 0, stream>>>(tmp1, ln1g, ln1b, attnF, attnB);

    // FFN
    gemm_bf16<1,0,0,1><<<gI, blk, 0, stream>>>(attnB, Wit, bi, nullptr, nullptr, interB, I_, D_);
    gemm_bf16<0,1,1,0><<<gD, blk, 0, stream>>>(interB, Woutt, bout, attnF, tmp2, nullptr, D_, I_);
    ln_kernel<<<dim3(M_), blk, 0, stream>>>(tmp2, ln2g, ln2b, out, nullptr);
}

// Round 3
// 303.929 us; speedup vs baseline: 7.9946x; 1.2202x over previous
//
#include <hip/hip_runtime.h>
#include <hip/hip_bf16.h>
#include <math.h>

#define B_ 4
#define S_ 1024
#define D_ 1024
#define NH_ 16
#define HD_ 64
#define I_ 4096
#define M_ (B_*S_)

typedef __bf16 bf16_8 __attribute__((ext_vector_type(8)));
typedef float f32x4 __attribute__((ext_vector_type(4)));
typedef unsigned short u16;

struct P4 { float* p[4]; };
struct T4 { const float* s[4]; u16* d[4]; };

__device__ __forceinline__ u16 f2b(float x) {
    __hip_bfloat16 h = __float2bfloat16(x);
    return *reinterpret_cast<u16*>(&h);
}

__device__ __forceinline__ void gload16(const void* g, void* l) {
    __builtin_amdgcn_global_load_lds(
        (const __attribute__((address_space(1))) void*)g,
        (__attribute__((address_space(3))) void*)l, 16, 0, 0);
}

// ---------------------------------------------------------------------------
// fp32 -> bf16 elementwise convert
// ---------------------------------------------------------------------------
__global__ __launch_bounds__(256) void cvt_bf16(
    const float4* __restrict__ in, ushort4* __restrict__ out, int n4)
{
    int i = blockIdx.x * 256 + threadIdx.x;
    if (i < n4) {
        float4 v = in[i];
        ushort4 o;
        o.x = f2b(v.x); o.y = f2b(v.y); o.z = f2b(v.z); o.w = f2b(v.w);
        out[i] = o;
    }
}

// ---------------------------------------------------------------------------
// W[K][N] fp32 -> Wt[N][K] bf16, 32x32 LDS tile transpose.
// ---------------------------------------------------------------------------
__global__ __launch_bounds__(256) void transpose_cvt(
    const float* __restrict__ in, u16* __restrict__ out, int K, int N)
{
    __shared__ float t[32][33];
    const int tid = threadIdx.x;
    const int k0 = blockIdx.y * 32, n0 = blockIdx.x * 32;
#pragma unroll
    for (int i = 0; i < 4; ++i) {
        int idx = i * 256 + tid;
        int r = idx >> 5, c = idx & 31;
        t[r][c] = in[(size_t)(k0 + r) * N + n0 + c];
    }
    __syncthreads();
    const int rr = tid >> 3, cc0 = (tid & 7) * 4;
    ushort4 o;
    o.x = f2b(t[cc0 + 0][rr]);
    o.y = f2b(t[cc0 + 1][rr]);
    o.z = f2b(t[cc0 + 2][rr]);
    o.w = f2b(t[cc0 + 3][rr]);
    *(ushort4*)(out + (size_t)(n0 + rr) * K + k0 + cc0) = o;
}

// fused 4x (1024x1024) transpose: z selects src/dst
__global__ __launch_bounds__(256) void transpose4_cvt(T4 t4)
{
    __shared__ float t[32][33];
    const int tid = threadIdx.x;
    const int k0 = blockIdx.y * 32, n0 = blockIdx.x * 32;
    const float* in = t4.s[blockIdx.z];
    u16* out = t4.d[blockIdx.z];
#pragma unroll
    for (int i = 0; i < 4; ++i) {
        int idx = i * 256 + tid;
        int r = idx >> 5, c = idx & 31;
        t[r][c] = in[(size_t)(k0 + r) * D_ + n0 + c];
    }
    __syncthreads();
    const int rr = tid >> 3, cc0 = (tid & 7) * 4;
    ushort4 o;
    o.x = f2b(t[cc0 + 0][rr]);
    o.y = f2b(t[cc0 + 1][rr]);
    o.z = f2b(t[cc0 + 2][rr]);
    o.w = f2b(t[cc0 + 3][rr]);
    *(ushort4*)(out + (size_t)(n0 + rr) * D_ + k0 + cc0) = o;
}

// ---------------------------------------------------------------------------
// bf16 MFMA GEMM, m97 structure. C = act(A[M,K] @ Bt[N,K]^T + bias).
// QKV3: bias selected from b0/b1/b2 per 1024-col group (fused QKV).
// ---------------------------------------------------------------------------
template<int ACT, int QKV3>
__global__ __launch_bounds__(256) void gemm_bf16(
    const u16* __restrict__ A, const u16* __restrict__ Bt,
    const float* __restrict__ b0, const float* __restrict__ b1,
    const float* __restrict__ b2,
    u16* __restrict__ outB, int N, int K)
{
    __shared__ __align__(16) u16 As[128 * 32];
    __shared__ __align__(16) u16 Bs[128 * 32];

    const int tid  = threadIdx.x;
    const int lane = tid & 63, wid = tid >> 6;
    const int l15  = lane & 15, lg = lane >> 4;
    const int wm   = (wid >> 1) * 64, wn = (wid & 1) * 64;
    const int bm   = blockIdx.y * 128, bn = blockIdx.x * 128;
    const int wbase16 = (tid & ~63) * 16;

    const int r0 = tid >> 2;
    const int c0 = (tid & 3) * 8;

    f32x4 acc[4][4];
#pragma unroll
    for (int i = 0; i < 4; ++i)
#pragma unroll
        for (int j = 0; j < 4; ++j) {
            acc[i][j][0] = 0.f; acc[i][j][1] = 0.f;
            acc[i][j][2] = 0.f; acc[i][j][3] = 0.f;
        }

    for (int kt = 0; kt < K; kt += 32) {
        __syncthreads();
        gload16(A  + (size_t)(bm + r0)      * K + kt + c0, (char*)As + wbase16);
        gload16(A  + (size_t)(bm + r0 + 64) * K + kt + c0, (char*)As + wbase16 + 4096);
        gload16(Bt + (size_t)(bn + r0)      * K + kt + c0, (char*)Bs + wbase16);
        gload16(Bt + (size_t)(bn + r0 + 64) * K + kt + c0, (char*)Bs + wbase16 + 4096);
        __syncthreads();

        bf16_8 af[4], bfr[4];
#pragma unroll
        for (int f = 0; f < 4; ++f) {
            af[f]  = *(const bf16_8*)((const char*)As + (wm + f * 16 + l15) * 64 + lg * 16);
            bfr[f] = *(const bf16_8*)((const char*)Bs + (wn + f * 16 + l15) * 64 + lg * 16);
        }
#pragma unroll
        for (int i = 0; i < 4; ++i)
#pragma unroll
            for (int j = 0; j < 4; ++j)
                acc[i][j] = __builtin_amdgcn_mfma_f32_16x16x32_bf16(
                    af[i], bfr[j], acc[i][j], 0, 0, 0);
    }

    const float* bp = b0;
    int bcol = bn;
    if (QKV3) {
        bp = (bn < 1024) ? b0 : (bn < 2048) ? b1 : b2;
        bcol = bn & 1023;
    }
    float bs[4];
#pragma unroll
    for (int j = 0; j < 4; ++j) bs[j] = bp[bcol + wn + j * 16 + l15];

#pragma unroll
    for (int i = 0; i < 4; ++i) {
#pragma unroll
        for (int r = 0; r < 4; ++r) {
            const int row = bm + wm + i * 16 + lg * 4 + r;
#pragma unroll
            for (int j = 0; j < 4; ++j) {
                const int col = bn + wn + j * 16 + l15;
                float v = acc[i][j][r] + bs[j];
                if (ACT) v = 0.5f * v * (1.0f + erff(v * 0.70710678118654752f));
                outB[(size_t)row * N + col] = f2b(v);
            }
        }
    }
}

// ---------------------------------------------------------------------------
// Split-K bf16 GEMM: blockIdx.z = K-chunk; writes fp32 partials, no epilogue.
// ---------------------------------------------------------------------------
__global__ __launch_bounds__(256) void gemm_splitk(
    const u16* __restrict__ A, const u16* __restrict__ Bt,
    P4 parts, int N, int K, int kchunk)
{
    __shared__ __align__(16) u16 As[128 * 32];
    __shared__ __align__(16) u16 Bs[128 * 32];

    const int tid  = threadIdx.x;
    const int lane = tid & 63, wid = tid >> 6;
    const int l15  = lane & 15, lg = lane >> 4;
    const int wm   = (wid >> 1) * 64, wn = (wid & 1) * 64;
    const int bm   = blockIdx.y * 128, bn = blockIdx.x * 128;
    const int wbase16 = (tid & ~63) * 16;
    const int kt0 = blockIdx.z * kchunk, kt1 = kt0 + kchunk;
    float* outP = parts.p[blockIdx.z];

    const int r0 = tid >> 2;
    const int c0 = (tid & 3) * 8;

    f32x4 acc[4][4];
#pragma unroll
    for (int i = 0; i < 4; ++i)
#pragma unroll
        for (int j = 0; j < 4; ++j) {
            acc[i][j][0] = 0.f; acc[i][j][1] = 0.f;
            acc[i][j][2] = 0.f; acc[i][j][3] = 0.f;
        }

    for (int kt = kt0; kt < kt1; kt += 32) {
        __syncthreads();
        gload16(A  + (size_t)(bm + r0)      * K + kt + c0, (char*)As + wbase16);
        gload16(A  + (size_t)(bm + r0 + 64) * K + kt + c0, (char*)As + wbase16 + 4096);
        gload16(Bt + (size_t)(bn + r0)      * K + kt + c0, (char*)Bs + wbase16);
        gload16(Bt + (size_t)(bn + r0 + 64) * K + kt + c0, (char*)Bs + wbase16 + 4096);
        __syncthreads();

        bf16_8 af[4], bfr[4];
#pragma unroll
        for (int f = 0; f < 4; ++f) {
            af[f]  = *(const bf16_8*)((const char*)As + (wm + f * 16 + l15) * 64 + lg * 16);
            bfr[f] = *(const bf16_8*)((const char*)Bs + (wn + f * 16 + l15) * 64 + lg * 16);
        }
#pragma unroll
        for (int i = 0; i < 4; ++i)
#pragma unroll
            for (int j = 0; j < 4; ++j)
                acc[i][j] = __builtin_amdgcn_mfma_f32_16x16x32_bf16(
                    af[i], bfr[j], acc[i][j], 0, 0, 0);
    }

#pragma unroll
    for (int i = 0; i < 4; ++i)
#pragma unroll
        for (int r = 0; r < 4; ++r) {
            const int row = bm + wm + i * 16 + lg * 4 + r;
#pragma unroll
            for (int j = 0; j < 4; ++j)
                outP[(size_t)row * N + bn + wn + j * 16 + l15] = acc[i][j][r];
        }
}

// ---------------------------------------------------------------------------
// Reduce NPART partials + bias + residual, then LayerNorm over D=1024.
// One block per row. Partial p[0] may alias outF (read-before-write per row).
// ---------------------------------------------------------------------------
template<int NPART>
__global__ __launch_bounds__(256) void ln_reduce(
    P4 parts, const float* __restrict__ bias, const float* __restrict__ res,
    const float* __restrict__ g, const float* __restrict__ b,
    float* __restrict__ O, u16* __restrict__ OB)
{
    const int row = blockIdx.x;
    const int tid = threadIdx.x;
    const size_t off = (size_t)row * D_ + tid * 4;

    float4 v = *(const float4*)(res + off);
    const float4 bi = *(const float4*)(bias + tid * 4);
    v.x += bi.x; v.y += bi.y; v.z += bi.z; v.w += bi.w;
#pragma unroll
    for (int p = 0; p < NPART; ++p) {
        const float4 t = *(const float4*)(parts.p[p] + off);
        v.x += t.x; v.y += t.y; v.z += t.z; v.w += t.w;
    }

    float s  = v.x + v.y + v.z + v.w;
    float sq = v.x * v.x + v.y * v.y + v.z * v.z + v.w * v.w;
#pragma unroll
    for (int o = 32; o; o >>= 1) {
        s  += __shfl_down(s, o);
        sq += __shfl_down(sq, o);
    }
    __shared__ float red[8];
    const int wid = tid >> 6, lane = tid & 63;
    if (lane == 0) { red[wid] = s; red[4 + wid] = sq; }
    __syncthreads();
    const float ts = red[0] + red[1] + red[2] + red[3];
    const float tq = red[4] + red[5] + red[6] + red[7];
    const float mu  = ts * (1.0f / D_);
    const float var = tq * (1.0f / D_) - mu * mu;
    const float rs  = rsqrtf(var + 1e-12f);

    const float4 gv = *(const float4*)(g + tid * 4);
    const float4 bv = *(const float4*)(b + tid * 4);
    float4 o;
    o.x = (v.x - mu) * rs * gv.x + bv.x;
    o.y = (v.y - mu) * rs * gv.y + bv.y;
    o.z = (v.z - mu) * rs * gv.z + bv.z;
    o.w = (v.w - mu) * rs * gv.w + bv.w;
    *(float4*)(O + off) = o;
    if (OB) {
        ushort4 ob;
        ob.x = f2b(o.x); ob.y = f2b(o.y); ob.z = f2b(o.z); ob.w = f2b(o.w);
        *(ushort4*)(OB + off) = ob;
    }
}

// ---------------------------------------------------------------------------
// Flash attention, bf16 MFMA (as R2, + row-stride arg for fused-QKV input).
// ---------------------------------------------------------------------------
__global__ __launch_bounds__(256) void attn_mfma(
    const u16* __restrict__ Qb, const u16* __restrict__ Kb,
    const u16* __restrict__ Vb, const float* __restrict__ mask,
    u16* __restrict__ ctxb, int qs)
{
    __shared__ __align__(16) char sm[24576];
    char* Ksm = sm;
    char* Vsm = sm + 8192;

    const int tid  = threadIdx.x;
    const int lane = tid & 63, wid = tid >> 6;
    char* Psm = sm + 16384 + wid * 2048;
    const int l15 = lane & 15, lg = lane >> 4;
    const int h = blockIdx.y, b = blockIdx.z;
    const int q0 = blockIdx.x * 64 + wid * 16;
    const size_t inhead  = ((size_t)b * S_) * qs + (size_t)h * 64;
    const size_t outhead = ((size_t)b * S_) * D_ + (size_t)h * 64;

    const u16* Qrow = Qb + inhead + (size_t)(q0 + l15) * qs;
    const bf16_8 qf0 = *(const bf16_8*)(Qrow + lg * 8);
    const bf16_8 qf1 = *(const bf16_8*)(Qrow + 32 + lg * 8);

    f32x4 ctx[4];
#pragma unroll
    for (int i = 0; i < 4; ++i) { ctx[i][0]=0.f; ctx[i][1]=0.f; ctx[i][2]=0.f; ctx[i][3]=0.f; }
    float m_r[4], l_r[4];
#pragma unroll
    for (int r = 0; r < 4; ++r) { m_r[r] = -1e30f; l_r[r] = 0.f; }

    const int skey = tid >> 2;
    const int sd0  = (tid & 3) * 16;

    for (int kt = 0; kt < S_; kt += 64) {
        __syncthreads();
        {
            const u16* ks = Kb + inhead + (size_t)(kt + skey) * qs + sd0;
            const bf16_8 k0 = *(const bf16_8*)(ks);
            const bf16_8 k1 = *(const bf16_8*)(ks + 8);
            const int xo = (skey & 7) << 4;
            *(bf16_8*)(Ksm + skey * 128 + ((sd0 * 2)      ^ xo)) = k0;
            *(bf16_8*)(Ksm + skey * 128 + ((sd0 * 2 + 16) ^ xo)) = k1;

            const u16* vs = Vb + inhead + (size_t)(kt + skey) * qs + sd0;
            const bf16_8 v0 = *(const bf16_8*)(vs);
            const bf16_8 v1 = *(const bf16_8*)(vs + 8);
#pragma unroll
            for (int j = 0; j < 8; ++j) {
                const int d = sd0 + j;
                *(__bf16*)(Vsm + d * 128 + ((skey * 2) ^ ((d & 7) << 4))) = v0[j];
            }
#pragma unroll
            for (int j = 0; j < 8; ++j) {
                const int d = sd0 + 8 + j;
                *(__bf16*)(Vsm + d * 128 + ((skey * 2) ^ ((d & 7) << 4))) = v1[j];
            }
        }
        __syncthreads();

        f32x4 sc[4];
#pragma unroll
        for (int kf = 0; kf < 4; ++kf) {
            const int key = kf * 16 + l15;
            const int xo = (key & 7) << 4;
            f32x4 a; a[0]=0.f; a[1]=0.f; a[2]=0.f; a[3]=0.f;
            const bf16_8 kA = *(const bf16_8*)(Ksm + key * 128 + ((lg * 16)      ^ xo));
            a = __builtin_amdgcn_mfma_f32_16x16x32_bf16(qf0, kA, a, 0, 0, 0);
            const bf16_8 kB = *(const bf16_8*)(Ksm + key * 128 + ((64 + lg * 16) ^ xo));
            a = __builtin_amdgcn_mfma_f32_16x16x32_bf16(qf1, kB, a, 0, 0, 0);
            sc[kf] = a;
        }

        float sv[4][4], mv[4];
#pragma unroll
        for (int kf = 0; kf < 4; ++kf)
            mv[kf] = mask[(size_t)b * S_ + kt + kf * 16 + l15];
#pragma unroll
        for (int kf = 0; kf < 4; ++kf)
#pragma unroll
            for (int r = 0; r < 4; ++r)
                sv[kf][r] = sc[kf][r] * 0.125f + mv[kf];

        float mnew[4], scl[4], psum[4];
#pragma unroll
        for (int r = 0; r < 4; ++r) {
            float t = fmaxf(fmaxf(sv[0][r], sv[1][r]), fmaxf(sv[2][r], sv[3][r]));
            t = fmaxf(t, __shfl_xor(t, 1));
            t = fmaxf(t, __shfl_xor(t, 2));
            t = fmaxf(t, __shfl_xor(t, 4));
            t = fmaxf(t, __shfl_xor(t, 8));
            mnew[r] = fmaxf(m_r[r], t);
            scl[r]  = __expf(m_r[r] - mnew[r]);
            m_r[r]  = mnew[r];
            psum[r] = 0.f;
        }
#pragma unroll
        for (int kf = 0; kf < 4; ++kf)
#pragma unroll
            for (int r = 0; r < 4; ++r) {
                const float p = __expf(sv[kf][r] - mnew[r]);
                psum[r] += p;
                const int q = lg * 4 + r;
                *(u16*)(Psm + q * 128 + (((kf * 16 + l15) * 2) ^ ((q & 7) << 4))) = f2b(p);
            }
#pragma unroll
        for (int r = 0; r < 4; ++r) {
            float ps = psum[r];
            ps += __shfl_xor(ps, 1);
            ps += __shfl_xor(ps, 2);
            ps += __shfl_xor(ps, 4);
            ps += __shfl_xor(ps, 8);
            l_r[r] = l_r[r] * scl[r] + ps;
        }
#pragma unroll
        for (int fd = 0; fd < 4; ++fd)
#pragma unroll
            for (int r = 0; r < 4; ++r) ctx[fd][r] *= scl[r];

        asm volatile("s_waitcnt lgkmcnt(0)" ::: "memory");

#pragma unroll
        for (int s = 0; s < 2; ++s) {
            const bf16_8 pf = *(const bf16_8*)(Psm + l15 * 128 +
                                ((s * 64 + lg * 16) ^ ((l15 & 7) << 4)));
#pragma unroll
            for (int fd = 0; fd < 4; ++fd) {
                const int d = fd * 16 + l15;
                const bf16_8 vf = *(const bf16_8*)(Vsm + d * 128 +
                                    ((s * 64 + lg * 16) ^ ((d & 7) << 4)));
                ctx[fd] = __builtin_amdgcn_mfma_f32_16x16x32_bf16(pf, vf, ctx[fd], 0, 0, 0);
            }
        }
    }

#pragma unroll
    for (int r = 0; r < 4; ++r) {
        const float inv = 1.f / l_r[r];
        const size_t rowoff = outhead + (size_t)(q0 + lg * 4 + r) * D_;
#pragma unroll
        for (int fd = 0; fd < 4; ++fd)
            ctxb[rowoff + fd * 16 + l15] = f2b(ctx[fd][r] * inv);
    }
}

// ---------------------------------------------------------------------------
extern "C" void kernel_launch(void* const* d_in, const int* in_sizes, int n_in,
                              void* d_out, int out_size, void* d_ws, size_t ws_size,
                              hipStream_t stream)
{
    const float* h    = (const float*)d_in[0];
    const float* mask = (const float*)d_in[1];
    const float* Wq   = (const float*)d_in[2];
    const float* bq   = (const float*)d_in[3];
    const float* Wk   = (const float*)d_in[4];
    const float* bk   = (const float*)d_in[5];
    const float* Wv   = (const float*)d_in[6];
    const float* bv   = (const float*)d_in[7];
    const float* Wo   = (const float*)d_in[8];
    const float* bo   = (const float*)d_in[9];
    const float* ln1g = (const float*)d_in[10];
    const float* ln1b = (const float*)d_in[11];
    const float* Wi   = (const float*)d_in[12];
    const float* bi   = (const float*)d_in[13];
    const float* Wout = (const float*)d_in[14];
    const float* bout = (const float*)d_in[15];
    const float* ln2g = (const float*)d_in[16];
    const float* ln2b = (const float*)d_in[17];
    float* out = (float*)d_out;

    char* w = (char*)d_ws;
    const size_t MiB = 1ull << 20;
    // liveness-packed layout, peak 120 MiB:
    u16*   Woutt  = (u16*)(w + 0);             // [0,8)
    float* attnF  = (float*)(w + 8 * MiB);     // [8,24)  == Wo partial 0
    float* woP0   = attnF;
    float* woP1   = (float*)(w + 24 * MiB);    // [24,40) dead before interB
    u16*   interB = (u16*)(w + 24 * MiB);      // [24,56)
    u16*   hb     = (u16*)(w + 56 * MiB);      // [56,64) dead before ffP0
    float* ffP0   = (float*)(w + 56 * MiB);    // [56,72)
    u16*   Wqkvt  = (u16*)(w + 64 * MiB);      // [64,70)
    u16*   Wot    = (u16*)(w + 70 * MiB);      // [70,72)
    float* ffP1   = (float*)(w + 72 * MiB);    // [72,88)
    u16*   Wit    = (u16*)(w + 72 * MiB);      // [72,80) dead before ffP1
    float* ffP2   = (float*)(w + 88 * MiB);    // [88,104)
    u16*   QKVb   = (u16*)(w + 80 * MiB);      // [80,104) dead before ffP1/2
    u16*   ctxb   = (u16*)(w + 104 * MiB);     // [104,112)
    float* ffP3   = (float*)(w + 104 * MiB);   // [104,120)
    u16*   attnB  = (u16*)(w + 112 * MiB);     // [112,120) dead before ffP3

    const dim3 blk(256);

    // prep: h -> bf16; weights -> bf16 [N][K]
    cvt_bf16<<<dim3((M_ * D_ / 4) / 256), blk, 0, stream>>>(
        (const float4*)h, (ushort4*)hb, M_ * D_ / 4);
    T4 t4;
    t4.s[0] = Wq; t4.s[1] = Wk; t4.s[2] = Wv; t4.s[3] = Wo;
    t4.d[0] = Wqkvt; t4.d[1] = Wqkvt + 1024 * 1024;
    t4.d[2] = Wqkvt + 2 * 1024 * 1024; t4.d[3] = Wot;
    transpose4_cvt<<<dim3(32, 32, 4), blk, 0, stream>>>(t4);
    transpose_cvt<<<dim3(128, 32), blk, 0, stream>>>(Wi,   Wit,   D_, I_);
    transpose_cvt<<<dim3(32, 128), blk, 0, stream>>>(Wout, Woutt, I_, D_);

    // fused QKV projection: N=3072, grid 768 blocks
    gemm_bf16<0, 1><<<dim3(24, 32), blk, 0, stream>>>(
        hb, Wqkvt, bq, bk, bv, QKVb, 3072, D_);

    // attention (reads QKV with row-stride 3072)
    attn_mfma<<<dim3(S_ / 64, NH_, B_), blk, 0, stream>>>(
        QKVb, QKVb + 1024, QKVb + 2048, mask, ctxb, 3072);

    // Wo projection, split-K x2 -> partials; reduce+bias+res(h)+LN1
    P4 woP; woP.p[0] = woP0; woP.p[1] = woP1; woP.p[2] = nullptr; woP.p[3] = nullptr;
    gemm_splitk<<<dim3(8, 32, 2), blk, 0, stream>>>(ctxb, Wot, woP, D_, D_, 512);
    ln_reduce<2><<<dim3(M_), blk, 0, stream>>>(woP, bo, h, ln1g, ln1b, attnF, attnB);

    // FFN1: GELU GEMM, grid 1024 blocks
    gemm_bf16<1, 0><<<dim3(32, 32), blk, 0, stream>>>(
        attnB, Wit, bi, bi, bi, interB, I_, D_);

    // FFN2: split-K x4 -> partials; reduce+bias+res(attnF)+LN2 -> out
    P4 ffP; ffP.p[0] = ffP0; ffP.p[1] = ffP1; ffP.p[2] = ffP2; ffP.p[3] = ffP3;
    gemm_splitk<<<dim3(8, 32, 4), blk, 0, stream>>>(interB, Woutt, ffP, D_, I_, 1024);
    ln_reduce<4><<<dim3(M_), blk, 0, stream>>>(ffP, bout, attnF, ln2g, ln2b, out, nullptr);
}

// Round 4
// 285.812 us; speedup vs baseline: 8.5014x; 1.0634x over previous
//
#include <hip/hip_runtime.h>
#include <hip/hip_bf16.h>
#include <math.h>

#define B_ 4
#define S_ 1024
#define D_ 1024
#define NH_ 16
#define HD_ 64
#define I_ 4096
#define M_ (B_*S_)

typedef __bf16 bf16_8 __attribute__((ext_vector_type(8)));
typedef float f32x4 __attribute__((ext_vector_type(4)));
typedef unsigned short u16;

struct P4 { float* p[4]; };
struct T4 { const float* s[4]; u16* d[4]; };

__device__ __forceinline__ u16 f2b(float x) {
    __hip_bfloat16 h = __float2bfloat16(x);
    return *reinterpret_cast<u16*>(&h);
}

__device__ __forceinline__ void gload16(const void* g, void* l) {
    __builtin_amdgcn_global_load_lds(
        (const __attribute__((address_space(1))) void*)g,
        (__attribute__((address_space(3))) void*)l, 16, 0, 0);
}

// ---------------------------------------------------------------------------
// fp32 -> bf16 elementwise convert
// ---------------------------------------------------------------------------
__global__ __launch_bounds__(256) void cvt_bf16(
    const float4* __restrict__ in, ushort4* __restrict__ out, int n4)
{
    int i = blockIdx.x * 256 + threadIdx.x;
    if (i < n4) {
        float4 v = in[i];
        ushort4 o;
        o.x = f2b(v.x); o.y = f2b(v.y); o.z = f2b(v.z); o.w = f2b(v.w);
        out[i] = o;
    }
}

// ---------------------------------------------------------------------------
// W[K][N] fp32 -> Wt[N][K] bf16, 32x32 LDS tile transpose.
// ---------------------------------------------------------------------------
__global__ __launch_bounds__(256) void transpose_cvt(
    const float* __restrict__ in, u16* __restrict__ out, int K, int N)
{
    __shared__ float t[32][33];
    const int tid = threadIdx.x;
    const int k0 = blockIdx.y * 32, n0 = blockIdx.x * 32;
#pragma unroll
    for (int i = 0; i < 4; ++i) {
        int idx = i * 256 + tid;
        int r = idx >> 5, c = idx & 31;
        t[r][c] = in[(size_t)(k0 + r) * N + n0 + c];
    }
    __syncthreads();
    const int rr = tid >> 3, cc0 = (tid & 7) * 4;
    ushort4 o;
    o.x = f2b(t[cc0 + 0][rr]);
    o.y = f2b(t[cc0 + 1][rr]);
    o.z = f2b(t[cc0 + 2][rr]);
    o.w = f2b(t[cc0 + 3][rr]);
    *(ushort4*)(out + (size_t)(n0 + rr) * K + k0 + cc0) = o;
}

// fused 4x (1024x1024) transpose: z selects src/dst
__global__ __launch_bounds__(256) void transpose4_cvt(T4 t4)
{
    __shared__ float t[32][33];
    const int tid = threadIdx.x;
    const int k0 = blockIdx.y * 32, n0 = blockIdx.x * 32;
    const float* in = t4.s[blockIdx.z];
    u16* out = t4.d[blockIdx.z];
#pragma unroll
    for (int i = 0; i < 4; ++i) {
        int idx = i * 256 + tid;
        int r = idx >> 5, c = idx & 31;
        t[r][c] = in[(size_t)(k0 + r) * D_ + n0 + c];
    }
    __syncthreads();
    const int rr = tid >> 3, cc0 = (tid & 7) * 4;
    ushort4 o;
    o.x = f2b(t[cc0 + 0][rr]);
    o.y = f2b(t[cc0 + 1][rr]);
    o.z = f2b(t[cc0 + 2][rr]);
    o.w = f2b(t[cc0 + 3][rr]);
    *(ushort4*)(out + (size_t)(n0 + rr) * D_ + k0 + cc0) = o;
}

// ---------------------------------------------------------------------------
// bf16 MFMA GEMM, m97 structure. C = act(A[M,K] @ Bt[N,K]^T + bias).
// QKV3: bias selected from b0/b1/b2 per 1024-col group (fused QKV).
// ---------------------------------------------------------------------------
template<int ACT, int QKV3>
__global__ __launch_bounds__(256) void gemm_bf16(
    const u16* __restrict__ A, const u16* __restrict__ Bt,
    const float* __restrict__ b0, const float* __restrict__ b1,
    const float* __restrict__ b2,
    u16* __restrict__ outB, int N, int K)
{
    __shared__ __align__(16) u16 As[128 * 32];
    __shared__ __align__(16) u16 Bs[128 * 32];

    const int tid  = threadIdx.x;
    const int lane = tid & 63, wid = tid >> 6;
    const int l15  = lane & 15, lg = lane >> 4;
    const int wm   = (wid >> 1) * 64, wn = (wid & 1) * 64;
    const int bm   = blockIdx.y * 128, bn = blockIdx.x * 128;
    const int wbase16 = (tid & ~63) * 16;

    const int r0 = tid >> 2;
    const int c0 = (tid & 3) * 8;

    f32x4 acc[4][4];
#pragma unroll
    for (int i = 0; i < 4; ++i)
#pragma unroll
        for (int j = 0; j < 4; ++j) {
            acc[i][j][0] = 0.f; acc[i][j][1] = 0.f;
            acc[i][j][2] = 0.f; acc[i][j][3] = 0.f;
        }

    for (int kt = 0; kt < K; kt += 32) {
        __syncthreads();
        gload16(A  + (size_t)(bm + r0)      * K + kt + c0, (char*)As + wbase16);
        gload16(A  + (size_t)(bm + r0 + 64) * K + kt + c0, (char*)As + wbase16 + 4096);
        gload16(Bt + (size_t)(bn + r0)      * K + kt + c0, (char*)Bs + wbase16);
        gload16(Bt + (size_t)(bn + r0 + 64) * K + kt + c0, (char*)Bs + wbase16 + 4096);
        __syncthreads();

        bf16_8 af[4], bfr[4];
#pragma unroll
        for (int f = 0; f < 4; ++f) {
            af[f]  = *(const bf16_8*)((const char*)As + (wm + f * 16 + l15) * 64 + lg * 16);
            bfr[f] = *(const bf16_8*)((const char*)Bs + (wn + f * 16 + l15) * 64 + lg * 16);
        }
#pragma unroll
        for (int i = 0; i < 4; ++i)
#pragma unroll
            for (int j = 0; j < 4; ++j)
                acc[i][j] = __builtin_amdgcn_mfma_f32_16x16x32_bf16(
                    af[i], bfr[j], acc[i][j], 0, 0, 0);
    }

    const float* bp = b0;
    int bcol = bn;
    if (QKV3) {
        bp = (bn < 1024) ? b0 : (bn < 2048) ? b1 : b2;
        bcol = bn & 1023;
    }
    float bs[4];
#pragma unroll
    for (int j = 0; j < 4; ++j) bs[j] = bp[bcol + wn + j * 16 + l15];

#pragma unroll
    for (int i = 0; i < 4; ++i) {
#pragma unroll
        for (int r = 0; r < 4; ++r) {
            const int row = bm + wm + i * 16 + lg * 4 + r;
#pragma unroll
            for (int j = 0; j < 4; ++j) {
                const int col = bn + wn + j * 16 + l15;
                float v = acc[i][j][r] + bs[j];
                if (ACT) v = 0.5f * v * (1.0f + erff(v * 0.70710678118654752f));
                outB[(size_t)row * N + col] = f2b(v);
            }
        }
    }
}

// ---------------------------------------------------------------------------
// Split-K bf16 GEMM: blockIdx.z = K-chunk; writes fp32 partials, no epilogue.
// ---------------------------------------------------------------------------
__global__ __launch_bounds__(256) void gemm_splitk(
    const u16* __restrict__ A, const u16* __restrict__ Bt,
    P4 parts, int N, int K, int kchunk)
{
    __shared__ __align__(16) u16 As[128 * 32];
    __shared__ __align__(16) u16 Bs[128 * 32];

    const int tid  = threadIdx.x;
    const int lane = tid & 63, wid = tid >> 6;
    const int l15  = lane & 15, lg = lane >> 4;
    const int wm   = (wid >> 1) * 64, wn = (wid & 1) * 64;
    const int bm   = blockIdx.y * 128, bn = blockIdx.x * 128;
    const int wbase16 = (tid & ~63) * 16;
    const int kt0 = blockIdx.z * kchunk, kt1 = kt0 + kchunk;
    float* outP = parts.p[blockIdx.z];

    const int r0 = tid >> 2;
    const int c0 = (tid & 3) * 8;

    f32x4 acc[4][4];
#pragma unroll
    for (int i = 0; i < 4; ++i)
#pragma unroll
        for (int j = 0; j < 4; ++j) {
            acc[i][j][0] = 0.f; acc[i][j][1] = 0.f;
            acc[i][j][2] = 0.f; acc[i][j][3] = 0.f;
        }

    for (int kt = kt0; kt < kt1; kt += 32) {
        __syncthreads();
        gload16(A  + (size_t)(bm + r0)      * K + kt + c0, (char*)As + wbase16);
        gload16(A  + (size_t)(bm + r0 + 64) * K + kt + c0, (char*)As + wbase16 + 4096);
        gload16(Bt + (size_t)(bn + r0)      * K + kt + c0, (char*)Bs + wbase16);
        gload16(Bt + (size_t)(bn + r0 + 64) * K + kt + c0, (char*)Bs + wbase16 + 4096);
        __syncthreads();

        bf16_8 af[4], bfr[4];
#pragma unroll
        for (int f = 0; f < 4; ++f) {
            af[f]  = *(const bf16_8*)((const char*)As + (wm + f * 16 + l15) * 64 + lg * 16);
            bfr[f] = *(const bf16_8*)((const char*)Bs + (wn + f * 16 + l15) * 64 + lg * 16);
        }
#pragma unroll
        for (int i = 0; i < 4; ++i)
#pragma unroll
            for (int j = 0; j < 4; ++j)
                acc[i][j] = __builtin_amdgcn_mfma_f32_16x16x32_bf16(
                    af[i], bfr[j], acc[i][j], 0, 0, 0);
    }

#pragma unroll
    for (int i = 0; i < 4; ++i)
#pragma unroll
        for (int r = 0; r < 4; ++r) {
            const int row = bm + wm + i * 16 + lg * 4 + r;
#pragma unroll
            for (int j = 0; j < 4; ++j)
                outP[(size_t)row * N + bn + wn + j * 16 + l15] = acc[i][j][r];
        }
}

// ---------------------------------------------------------------------------
// Reduce NPART partials + bias + residual, then LayerNorm over D=1024.
// ---------------------------------------------------------------------------
template<int NPART>
__global__ __launch_bounds__(256) void ln_reduce(
    P4 parts, const float* __restrict__ bias, const float* __restrict__ res,
    const float* __restrict__ g, const float* __restrict__ b,
    float* __restrict__ O, u16* __restrict__ OB)
{
    const int row = blockIdx.x;
    const int tid = threadIdx.x;
    const size_t off = (size_t)row * D_ + tid * 4;

    float4 v = *(const float4*)(res + off);
    const float4 bi = *(const float4*)(bias + tid * 4);
    v.x += bi.x; v.y += bi.y; v.z += bi.z; v.w += bi.w;
#pragma unroll
    for (int p = 0; p < NPART; ++p) {
        const float4 t = *(const float4*)(parts.p[p] + off);
        v.x += t.x; v.y += t.y; v.z += t.z; v.w += t.w;
    }

    float s  = v.x + v.y + v.z + v.w;
    float sq = v.x * v.x + v.y * v.y + v.z * v.z + v.w * v.w;
#pragma unroll
    for (int o = 32; o; o >>= 1) {
        s  += __shfl_down(s, o);
        sq += __shfl_down(sq, o);
    }
    __shared__ float red[8];
    const int wid = tid >> 6, lane = tid & 63;
    if (lane == 0) { red[wid] = s; red[4 + wid] = sq; }
    __syncthreads();
    const float ts = red[0] + red[1] + red[2] + red[3];
    const float tq = red[4] + red[5] + red[6] + red[7];
    const float mu  = ts * (1.0f / D_);
    const float var = tq * (1.0f / D_) - mu * mu;
    const float rs  = rsqrtf(var + 1e-12f);

    const float4 gv = *(const float4*)(g + tid * 4);
    const float4 bv = *(const float4*)(b + tid * 4);
    float4 o;
    o.x = (v.x - mu) * rs * gv.x + bv.x;
    o.y = (v.y - mu) * rs * gv.y + bv.y;
    o.z = (v.z - mu) * rs * gv.z + bv.z;
    o.w = (v.w - mu) * rs * gv.w + bv.w;
    *(float4*)(O + off) = o;
    if (OB) {
        ushort4 ob;
        ob.x = f2b(o.x); ob.y = f2b(o.y); ob.z = f2b(o.z); ob.w = f2b(o.w);
        *(ushort4*)(OB + off) = ob;
    }
}

// ---------------------------------------------------------------------------
// Flash attention, bf16 MFMA, swapped-QK^T (T12 structure).
// Block = 64 q-rows of one (b,h); 4 waves x 16 q. K-tiles of 64 keys.
// S^T = mfma(K,Q): lane holds 16 scores for q=lane&15 -> lane-local softmax.
// ctx^T = mfma(V^T, P^T): lane holds d=fd*16+lg*4+r for q=lane&15.
// ---------------------------------------------------------------------------
__global__ __launch_bounds__(256) void attn_mfma(
    const u16* __restrict__ Qb, const u16* __restrict__ Kb,
    const u16* __restrict__ Vb, const float* __restrict__ mask,
    u16* __restrict__ ctxb, int qs)
{
    __shared__ __align__(16) char sm[24576];
    char* Ksm = sm;                 // [64 key][64 d] bf16, XOR-swizzled
    char* Vsm = sm + 8192;          // [64 d][64 key] bf16 (V^T), XOR-swizzled

    const int tid  = threadIdx.x;
    const int lane = tid & 63, wid = tid >> 6;
    char* Psm = sm + 16384 + wid * 2048;   // per-wave P[16 q][64 key], swizzled
    const int l15 = lane & 15, lg = lane >> 4;
    const int h = blockIdx.y, b = blockIdx.z;
    const int q0 = blockIdx.x * 64 + wid * 16;
    const size_t inhead  = ((size_t)b * S_) * qs + (size_t)h * 64;
    const size_t outhead = ((size_t)b * S_) * D_ + (size_t)h * 64;

    // Q fragments (B operand: col=q=l15, k=lg*8+j)
    const u16* Qrow = Qb + inhead + (size_t)(q0 + l15) * qs;
    const bf16_8 qf0 = *(const bf16_8*)(Qrow + lg * 8);
    const bf16_8 qf1 = *(const bf16_8*)(Qrow + 32 + lg * 8);

    f32x4 ctx[4];
#pragma unroll
    for (int i = 0; i < 4; ++i) { ctx[i][0]=0.f; ctx[i][1]=0.f; ctx[i][2]=0.f; ctx[i][3]=0.f; }
    float m_r = -1e30f, l_r = 0.f;

    const int skey = tid >> 2;
    const int sd0  = (tid & 3) * 16;
    const int xo_p = (l15 & 7) << 4;

    for (int kt = 0; kt < S_; kt += 64) {
        __syncthreads();
        {
            const u16* ks = Kb + inhead + (size_t)(kt + skey) * qs + sd0;
            const bf16_8 k0 = *(const bf16_8*)(ks);
            const bf16_8 k1 = *(const bf16_8*)(ks + 8);
            const int xo = (skey & 7) << 4;
            *(bf16_8*)(Ksm + skey * 128 + ((sd0 * 2)      ^ xo)) = k0;
            *(bf16_8*)(Ksm + skey * 128 + ((sd0 * 2 + 16) ^ xo)) = k1;

            const u16* vs = Vb + inhead + (size_t)(kt + skey) * qs + sd0;
            const bf16_8 v0 = *(const bf16_8*)(vs);
            const bf16_8 v1 = *(const bf16_8*)(vs + 8);
#pragma unroll
            for (int j = 0; j < 8; ++j) {
                const int d = sd0 + j;
                *(__bf16*)(Vsm + d * 128 + ((skey * 2) ^ ((d & 7) << 4))) = v0[j];
            }
#pragma unroll
            for (int j = 0; j < 8; ++j) {
                const int d = sd0 + 8 + j;
                *(__bf16*)(Vsm + d * 128 + ((skey * 2) ^ ((d & 7) << 4))) = v1[j];
            }
        }
        __syncthreads();

        // S^T = K·Q^T: frag kf rows = keys kf*16+lg*4+r, col = q = l15
        f32x4 sc[4];
#pragma unroll
        for (int kf = 0; kf < 4; ++kf) {
            const int key = kf * 16 + l15;
            const int xo = (key & 7) << 4;
            f32x4 a; a[0]=0.f; a[1]=0.f; a[2]=0.f; a[3]=0.f;
            const bf16_8 kA = *(const bf16_8*)(Ksm + key * 128 + ((lg * 16)      ^ xo));
            a = __builtin_amdgcn_mfma_f32_16x16x32_bf16(kA, qf0, a, 0, 0, 0);
            const bf16_8 kB = *(const bf16_8*)(Ksm + key * 128 + ((64 + lg * 16) ^ xo));
            a = __builtin_amdgcn_mfma_f32_16x16x32_bf16(kB, qf1, a, 0, 0, 0);
            sc[kf] = a;
        }

        // lane-local softmax for q = l15 over this tile's 16 keys (x4 lg)
        float p[16];
        float tmax = -1e30f;
#pragma unroll
        for (int kf = 0; kf < 4; ++kf) {
            const float4 mk = *(const float4*)(mask + (size_t)b * S_ + kt + kf * 16 + lg * 4);
#pragma unroll
            for (int r = 0; r < 4; ++r) {
                const float mkr = (r == 0) ? mk.x : (r == 1) ? mk.y : (r == 2) ? mk.z : mk.w;
                p[kf * 4 + r] = sc[kf][r] * 0.125f + mkr;
                tmax = fmaxf(tmax, p[kf * 4 + r]);
            }
        }
        tmax = fmaxf(tmax, __shfl_xor(tmax, 16));
        tmax = fmaxf(tmax, __shfl_xor(tmax, 32));

        const float mnew = fmaxf(m_r, tmax);
        const float scl  = __expf(m_r - mnew);
        m_r = mnew;

        float psum = 0.f;
#pragma unroll
        for (int i = 0; i < 16; ++i) {
            p[i] = __expf(p[i] - mnew);
            psum += p[i];
        }
        psum += __shfl_xor(psum, 16);
        psum += __shfl_xor(psum, 32);
        l_r = l_r * scl + psum;

#pragma unroll
        for (int fd = 0; fd < 4; ++fd)
#pragma unroll
            for (int r = 0; r < 4; ++r) ctx[fd][r] *= scl;

        // store P row q=l15 (8 x ushort2, swizzled)
#pragma unroll
        for (int kf = 0; kf < 4; ++kf)
#pragma unroll
            for (int rr = 0; rr < 2; ++rr) {
                ushort2 wv;
                wv.x = f2b(p[kf * 4 + 2 * rr]);
                wv.y = f2b(p[kf * 4 + 2 * rr + 1]);
                *(ushort2*)(Psm + l15 * 128 +
                            (((kf * 16 + lg * 4 + 2 * rr) * 2) ^ xo_p)) = wv;
            }

        asm volatile("s_waitcnt lgkmcnt(0)" ::: "memory");

        // ctx^T += V^T · P^T  (A = V^T frag, B = P^T frag)
#pragma unroll
        for (int s = 0; s < 2; ++s) {
            const bf16_8 pf = *(const bf16_8*)(Psm + l15 * 128 +
                                ((s * 64 + lg * 16) ^ xo_p));
#pragma unroll
            for (int fd = 0; fd < 4; ++fd) {
                const int d = fd * 16 + l15;
                const bf16_8 vf = *(const bf16_8*)(Vsm + d * 128 +
                                    ((s * 64 + lg * 16) ^ ((d & 7) << 4)));
                ctx[fd] = __builtin_amdgcn_mfma_f32_16x16x32_bf16(vf, pf, ctx[fd], 0, 0, 0);
            }
        }
    }

    // normalize + write ctx^T: lane q=l15, d = fd*16+lg*4+r (ushort4 stores)
    const float inv = 1.f / l_r;
    const size_t qrow = outhead + (size_t)(q0 + l15) * D_;
#pragma unroll
    for (int fd = 0; fd < 4; ++fd) {
        ushort4 o;
        o.x = f2b(ctx[fd][0] * inv);
        o.y = f2b(ctx[fd][1] * inv);
        o.z = f2b(ctx[fd][2] * inv);
        o.w = f2b(ctx[fd][3] * inv);
        *(ushort4*)(ctxb + qrow + fd * 16 + lg * 4) = o;
    }
}

// ---------------------------------------------------------------------------
extern "C" void kernel_launch(void* const* d_in, const int* in_sizes, int n_in,
                              void* d_out, int out_size, void* d_ws, size_t ws_size,
                              hipStream_t stream)
{
    const float* h    = (const float*)d_in[0];
    const float* mask = (const float*)d_in[1];
    const float* Wq   = (const float*)d_in[2];
    const float* bq   = (const float*)d_in[3];
    const float* Wk   = (const float*)d_in[4];
    const float* bk   = (const float*)d_in[5];
    const float* Wv   = (const float*)d_in[6];
    const float* bv   = (const float*)d_in[7];
    const float* Wo   = (const float*)d_in[8];
    const float* bo   = (const float*)d_in[9];
    const float* ln1g = (const float*)d_in[10];
    const float* ln1b = (const float*)d_in[11];
    const float* Wi   = (const float*)d_in[12];
    const float* bi   = (const float*)d_in[13];
    const float* Wout = (const float*)d_in[14];
    const float* bout = (const float*)d_in[15];
    const float* ln2g = (const float*)d_in[16];
    const float* ln2b = (const float*)d_in[17];
    float* out = (float*)d_out;

    char* w = (char*)d_ws;
    const size_t MiB = 1ull << 20;
    // liveness-packed layout, peak 120 MiB:
    u16*   Woutt  = (u16*)(w + 0);             // [0,8)
    float* attnF  = (float*)(w + 8 * MiB);     // [8,24)  == Wo partial 0
    float* woP0   = attnF;
    float* woP1   = (float*)(w + 24 * MiB);    // [24,40) dead before interB
    u16*   interB = (u16*)(w + 24 * MiB);      // [24,56)
    u16*   hb     = (u16*)(w + 56 * MiB);      // [56,64) dead before ffP0
    float* ffP0   = (float*)(w + 56 * MiB);    // [56,72)
    u16*   Wqkvt  = (u16*)(w + 64 * MiB);      // [64,70)
    u16*   Wot    = (u16*)(w + 70 * MiB);      // [70,72)
    float* ffP1   = (float*)(w + 72 * MiB);    // [72,88)
    u16*   Wit    = (u16*)(w + 72 * MiB);      // [72,80) dead before ffP1
    float* ffP2   = (float*)(w + 88 * MiB);    // [88,104)
    u16*   QKVb   = (u16*)(w + 80 * MiB);      // [80,104) dead before ffP1/2
    u16*   ctxb   = (u16*)(w + 104 * MiB);     // [104,112)
    float* ffP3   = (float*)(w + 104 * MiB);   // [104,120)
    u16*   attnB  = (u16*)(w + 112 * MiB);     // [112,120) dead before ffP3

    const dim3 blk(256);

    // prep: h -> bf16; weights -> bf16 [N][K]
    cvt_bf16<<<dim3((M_ * D_ / 4) / 256), blk, 0, stream>>>(
        (const float4*)h, (ushort4*)hb, M_ * D_ / 4);
    T4 t4;
    t4.s[0] = Wq; t4.s[1] = Wk; t4.s[2] = Wv; t4.s[3] = Wo;
    t4.d[0] = Wqkvt; t4.d[1] = Wqkvt + 1024 * 1024;
    t4.d[2] = Wqkvt + 2 * 1024 * 1024; t4.d[3] = Wot;
    transpose4_cvt<<<dim3(32, 32, 4), blk, 0, stream>>>(t4);
    transpose_cvt<<<dim3(128, 32), blk, 0, stream>>>(Wi,   Wit,   D_, I_);
    transpose_cvt<<<dim3(32, 128), blk, 0, stream>>>(Wout, Woutt, I_, D_);

    // fused QKV projection: N=3072, grid 768 blocks
    gemm_bf16<0, 1><<<dim3(24, 32), blk, 0, stream>>>(
        hb, Wqkvt, bq, bk, bv, QKVb, 3072, D_);

    // attention (reads QKV with row-stride 3072)
    attn_mfma<<<dim3(S_ / 64, NH_, B_), blk, 0, stream>>>(
        QKVb, QKVb + 1024, QKVb + 2048, mask, ctxb, 3072);

    // Wo projection, split-K x2 -> partials; reduce+bias+res(h)+LN1
    P4 woP; woP.p[0] = woP0; woP.p[1] = woP1; woP.p[2] = nullptr; woP.p[3] = nullptr;
    gemm_splitk<<<dim3(8, 32, 2), blk, 0, stream>>>(ctxb, Wot, woP, D_, D_, 512);
    ln_reduce<2><<<dim3(M_), blk, 0, stream>>>(woP, bo, h, ln1g, ln1b, attnF, attnB);

    // FFN1: GELU GEMM, grid 1024 blocks
    gemm_bf16<1, 0><<<dim3(32, 32), blk, 0, stream>>>(
        attnB, Wit, bi, bi, bi, interB, I_, D_);

    // FFN2: split-K x4 -> partials; reduce+bias+res(attnF)+LN2 -> out
    P4 ffP; ffP.p[0] = ffP0; ffP.p[1] = ffP1; ffP.p[2] = ffP2; ffP.p[3] = ffP3;
    gemm_splitk<<<dim3(8, 32, 4), blk, 0, stream>>>(interB, Woutt, ffP, D_, I_, 1024);
    ln_reduce<4><<<dim3(M_), blk, 0, stream>>>(ffP, bout, attnF, ln2g, ln2b, out, nullptr);
}

// Round 5
// 239.003 us; speedup vs baseline: 10.1664x; 1.1958x over previous
//
#include <hip/hip_runtime.h>
#include <hip/hip_bf16.h>
#include <math.h>

#define B_ 4
#define S_ 1024
#define D_ 1024
#define NH_ 16
#define HD_ 64
#define I_ 4096
#define M_ (B_*S_)

typedef __bf16 bf16_8 __attribute__((ext_vector_type(8)));
typedef float f32x4 __attribute__((ext_vector_type(4)));
typedef unsigned short u16;

struct P4 { float* p[4]; };
struct T4 { const float* s[4]; u16* d[4]; };

__device__ __forceinline__ u16 f2b(float x) {
    __hip_bfloat16 h = __float2bfloat16(x);
    return *reinterpret_cast<u16*>(&h);
}

__device__ __forceinline__ void gload16(const void* g, void* l) {
    __builtin_amdgcn_global_load_lds(
        (const __attribute__((address_space(1))) void*)g,
        (__attribute__((address_space(3))) void*)l, 16, 0, 0);
}

// ---------------------------------------------------------------------------
// fp32 -> bf16 elementwise convert
// ---------------------------------------------------------------------------
__global__ __launch_bounds__(256) void cvt_bf16(
    const float4* __restrict__ in, ushort4* __restrict__ out, int n4)
{
    int i = blockIdx.x * 256 + threadIdx.x;
    if (i < n4) {
        float4 v = in[i];
        ushort4 o;
        o.x = f2b(v.x); o.y = f2b(v.y); o.z = f2b(v.z); o.w = f2b(v.w);
        out[i] = o;
    }
}

// ---------------------------------------------------------------------------
// W[K][N] fp32 -> Wt[N][K] bf16, 32x32 LDS tile transpose.
// ---------------------------------------------------------------------------
__global__ __launch_bounds__(256) void transpose_cvt(
    const float* __restrict__ in, u16* __restrict__ out, int K, int N)
{
    __shared__ float t[32][33];
    const int tid = threadIdx.x;
    const int k0 = blockIdx.y * 32, n0 = blockIdx.x * 32;
#pragma unroll
    for (int i = 0; i < 4; ++i) {
        int idx = i * 256 + tid;
        int r = idx >> 5, c = idx & 31;
        t[r][c] = in[(size_t)(k0 + r) * N + n0 + c];
    }
    __syncthreads();
    const int rr = tid >> 3, cc0 = (tid & 7) * 4;
    ushort4 o;
    o.x = f2b(t[cc0 + 0][rr]);
    o.y = f2b(t[cc0 + 1][rr]);
    o.z = f2b(t[cc0 + 2][rr]);
    o.w = f2b(t[cc0 + 3][rr]);
    *(ushort4*)(out + (size_t)(n0 + rr) * K + k0 + cc0) = o;
}

// fused 4x (1024x1024) transpose: z selects src/dst
__global__ __launch_bounds__(256) void transpose4_cvt(T4 t4)
{
    __shared__ float t[32][33];
    const int tid = threadIdx.x;
    const int k0 = blockIdx.y * 32, n0 = blockIdx.x * 32;
    const float* in = t4.s[blockIdx.z];
    u16* out = t4.d[blockIdx.z];
#pragma unroll
    for (int i = 0; i < 4; ++i) {
        int idx = i * 256 + tid;
        int r = idx >> 5, c = idx & 31;
        t[r][c] = in[(size_t)(k0 + r) * D_ + n0 + c];
    }
    __syncthreads();
    const int rr = tid >> 3, cc0 = (tid & 7) * 4;
    ushort4 o;
    o.x = f2b(t[cc0 + 0][rr]);
    o.y = f2b(t[cc0 + 1][rr]);
    o.z = f2b(t[cc0 + 2][rr]);
    o.w = f2b(t[cc0 + 3][rr]);
    *(ushort4*)(out + (size_t)(n0 + rr) * D_ + k0 + cc0) = o;
}

// ---------------------------------------------------------------------------
// 256x256 8-phase bf16 MFMA GEMM (HK-style schedule, plain HIP).
// C[M,N] = epi(A[M,K-chunk] @ Bt[N,K-chunk]^T), K-chunk = 1024 (NT=16 tiles
// of BK=64). 512 threads = 8 waves (2M x 4N), per-wave 128x64 output.
// LDS: 2 dbuf x {A: 2x[128][64], B: 2x[128][64]} bf16 = 128 KiB.
// XOR swizzle byte^=((row&7)<<4): inverse-swz global source + swz ds_read.
// Counted vmcnt(4): A(v+2) issued @p4, B(v+1) @p1; never drain to 0 in-loop.
// MODE 0: +bias(QKV-select) -> bf16.  MODE 1: +bias+GELU -> bf16.
// MODE 2: split-K fp32 partial (blockIdx.z selects chunk+partial buffer).
// ---------------------------------------------------------------------------
#define NT_ 16

template<int MODE>
__global__ __launch_bounds__(512, 2) void gemm256(
    const u16* __restrict__ A, const u16* __restrict__ Bt,
    const float* __restrict__ b0, const float* __restrict__ b1,
    const float* __restrict__ b2,
    u16* __restrict__ outB, P4 parts, int N, int sA, int sB)
{
    __shared__ __align__(16) char sm[131072];

    const int tid  = threadIdx.x;
    const int lane = tid & 63, wid = tid >> 6;
    const int l15  = lane & 15, lg = lane >> 4;
    const int gm   = wid >> 2, gn = wid & 3;
    const int bm   = blockIdx.y * 256, bn = blockIdx.x * 256;
    const int koff = blockIdx.z * 1024;

    // staging constants (per lane): linear dest byte p = wid*1024 + lane*16
    const int srow = (wid << 3) + (lane >> 3);                 // p>>7 (round 0)
    const int skb  = ((lane & 7) << 4) ^ (((lane >> 3) & 7) << 4); // (p&127)^swz
    const int scol = skb >> 1;                                 // element offset
    // read-side swizzle mask (row&7 == l15&7 for all frag rows)
    const int xm   = (l15 & 7) << 4;

    f32x4 acc[8][4];
#pragma unroll
    for (int m = 0; m < 8; ++m)
#pragma unroll
        for (int j = 0; j < 4; ++j) {
            acc[m][j][0] = 0.f; acc[m][j][1] = 0.f;
            acc[m][j][2] = 0.f; acc[m][j][3] = 0.f;
        }

    // stage half-tile h of K-tile v (2 x gload16 per wave)
    auto stageA = [&](int v, int h) {
        const u16* src = A + (size_t)(bm + h * 128 + srow) * sA + koff + v * 64 + scol;
        char* dst = sm + ((v & 1) * 65536 + h * 16384 + wid * 1024);
        gload16(src, dst);
        gload16(src + (size_t)64 * sA, dst + 8192);
    };
    auto stageB = [&](int v, int h) {
        const u16* src = Bt + (size_t)(bn + h * 128 + srow) * sB + koff + v * 64 + scol;
        char* dst = sm + ((v & 1) * 65536 + 32768 + h * 16384 + wid * 1024);
        gload16(src, dst);
        gload16(src + (size_t)64 * sB, dst + 8192);
    };

    bf16_8 a[8], bb[2];
    auto loadA = [&](int vb, int s) {
        const char* base = sm + (vb * 65536 + gm * 16384);
#pragma unroll
        for (int m = 0; m < 8; ++m)
            a[m] = *(const bf16_8*)(base + (m * 16 + l15) * 128 +
                                    ((s * 64 + lg * 16) ^ xm));
    };
    auto loadB = [&](int vb, int s, int np) {
        const char* base = sm + (vb * 65536 + 32768 + (gn >> 1) * 16384);
#pragma unroll
        for (int j = 0; j < 2; ++j)
            bb[j] = *(const bf16_8*)(base + ((gn & 1) * 64 + (np * 2 + j) * 16 + l15) * 128 +
                                     ((s * 64 + lg * 16) ^ xm));
    };
    auto mfma16 = [&](int np) {
#pragma unroll
        for (int m = 0; m < 8; ++m)
#pragma unroll
            for (int j = 0; j < 2; ++j)
                acc[m][np * 2 + j] = __builtin_amdgcn_mfma_f32_16x16x32_bf16(
                    a[m], bb[j], acc[m][np * 2 + j], 0, 0, 0);
    };

    // prologue: stage tile0 fully + A(1); wait tile0; barrier
    stageA(0, 0); stageA(0, 1);
    stageB(0, 0); stageB(0, 1);
    stageA(1, 0); stageA(1, 1);
    asm volatile("s_waitcnt vmcnt(4)" ::: "memory");
    __builtin_amdgcn_sched_barrier(0);
    __builtin_amdgcn_s_barrier();

    // main loop: full prefetch pattern
    for (int v = 0; v < NT_ - 2; ++v) {
        const int vb = v & 1;
        // p1: kslice0, N-pair0; issue B(v+1)
        loadA(vb, 0); loadB(vb, 0, 0);
        stageB(v + 1, 0); stageB(v + 1, 1);
        __builtin_amdgcn_s_barrier();
        asm volatile("s_waitcnt lgkmcnt(0)" ::: "memory");
        __builtin_amdgcn_s_setprio(1); mfma16(0); __builtin_amdgcn_s_setprio(0);
        __builtin_amdgcn_s_barrier();
        // p2: kslice0, N-pair1
        loadB(vb, 0, 1);
        __builtin_amdgcn_s_barrier();
        asm volatile("s_waitcnt lgkmcnt(0)" ::: "memory");
        __builtin_amdgcn_s_setprio(1); mfma16(1); __builtin_amdgcn_s_setprio(0);
        __builtin_amdgcn_s_barrier();
        // p3: kslice1, N-pair0
        loadA(vb, 1); loadB(vb, 1, 0);
        __builtin_amdgcn_s_barrier();
        asm volatile("s_waitcnt lgkmcnt(0)" ::: "memory");
        __builtin_amdgcn_s_setprio(1); mfma16(0); __builtin_amdgcn_s_setprio(0);
        __builtin_amdgcn_s_barrier();
        // p4: kslice1, N-pair1; issue A(v+2); counted vmcnt
        loadB(vb, 1, 1);
        stageA(v + 2, 0); stageA(v + 2, 1);
        __builtin_amdgcn_s_barrier();
        asm volatile("s_waitcnt lgkmcnt(0)" ::: "memory");
        __builtin_amdgcn_s_setprio(1); mfma16(1); __builtin_amdgcn_s_setprio(0);
        asm volatile("s_waitcnt vmcnt(4)" ::: "memory");
        __builtin_amdgcn_sched_barrier(0);
        __builtin_amdgcn_s_barrier();
    }
    // tail v = NT_-2: issue B(NT_-1) only; drain fully at p4
    {
        const int vb = (NT_ - 2) & 1;
        loadA(vb, 0); loadB(vb, 0, 0);
        stageB(NT_ - 1, 0); stageB(NT_ - 1, 1);
        __builtin_amdgcn_s_barrier();
        asm volatile("s_waitcnt lgkmcnt(0)" ::: "memory");
        __builtin_amdgcn_s_setprio(1); mfma16(0); __builtin_amdgcn_s_setprio(0);
        __builtin_amdgcn_s_barrier();
        loadB(vb, 0, 1);
        __builtin_amdgcn_s_barrier();
        asm volatile("s_waitcnt lgkmcnt(0)" ::: "memory");
        __builtin_amdgcn_s_setprio(1); mfma16(1); __builtin_amdgcn_s_setprio(0);
        __builtin_amdgcn_s_barrier();
        loadA(vb, 1); loadB(vb, 1, 0);
        __builtin_amdgcn_s_barrier();
        asm volatile("s_waitcnt lgkmcnt(0)" ::: "memory");
        __builtin_amdgcn_s_setprio(1); mfma16(0); __builtin_amdgcn_s_setprio(0);
        __builtin_amdgcn_s_barrier();
        loadB(vb, 1, 1);
        __builtin_amdgcn_s_barrier();
        asm volatile("s_waitcnt lgkmcnt(0)" ::: "memory");
        __builtin_amdgcn_s_setprio(1); mfma16(1); __builtin_amdgcn_s_setprio(0);
        asm volatile("s_waitcnt vmcnt(0)" ::: "memory");
        __builtin_amdgcn_sched_barrier(0);
        __builtin_amdgcn_s_barrier();
    }
    // tail v = NT_-1: everything resident; no barriers needed
    {
        const int vb = (NT_ - 1) & 1;
        loadA(vb, 0); loadB(vb, 0, 0); mfma16(0);
        loadB(vb, 0, 1);               mfma16(1);
        loadA(vb, 1); loadB(vb, 1, 0); mfma16(0);
        loadB(vb, 1, 1);               mfma16(1);
    }

    // epilogue
    if (MODE == 2) {
        float* oP = parts.p[blockIdx.z];
#pragma unroll
        for (int m = 0; m < 8; ++m)
#pragma unroll
            for (int r = 0; r < 4; ++r) {
                const int row = bm + gm * 128 + m * 16 + lg * 4 + r;
#pragma unroll
                for (int j = 0; j < 4; ++j)
                    oP[(size_t)row * N + bn + gn * 64 + j * 16 + l15] = acc[m][j][r];
            }
    } else {
        const int cg = (bn + gn * 64) >> 10;
        const float* bp = (MODE == 0) ? (cg == 0 ? b0 : cg == 1 ? b1 : b2) : b0;
        const int cbase = (MODE == 0) ? ((bn + gn * 64) & 1023) : (bn + gn * 64);
        float bs[4];
#pragma unroll
        for (int j = 0; j < 4; ++j) bs[j] = bp[cbase + j * 16 + l15];
#pragma unroll
        for (int m = 0; m < 8; ++m)
#pragma unroll
            for (int r = 0; r < 4; ++r) {
                const int row = bm + gm * 128 + m * 16 + lg * 4 + r;
#pragma unroll
                for (int j = 0; j < 4; ++j) {
                    float v = acc[m][j][r] + bs[j];
                    if (MODE == 1)
                        v = 0.5f * v * (1.0f + erff(v * 0.70710678118654752f));
                    outB[(size_t)row * N + bn + gn * 64 + j * 16 + l15] = f2b(v);
                }
            }
    }
}

// ---------------------------------------------------------------------------
// Split-K bf16 GEMM (m97 128x128 structure) — used for Wo only.
// ---------------------------------------------------------------------------
__global__ __launch_bounds__(256) void gemm_splitk(
    const u16* __restrict__ A, const u16* __restrict__ Bt,
    P4 parts, int N, int K, int kchunk)
{
    __shared__ __align__(16) u16 As[128 * 32];
    __shared__ __align__(16) u16 Bs[128 * 32];

    const int tid  = threadIdx.x;
    const int lane = tid & 63, wid = tid >> 6;
    const int l15  = lane & 15, lg = lane >> 4;
    const int wm   = (wid >> 1) * 64, wn = (wid & 1) * 64;
    const int bm   = blockIdx.y * 128, bn = blockIdx.x * 128;
    const int wbase16 = (tid & ~63) * 16;
    const int kt0 = blockIdx.z * kchunk, kt1 = kt0 + kchunk;
    float* outP = parts.p[blockIdx.z];

    const int r0 = tid >> 2;
    const int c0 = (tid & 3) * 8;

    f32x4 acc[4][4];
#pragma unroll
    for (int i = 0; i < 4; ++i)
#pragma unroll
        for (int j = 0; j < 4; ++j) {
            acc[i][j][0] = 0.f; acc[i][j][1] = 0.f;
            acc[i][j][2] = 0.f; acc[i][j][3] = 0.f;
        }

    for (int kt = kt0; kt < kt1; kt += 32) {
        __syncthreads();
        gload16(A  + (size_t)(bm + r0)      * K + kt + c0, (char*)As + wbase16);
        gload16(A  + (size_t)(bm + r0 + 64) * K + kt + c0, (char*)As + wbase16 + 4096);
        gload16(Bt + (size_t)(bn + r0)      * K + kt + c0, (char*)Bs + wbase16);
        gload16(Bt + (size_t)(bn + r0 + 64) * K + kt + c0, (char*)Bs + wbase16 + 4096);
        __syncthreads();

        bf16_8 af[4], bfr[4];
#pragma unroll
        for (int f = 0; f < 4; ++f) {
            af[f]  = *(const bf16_8*)((const char*)As + (wm + f * 16 + l15) * 64 + lg * 16);
            bfr[f] = *(const bf16_8*)((const char*)Bs + (wn + f * 16 + l15) * 64 + lg * 16);
        }
#pragma unroll
        for (int i = 0; i < 4; ++i)
#pragma unroll
            for (int j = 0; j < 4; ++j)
                acc[i][j] = __builtin_amdgcn_mfma_f32_16x16x32_bf16(
                    af[i], bfr[j], acc[i][j], 0, 0, 0);
    }

#pragma unroll
    for (int i = 0; i < 4; ++i)
#pragma unroll
        for (int r = 0; r < 4; ++r) {
            const int row = bm + wm + i * 16 + lg * 4 + r;
#pragma unroll
            for (int j = 0; j < 4; ++j)
                outP[(size_t)row * N + bn + wn + j * 16 + l15] = acc[i][j][r];
        }
}

// ---------------------------------------------------------------------------
// Reduce NPART partials + bias + residual, then LayerNorm over D=1024.
// ---------------------------------------------------------------------------
template<int NPART>
__global__ __launch_bounds__(256) void ln_reduce(
    P4 parts, const float* __restrict__ bias, const float* __restrict__ res,
    const float* __restrict__ g, const float* __restrict__ b,
    float* __restrict__ O, u16* __restrict__ OB)
{
    const int row = blockIdx.x;
    const int tid = threadIdx.x;
    const size_t off = (size_t)row * D_ + tid * 4;

    float4 v = *(const float4*)(res + off);
    const float4 bi = *(const float4*)(bias + tid * 4);
    v.x += bi.x; v.y += bi.y; v.z += bi.z; v.w += bi.w;
#pragma unroll
    for (int p = 0; p < NPART; ++p) {
        const float4 t = *(const float4*)(parts.p[p] + off);
        v.x += t.x; v.y += t.y; v.z += t.z; v.w += t.w;
    }

    float s  = v.x + v.y + v.z + v.w;
    float sq = v.x * v.x + v.y * v.y + v.z * v.z + v.w * v.w;
#pragma unroll
    for (int o = 32; o; o >>= 1) {
        s  += __shfl_down(s, o);
        sq += __shfl_down(sq, o);
    }
    __shared__ float red[8];
    const int wid = tid >> 6, lane = tid & 63;
    if (lane == 0) { red[wid] = s; red[4 + wid] = sq; }
    __syncthreads();
    const float ts = red[0] + red[1] + red[2] + red[3];
    const float tq = red[4] + red[5] + red[6] + red[7];
    const float mu  = ts * (1.0f / D_);
    const float var = tq * (1.0f / D_) - mu * mu;
    const float rs  = rsqrtf(var + 1e-12f);

    const float4 gv = *(const float4*)(g + tid * 4);
    const float4 bv = *(const float4*)(b + tid * 4);
    float4 o;
    o.x = (v.x - mu) * rs * gv.x + bv.x;
    o.y = (v.y - mu) * rs * gv.y + bv.y;
    o.z = (v.z - mu) * rs * gv.z + bv.z;
    o.w = (v.w - mu) * rs * gv.w + bv.w;
    *(float4*)(O + off) = o;
    if (OB) {
        ushort4 ob;
        ob.x = f2b(o.x); ob.y = f2b(o.y); ob.z = f2b(o.z); ob.w = f2b(o.w);
        *(ushort4*)(OB + off) = ob;
    }
}

// ---------------------------------------------------------------------------
// Flash attention, bf16 MFMA, swapped-QK^T (T12 structure). Unchanged (R4).
// ---------------------------------------------------------------------------
__global__ __launch_bounds__(256) void attn_mfma(
    const u16* __restrict__ Qb, const u16* __restrict__ Kb,
    const u16* __restrict__ Vb, const float* __restrict__ mask,
    u16* __restrict__ ctxb, int qs)
{
    __shared__ __align__(16) char sm[24576];
    char* Ksm = sm;
    char* Vsm = sm + 8192;

    const int tid  = threadIdx.x;
    const int lane = tid & 63, wid = tid >> 6;
    char* Psm = sm + 16384 + wid * 2048;
    const int l15 = lane & 15, lg = lane >> 4;
    const int h = blockIdx.y, b = blockIdx.z;
    const int q0 = blockIdx.x * 64 + wid * 16;
    const size_t inhead  = ((size_t)b * S_) * qs + (size_t)h * 64;
    const size_t outhead = ((size_t)b * S_) * D_ + (size_t)h * 64;

    const u16* Qrow = Qb + inhead + (size_t)(q0 + l15) * qs;
    const bf16_8 qf0 = *(const bf16_8*)(Qrow + lg * 8);
    const bf16_8 qf1 = *(const bf16_8*)(Qrow + 32 + lg * 8);

    f32x4 ctx[4];
#pragma unroll
    for (int i = 0; i < 4; ++i) { ctx[i][0]=0.f; ctx[i][1]=0.f; ctx[i][2]=0.f; ctx[i][3]=0.f; }
    float m_r = -1e30f, l_r = 0.f;

    const int skey = tid >> 2;
    const int sd0  = (tid & 3) * 16;
    const int xo_p = (l15 & 7) << 4;

    for (int kt = 0; kt < S_; kt += 64) {
        __syncthreads();
        {
            const u16* ks = Kb + inhead + (size_t)(kt + skey) * qs + sd0;
            const bf16_8 k0 = *(const bf16_8*)(ks);
            const bf16_8 k1 = *(const bf16_8*)(ks + 8);
            const int xo = (skey & 7) << 4;
            *(bf16_8*)(Ksm + skey * 128 + ((sd0 * 2)      ^ xo)) = k0;
            *(bf16_8*)(Ksm + skey * 128 + ((sd0 * 2 + 16) ^ xo)) = k1;

            const u16* vs = Vb + inhead + (size_t)(kt + skey) * qs + sd0;
            const bf16_8 v0 = *(const bf16_8*)(vs);
            const bf16_8 v1 = *(const bf16_8*)(vs + 8);
#pragma unroll
            for (int j = 0; j < 8; ++j) {
                const int d = sd0 + j;
                *(__bf16*)(Vsm + d * 128 + ((skey * 2) ^ ((d & 7) << 4))) = v0[j];
            }
#pragma unroll
            for (int j = 0; j < 8; ++j) {
                const int d = sd0 + 8 + j;
                *(__bf16*)(Vsm + d * 128 + ((skey * 2) ^ ((d & 7) << 4))) = v1[j];
            }
        }
        __syncthreads();

        f32x4 sc[4];
#pragma unroll
        for (int kf = 0; kf < 4; ++kf) {
            const int key = kf * 16 + l15;
            const int xo = (key & 7) << 4;
            f32x4 a; a[0]=0.f; a[1]=0.f; a[2]=0.f; a[3]=0.f;
            const bf16_8 kA = *(const bf16_8*)(Ksm + key * 128 + ((lg * 16)      ^ xo));
            a = __builtin_amdgcn_mfma_f32_16x16x32_bf16(kA, qf0, a, 0, 0, 0);
            const bf16_8 kB = *(const bf16_8*)(Ksm + key * 128 + ((64 + lg * 16) ^ xo));
            a = __builtin_amdgcn_mfma_f32_16x16x32_bf16(kB, qf1, a, 0, 0, 0);
            sc[kf] = a;
        }

        float p[16];
        float tmax = -1e30f;
#pragma unroll
        for (int kf = 0; kf < 4; ++kf) {
            const float4 mk = *(const float4*)(mask + (size_t)b * S_ + kt + kf * 16 + lg * 4);
#pragma unroll
            for (int r = 0; r < 4; ++r) {
                const float mkr = (r == 0) ? mk.x : (r == 1) ? mk.y : (r == 2) ? mk.z : mk.w;
                p[kf * 4 + r] = sc[kf][r] * 0.125f + mkr;
                tmax = fmaxf(tmax, p[kf * 4 + r]);
            }
        }
        tmax = fmaxf(tmax, __shfl_xor(tmax, 16));
        tmax = fmaxf(tmax, __shfl_xor(tmax, 32));

        const float mnew = fmaxf(m_r, tmax);
        const float scl  = __expf(m_r - mnew);
        m_r = mnew;

        float psum = 0.f;
#pragma unroll
        for (int i = 0; i < 16; ++i) {
            p[i] = __expf(p[i] - mnew);
            psum += p[i];
        }
        psum += __shfl_xor(psum, 16);
        psum += __shfl_xor(psum, 32);
        l_r = l_r * scl + psum;

#pragma unroll
        for (int fd = 0; fd < 4; ++fd)
#pragma unroll
            for (int r = 0; r < 4; ++r) ctx[fd][r] *= scl;

#pragma unroll
        for (int kf = 0; kf < 4; ++kf)
#pragma unroll
            for (int rr = 0; rr < 2; ++rr) {
                ushort2 wv;
                wv.x = f2b(p[kf * 4 + 2 * rr]);
                wv.y = f2b(p[kf * 4 + 2 * rr + 1]);
                *(ushort2*)(Psm + l15 * 128 +
                            (((kf * 16 + lg * 4 + 2 * rr) * 2) ^ xo_p)) = wv;
            }

        asm volatile("s_waitcnt lgkmcnt(0)" ::: "memory");

#pragma unroll
        for (int s = 0; s < 2; ++s) {
            const bf16_8 pf = *(const bf16_8*)(Psm + l15 * 128 +
                                ((s * 64 + lg * 16) ^ xo_p));
#pragma unroll
            for (int fd = 0; fd < 4; ++fd) {
                const int d = fd * 16 + l15;
                const bf16_8 vf = *(const bf16_8*)(Vsm + d * 128 +
                                    ((s * 64 + lg * 16) ^ ((d & 7) << 4)));
                ctx[fd] = __builtin_amdgcn_mfma_f32_16x16x32_bf16(vf, pf, ctx[fd], 0, 0, 0);
            }
        }
    }

    const float inv = 1.f / l_r;
    const size_t qrow = outhead + (size_t)(q0 + l15) * D_;
#pragma unroll
    for (int fd = 0; fd < 4; ++fd) {
        ushort4 o;
        o.x = f2b(ctx[fd][0] * inv);
        o.y = f2b(ctx[fd][1] * inv);
        o.z = f2b(ctx[fd][2] * inv);
        o.w = f2b(ctx[fd][3] * inv);
        *(ushort4*)(ctxb + qrow + fd * 16 + lg * 4) = o;
    }
}

// ---------------------------------------------------------------------------
extern "C" void kernel_launch(void* const* d_in, const int* in_sizes, int n_in,
                              void* d_out, int out_size, void* d_ws, size_t ws_size,
                              hipStream_t stream)
{
    const float* h    = (const float*)d_in[0];
    const float* mask = (const float*)d_in[1];
    const float* Wq   = (const float*)d_in[2];
    const float* bq   = (const float*)d_in[3];
    const float* Wk   = (const float*)d_in[4];
    const float* bk   = (const float*)d_in[5];
    const float* Wv   = (const float*)d_in[6];
    const float* bv   = (const float*)d_in[7];
    const float* Wo   = (const float*)d_in[8];
    const float* bo   = (const float*)d_in[9];
    const float* ln1g = (const float*)d_in[10];
    const float* ln1b = (const float*)d_in[11];
    const float* Wi   = (const float*)d_in[12];
    const float* bi   = (const float*)d_in[13];
    const float* Wout = (const float*)d_in[14];
    const float* bout = (const float*)d_in[15];
    const float* ln2g = (const float*)d_in[16];
    const float* ln2b = (const float*)d_in[17];
    float* out = (float*)d_out;

    char* w = (char*)d_ws;
    const size_t MiB = 1ull << 20;
    // liveness-packed layout, peak 120 MiB:
    u16*   Woutt  = (u16*)(w + 0);             // [0,8)
    float* attnF  = (float*)(w + 8 * MiB);     // [8,24)  == Wo partial 0
    float* woP0   = attnF;
    float* woP1   = (float*)(w + 24 * MiB);    // [24,40) dead before interB
    u16*   interB = (u16*)(w + 24 * MiB);      // [24,56)
    u16*   hb     = (u16*)(w + 56 * MiB);      // [56,64) dead before ffP0
    float* ffP0   = (float*)(w + 56 * MiB);    // [56,72)
    u16*   Wqkvt  = (u16*)(w + 64 * MiB);      // [64,70)
    u16*   Wot    = (u16*)(w + 70 * MiB);      // [70,72)
    float* ffP1   = (float*)(w + 72 * MiB);    // [72,88)
    u16*   Wit    = (u16*)(w + 72 * MiB);      // [72,80) dead before ffP1
    float* ffP2   = (float*)(w + 88 * MiB);    // [88,104)
    u16*   QKVb   = (u16*)(w + 80 * MiB);      // [80,104) dead before ffP1/2
    u16*   ctxb   = (u16*)(w + 104 * MiB);     // [104,112)
    float* ffP3   = (float*)(w + 104 * MiB);   // [104,120)
    u16*   attnB  = (u16*)(w + 112 * MiB);     // [112,120) dead before ffP3

    const dim3 blk(256);
    P4 zp; zp.p[0] = zp.p[1] = zp.p[2] = zp.p[3] = nullptr;

    // prep: h -> bf16; weights -> bf16 [N][K]
    cvt_bf16<<<dim3((M_ * D_ / 4) / 256), blk, 0, stream>>>(
        (const float4*)h, (ushort4*)hb, M_ * D_ / 4);
    T4 t4;
    t4.s[0] = Wq; t4.s[1] = Wk; t4.s[2] = Wv; t4.s[3] = Wo;
    t4.d[0] = Wqkvt; t4.d[1] = Wqkvt + 1024 * 1024;
    t4.d[2] = Wqkvt + 2 * 1024 * 1024; t4.d[3] = Wot;
    transpose4_cvt<<<dim3(32, 32, 4), blk, 0, stream>>>(t4);
    transpose_cvt<<<dim3(128, 32), blk, 0, stream>>>(Wi,   Wit,   D_, I_);
    transpose_cvt<<<dim3(32, 128), blk, 0, stream>>>(Wout, Woutt, I_, D_);

    // fused QKV projection: 256^2 8-phase, grid (12,16)
    gemm256<0><<<dim3(12, 16, 1), dim3(512), 0, stream>>>(
        hb, Wqkvt, bq, bk, bv, QKVb, zp, 3072, 1024, 1024);

    // attention (reads QKV with row-stride 3072)
    attn_mfma<<<dim3(S_ / 64, NH_, B_), blk, 0, stream>>>(
        QKVb, QKVb + 1024, QKVb + 2048, mask, ctxb, 3072);

    // Wo projection, split-K x2 (128^2 path) -> partials; reduce+bias+res(h)+LN1
    P4 woP; woP.p[0] = woP0; woP.p[1] = woP1; woP.p[2] = nullptr; woP.p[3] = nullptr;
    gemm_splitk<<<dim3(8, 32, 2), blk, 0, stream>>>(ctxb, Wot, woP, D_, D_, 512);
    ln_reduce<2><<<dim3(M_), blk, 0, stream>>>(woP, bo, h, ln1g, ln1b, attnF, attnB);

    // FFN1: GELU GEMM, 256^2 8-phase, grid (16,16)
    gemm256<1><<<dim3(16, 16, 1), dim3(512), 0, stream>>>(
        attnB, Wit, bi, nullptr, nullptr, interB, zp, 4096, 1024, 1024);

    // FFN2: 256^2 8-phase split-K x4 -> fp32 partials; reduce+bias+res+LN2 -> out
    P4 ffP; ffP.p[0] = ffP0; ffP.p[1] = ffP1; ffP.p[2] = ffP2; ffP.p[3] = ffP3;
    gemm256<2><<<dim3(4, 16, 4), dim3(512), 0, stream>>>(
        interB, Woutt, nullptr, nullptr, nullptr, nullptr, ffP, 1024, 4096, 4096);
    ln_reduce<4><<<dim3(M_), blk, 0, stream>>>(ffP, bout, attnF, ln2g, ln2b, out, nullptr);
}

// Round 6
// 219.312 us; speedup vs baseline: 11.0792x; 1.0898x over previous
//
#include <hip/hip_runtime.h>
#include <hip/hip_bf16.h>
#include <math.h>

#define B_ 4
#define S_ 1024
#define D_ 1024
#define NH_ 16
#define HD_ 64
#define I_ 4096
#define M_ (B_*S_)

typedef __bf16 bf16_8 __attribute__((ext_vector_type(8)));
typedef float f32x4 __attribute__((ext_vector_type(4)));
typedef unsigned int u32x2 __attribute__((ext_vector_type(2)));
typedef unsigned short u16;

struct P4 { float* p[4]; };
struct T4 { const float* s[4]; u16* d[4]; };

__device__ __forceinline__ u16 f2b(float x) {
    __hip_bfloat16 h = __float2bfloat16(x);
    return *reinterpret_cast<u16*>(&h);
}

__device__ __forceinline__ void gload16(const void* g, void* l) {
    __builtin_amdgcn_global_load_lds(
        (const __attribute__((address_space(1))) void*)g,
        (__attribute__((address_space(3))) void*)l, 16, 0, 0);
}

// ---------------------------------------------------------------------------
// fp32 -> bf16 elementwise convert
// ---------------------------------------------------------------------------
__global__ __launch_bounds__(256) void cvt_bf16(
    const float4* __restrict__ in, ushort4* __restrict__ out, int n4)
{
    int i = blockIdx.x * 256 + threadIdx.x;
    if (i < n4) {
        float4 v = in[i];
        ushort4 o;
        o.x = f2b(v.x); o.y = f2b(v.y); o.z = f2b(v.z); o.w = f2b(v.w);
        out[i] = o;
    }
}

// ---------------------------------------------------------------------------
// W[K][N] fp32 -> Wt[N][K] bf16, 32x32 LDS tile transpose.
// ---------------------------------------------------------------------------
__global__ __launch_bounds__(256) void transpose_cvt(
    const float* __restrict__ in, u16* __restrict__ out, int K, int N)
{
    __shared__ float t[32][33];
    const int tid = threadIdx.x;
    const int k0 = blockIdx.y * 32, n0 = blockIdx.x * 32;
#pragma unroll
    for (int i = 0; i < 4; ++i) {
        int idx = i * 256 + tid;
        int r = idx >> 5, c = idx & 31;
        t[r][c] = in[(size_t)(k0 + r) * N + n0 + c];
    }
    __syncthreads();
    const int rr = tid >> 3, cc0 = (tid & 7) * 4;
    ushort4 o;
    o.x = f2b(t[cc0 + 0][rr]);
    o.y = f2b(t[cc0 + 1][rr]);
    o.z = f2b(t[cc0 + 2][rr]);
    o.w = f2b(t[cc0 + 3][rr]);
    *(ushort4*)(out + (size_t)(n0 + rr) * K + k0 + cc0) = o;
}

// fused 4x (1024x1024) transpose: z selects src/dst
__global__ __launch_bounds__(256) void transpose4_cvt(T4 t4)
{
    __shared__ float t[32][33];
    const int tid = threadIdx.x;
    const int k0 = blockIdx.y * 32, n0 = blockIdx.x * 32;
    const float* in = t4.s[blockIdx.z];
    u16* out = t4.d[blockIdx.z];
#pragma unroll
    for (int i = 0; i < 4; ++i) {
        int idx = i * 256 + tid;
        int r = idx >> 5, c = idx & 31;
        t[r][c] = in[(size_t)(k0 + r) * D_ + n0 + c];
    }
    __syncthreads();
    const int rr = tid >> 3, cc0 = (tid & 7) * 4;
    ushort4 o;
    o.x = f2b(t[cc0 + 0][rr]);
    o.y = f2b(t[cc0 + 1][rr]);
    o.z = f2b(t[cc0 + 2][rr]);
    o.w = f2b(t[cc0 + 3][rr]);
    *(ushort4*)(out + (size_t)(n0 + rr) * D_ + k0 + cc0) = o;
}

// ---------------------------------------------------------------------------
// 256x256 8-phase bf16 MFMA GEMM (HK-style schedule, plain HIP).
// MODE 0: +bias(QKV-select) -> bf16.  MODE 1: +bias+fast GELU -> bf16.
// MODE 2: split-K fp32 partial (blockIdx.z selects chunk+partial buffer).
// ---------------------------------------------------------------------------
#define NT_ 16

template<int MODE>
__global__ __launch_bounds__(512, 2) void gemm256(
    const u16* __restrict__ A, const u16* __restrict__ Bt,
    const float* __restrict__ b0, const float* __restrict__ b1,
    const float* __restrict__ b2,
    u16* __restrict__ outB, P4 parts, int N, int sA, int sB)
{
    __shared__ __align__(16) char sm[131072];

    const int tid  = threadIdx.x;
    const int lane = tid & 63, wid = tid >> 6;
    const int l15  = lane & 15, lg = lane >> 4;
    const int gm   = wid >> 2, gn = wid & 3;
    const int bm   = blockIdx.y * 256, bn = blockIdx.x * 256;
    const int koff = blockIdx.z * 1024;

    const int srow = (wid << 3) + (lane >> 3);
    const int skb  = ((lane & 7) << 4) ^ (((lane >> 3) & 7) << 4);
    const int scol = skb >> 1;
    const int xm   = (l15 & 7) << 4;

    f32x4 acc[8][4];
#pragma unroll
    for (int m = 0; m < 8; ++m)
#pragma unroll
        for (int j = 0; j < 4; ++j) {
            acc[m][j][0] = 0.f; acc[m][j][1] = 0.f;
            acc[m][j][2] = 0.f; acc[m][j][3] = 0.f;
        }

    auto stageA = [&](int v, int h) {
        const u16* src = A + (size_t)(bm + h * 128 + srow) * sA + koff + v * 64 + scol;
        char* dst = sm + ((v & 1) * 65536 + h * 16384 + wid * 1024);
        gload16(src, dst);
        gload16(src + (size_t)64 * sA, dst + 8192);
    };
    auto stageB = [&](int v, int h) {
        const u16* src = Bt + (size_t)(bn + h * 128 + srow) * sB + koff + v * 64 + scol;
        char* dst = sm + ((v & 1) * 65536 + 32768 + h * 16384 + wid * 1024);
        gload16(src, dst);
        gload16(src + (size_t)64 * sB, dst + 8192);
    };

    bf16_8 a[8], bb[2];
    auto loadA = [&](int vb, int s) {
        const char* base = sm + (vb * 65536 + gm * 16384);
#pragma unroll
        for (int m = 0; m < 8; ++m)
            a[m] = *(const bf16_8*)(base + (m * 16 + l15) * 128 +
                                    ((s * 64 + lg * 16) ^ xm));
    };
    auto loadB = [&](int vb, int s, int np) {
        const char* base = sm + (vb * 65536 + 32768 + (gn >> 1) * 16384);
#pragma unroll
        for (int j = 0; j < 2; ++j)
            bb[j] = *(const bf16_8*)(base + ((gn & 1) * 64 + (np * 2 + j) * 16 + l15) * 128 +
                                     ((s * 64 + lg * 16) ^ xm));
    };
    auto mfma16 = [&](int np) {
#pragma unroll
        for (int m = 0; m < 8; ++m)
#pragma unroll
            for (int j = 0; j < 2; ++j)
                acc[m][np * 2 + j] = __builtin_amdgcn_mfma_f32_16x16x32_bf16(
                    a[m], bb[j], acc[m][np * 2 + j], 0, 0, 0);
    };

    // prologue
    stageA(0, 0); stageA(0, 1);
    stageB(0, 0); stageB(0, 1);
    stageA(1, 0); stageA(1, 1);
    asm volatile("s_waitcnt vmcnt(4)" ::: "memory");
    __builtin_amdgcn_sched_barrier(0);
    __builtin_amdgcn_s_barrier();

    for (int v = 0; v < NT_ - 2; ++v) {
        const int vb = v & 1;
        loadA(vb, 0); loadB(vb, 0, 0);
        stageB(v + 1, 0); stageB(v + 1, 1);
        __builtin_amdgcn_s_barrier();
        asm volatile("s_waitcnt lgkmcnt(0)" ::: "memory");
        __builtin_amdgcn_s_setprio(1); mfma16(0); __builtin_amdgcn_s_setprio(0);
        __builtin_amdgcn_s_barrier();
        loadB(vb, 0, 1);
        __builtin_amdgcn_s_barrier();
        asm volatile("s_waitcnt lgkmcnt(0)" ::: "memory");
        __builtin_amdgcn_s_setprio(1); mfma16(1); __builtin_amdgcn_s_setprio(0);
        __builtin_amdgcn_s_barrier();
        loadA(vb, 1); loadB(vb, 1, 0);
        __builtin_amdgcn_s_barrier();
        asm volatile("s_waitcnt lgkmcnt(0)" ::: "memory");
        __builtin_amdgcn_s_setprio(1); mfma16(0); __builtin_amdgcn_s_setprio(0);
        __builtin_amdgcn_s_barrier();
        loadB(vb, 1, 1);
        stageA(v + 2, 0); stageA(v + 2, 1);
        __builtin_amdgcn_s_barrier();
        asm volatile("s_waitcnt lgkmcnt(0)" ::: "memory");
        __builtin_amdgcn_s_setprio(1); mfma16(1); __builtin_amdgcn_s_setprio(0);
        asm volatile("s_waitcnt vmcnt(4)" ::: "memory");
        __builtin_amdgcn_sched_barrier(0);
        __builtin_amdgcn_s_barrier();
    }
    {
        const int vb = (NT_ - 2) & 1;
        loadA(vb, 0); loadB(vb, 0, 0);
        stageB(NT_ - 1, 0); stageB(NT_ - 1, 1);
        __builtin_amdgcn_s_barrier();
        asm volatile("s_waitcnt lgkmcnt(0)" ::: "memory");
        __builtin_amdgcn_s_setprio(1); mfma16(0); __builtin_amdgcn_s_setprio(0);
        __builtin_amdgcn_s_barrier();
        loadB(vb, 0, 1);
        __builtin_amdgcn_s_barrier();
        asm volatile("s_waitcnt lgkmcnt(0)" ::: "memory");
        __builtin_amdgcn_s_setprio(1); mfma16(1); __builtin_amdgcn_s_setprio(0);
        __builtin_amdgcn_s_barrier();
        loadA(vb, 1); loadB(vb, 1, 0);
        __builtin_amdgcn_s_barrier();
        asm volatile("s_waitcnt lgkmcnt(0)" ::: "memory");
        __builtin_amdgcn_s_setprio(1); mfma16(0); __builtin_amdgcn_s_setprio(0);
        __builtin_amdgcn_s_barrier();
        loadB(vb, 1, 1);
        __builtin_amdgcn_s_barrier();
        asm volatile("s_waitcnt lgkmcnt(0)" ::: "memory");
        __builtin_amdgcn_s_setprio(1); mfma16(1); __builtin_amdgcn_s_setprio(0);
        asm volatile("s_waitcnt vmcnt(0)" ::: "memory");
        __builtin_amdgcn_sched_barrier(0);
        __builtin_amdgcn_s_barrier();
    }
    {
        const int vb = (NT_ - 1) & 1;
        loadA(vb, 0); loadB(vb, 0, 0); mfma16(0);
        loadB(vb, 0, 1);               mfma16(1);
        loadA(vb, 1); loadB(vb, 1, 0); mfma16(0);
        loadB(vb, 1, 1);               mfma16(1);
    }

    // epilogue
    if (MODE == 2) {
        float* oP = parts.p[blockIdx.z];
#pragma unroll
        for (int m = 0; m < 8; ++m)
#pragma unroll
            for (int r = 0; r < 4; ++r) {
                const int row = bm + gm * 128 + m * 16 + lg * 4 + r;
#pragma unroll
                for (int j = 0; j < 4; ++j)
                    oP[(size_t)row * N + bn + gn * 64 + j * 16 + l15] = acc[m][j][r];
            }
    } else {
        const int cg = (bn + gn * 64) >> 10;
        const float* bp = (MODE == 0) ? (cg == 0 ? b0 : cg == 1 ? b1 : b2) : b0;
        const int cbase = (MODE == 0) ? ((bn + gn * 64) & 1023) : (bn + gn * 64);
        float bs[4];
#pragma unroll
        for (int j = 0; j < 4; ++j) bs[j] = bp[cbase + j * 16 + l15];
#pragma unroll
        for (int m = 0; m < 8; ++m)
#pragma unroll
            for (int r = 0; r < 4; ++r) {
                const int row = bm + gm * 128 + m * 16 + lg * 4 + r;
#pragma unroll
                for (int j = 0; j < 4; ++j) {
                    float v = acc[m][j][r] + bs[j];
                    if (MODE == 1) {
                        // tanh-form GELU: x*sigmoid(1.5957691x + 0.0713548x^3)
                        const float u = v * (1.5957691216f + 0.0713548163f * v * v);
                        v = __fdividef(v, 1.0f + __expf(-u));
                    }
                    outB[(size_t)row * N + bn + gn * 64 + j * 16 + l15] = f2b(v);
                }
            }
    }
}

// ---------------------------------------------------------------------------
// Split-K bf16 GEMM (m97 128x128 structure) — used for Wo only.
// ---------------------------------------------------------------------------
__global__ __launch_bounds__(256) void gemm_splitk(
    const u16* __restrict__ A, const u16* __restrict__ Bt,
    P4 parts, int N, int K, int kchunk)
{
    __shared__ __align__(16) u16 As[128 * 32];
    __shared__ __align__(16) u16 Bs[128 * 32];

    const int tid  = threadIdx.x;
    const int lane = tid & 63, wid = tid >> 6;
    const int l15  = lane & 15, lg = lane >> 4;
    const int wm   = (wid >> 1) * 64, wn = (wid & 1) * 64;
    const int bm   = blockIdx.y * 128, bn = blockIdx.x * 128;
    const int wbase16 = (tid & ~63) * 16;
    const int kt0 = blockIdx.z * kchunk, kt1 = kt0 + kchunk;
    float* outP = parts.p[blockIdx.z];

    const int r0 = tid >> 2;
    const int c0 = (tid & 3) * 8;

    f32x4 acc[4][4];
#pragma unroll
    for (int i = 0; i < 4; ++i)
#pragma unroll
        for (int j = 0; j < 4; ++j) {
            acc[i][j][0] = 0.f; acc[i][j][1] = 0.f;
            acc[i][j][2] = 0.f; acc[i][j][3] = 0.f;
        }

    for (int kt = kt0; kt < kt1; kt += 32) {
        __syncthreads();
        gload16(A  + (size_t)(bm + r0)      * K + kt + c0, (char*)As + wbase16);
        gload16(A  + (size_t)(bm + r0 + 64) * K + kt + c0, (char*)As + wbase16 + 4096);
        gload16(Bt + (size_t)(bn + r0)      * K + kt + c0, (char*)Bs + wbase16);
        gload16(Bt + (size_t)(bn + r0 + 64) * K + kt + c0, (char*)Bs + wbase16 + 4096);
        __syncthreads();

        bf16_8 af[4], bfr[4];
#pragma unroll
        for (int f = 0; f < 4; ++f) {
            af[f]  = *(const bf16_8*)((const char*)As + (wm + f * 16 + l15) * 64 + lg * 16);
            bfr[f] = *(const bf16_8*)((const char*)Bs + (wn + f * 16 + l15) * 64 + lg * 16);
        }
#pragma unroll
        for (int i = 0; i < 4; ++i)
#pragma unroll
            for (int j = 0; j < 4; ++j)
                acc[i][j] = __builtin_amdgcn_mfma_f32_16x16x32_bf16(
                    af[i], bfr[j], acc[i][j], 0, 0, 0);
    }

#pragma unroll
    for (int i = 0; i < 4; ++i)
#pragma unroll
        for (int r = 0; r < 4; ++r) {
            const int row = bm + wm + i * 16 + lg * 4 + r;
#pragma unroll
            for (int j = 0; j < 4; ++j)
                outP[(size_t)row * N + bn + wn + j * 16 + l15] = acc[i][j][r];
        }
}

// ---------------------------------------------------------------------------
// Reduce NPART partials + bias + residual, then LayerNorm over D=1024.
// ---------------------------------------------------------------------------
template<int NPART>
__global__ __launch_bounds__(256) void ln_reduce(
    P4 parts, const float* __restrict__ bias, const float* __restrict__ res,
    const float* __restrict__ g, const float* __restrict__ b,
    float* __restrict__ O, u16* __restrict__ OB)
{
    const int row = blockIdx.x;
    const int tid = threadIdx.x;
    const size_t off = (size_t)row * D_ + tid * 4;

    float4 v = *(const float4*)(res + off);
    const float4 bi = *(const float4*)(bias + tid * 4);
    v.x += bi.x; v.y += bi.y; v.z += bi.z; v.w += bi.w;
#pragma unroll
    for (int p = 0; p < NPART; ++p) {
        const float4 t = *(const float4*)(parts.p[p] + off);
        v.x += t.x; v.y += t.y; v.z += t.z; v.w += t.w;
    }

    float s  = v.x + v.y + v.z + v.w;
    float sq = v.x * v.x + v.y * v.y + v.z * v.z + v.w * v.w;
#pragma unroll
    for (int o = 32; o; o >>= 1) {
        s  += __shfl_down(s, o);
        sq += __shfl_down(sq, o);
    }
    __shared__ float red[8];
    const int wid = tid >> 6, lane = tid & 63;
    if (lane == 0) { red[wid] = s; red[4 + wid] = sq; }
    __syncthreads();
    const float ts = red[0] + red[1] + red[2] + red[3];
    const float tq = red[4] + red[5] + red[6] + red[7];
    const float mu  = ts * (1.0f / D_);
    const float var = tq * (1.0f / D_) - mu * mu;
    const float rs  = rsqrtf(var + 1e-12f);

    const float4 gv = *(const float4*)(g + tid * 4);
    const float4 bv = *(const float4*)(b + tid * 4);
    float4 o;
    o.x = (v.x - mu) * rs * gv.x + bv.x;
    o.y = (v.y - mu) * rs * gv.y + bv.y;
    o.z = (v.z - mu) * rs * gv.z + bv.z;
    o.w = (v.w - mu) * rs * gv.w + bv.w;
    *(float4*)(O + off) = o;
    if (OB) {
        ushort4 ob;
        ob.x = f2b(o.x); ob.y = f2b(o.y); ob.z = f2b(o.z); ob.w = f2b(o.w);
        *(ushort4*)(OB + off) = ob;
    }
}

// ---------------------------------------------------------------------------
// Flash attention, bf16 MFMA, swapped-QK^T. 8 waves x 16 q = 128 q per block.
// K LDS [64key][64d] XOR-swizzled; V LDS panels [4][64key][16d] read via
// ds_read_b64_tr_b16 (HW transpose). Reg double-buffer of next K/V tile.
// XCD-chunked block swizzle: each XCD owns 8 consecutive (b,h) groups.
// ---------------------------------------------------------------------------
__global__ __launch_bounds__(512) void attn_mfma(
    const u16* __restrict__ Qb, const u16* __restrict__ Kb,
    const u16* __restrict__ Vb, const float* __restrict__ mask,
    u16* __restrict__ ctxb, int qs)
{
    __shared__ __align__(16) char sm[32768];
    char* Ksm = sm;                 // [64 key][64 d], XOR-swizzled
    char* Vsm = sm + 8192;          // [4 d-panel][64 key][16 d], linear

    const int tid  = threadIdx.x;
    const int lane = tid & 63, wid = tid >> 6;
    char* Psm = sm + 16384 + wid * 2048;   // per-wave P[16 q][64 key], swizzled
    const int l15 = lane & 15, lg = lane >> 4;

    // bijective XCD-chunked swizzle (512 blocks, 64 per XCD, qb fastest)
    const int wg  = blockIdx.x;
    const int swz = (wg & 7) * 64 + (wg >> 3);
    const int b   = swz >> 7;
    const int h   = (swz >> 3) & 15;
    const int qb  = swz & 7;

    const int q0 = qb * 128 + wid * 16;
    const size_t inhead  = ((size_t)b * S_) * qs + (size_t)h * 64;
    const size_t outhead = ((size_t)b * S_) * D_ + (size_t)h * 64;

    const u16* Qrow = Qb + inhead + (size_t)(q0 + l15) * qs;
    const bf16_8 qf0 = *(const bf16_8*)(Qrow + lg * 8);
    const bf16_8 qf1 = *(const bf16_8*)(Qrow + 32 + lg * 8);

    f32x4 ctx[4];
#pragma unroll
    for (int i = 0; i < 4; ++i) { ctx[i][0]=0.f; ctx[i][1]=0.f; ctx[i][2]=0.f; ctx[i][3]=0.f; }
    float m_r = -1e30f, l_r = 0.f;

    // staging (512 threads): one 16B K chunk + one 16B V chunk each
    const int skey = tid >> 3;           // 0..63
    const int sd0  = (tid & 7) * 8;      // 0..56
    const int xo_p = (l15 & 7) << 4;
    const int kwoff = skey * 128 + ((sd0 * 2) ^ ((skey & 7) << 4));
    const int vwoff = (sd0 >> 4) * 2048 + skey * 32 + ((sd0 & 8) << 1);

    // per-lane tr-read base: element (key=lg*8, d=l15) of panel 0
    const __attribute__((address_space(3))) char* vtr =
        (const __attribute__((address_space(3))) char*)(Vsm + lg * 256 + l15 * 2);

    // prefetch tile 0 into registers
    bf16_8 kreg = *(const bf16_8*)(Kb + inhead + (size_t)skey * qs + sd0);
    bf16_8 vreg = *(const bf16_8*)(Vb + inhead + (size_t)skey * qs + sd0);

    for (int t = 0; t < S_ / 64; ++t) {
        __syncthreads();
        *(bf16_8*)(Ksm + kwoff) = kreg;
        *(bf16_8*)(Vsm + vwoff) = vreg;
        __syncthreads();
        if (t < S_ / 64 - 1) {
            const size_t noff = inhead + (size_t)((t + 1) * 64 + skey) * qs + sd0;
            kreg = *(const bf16_8*)(Kb + noff);
            vreg = *(const bf16_8*)(Vb + noff);
        }

        // S^T = K·Q^T: lane holds 16 scores for q=l15 (keys kf*16+lg*4+r)
        f32x4 sc[4];
#pragma unroll
        for (int kf = 0; kf < 4; ++kf) {
            const int key = kf * 16 + l15;
            f32x4 a; a[0]=0.f; a[1]=0.f; a[2]=0.f; a[3]=0.f;
            const bf16_8 kA = *(const bf16_8*)(Ksm + key * 128 + ((lg * 16)      ^ xo_p));
            a = __builtin_amdgcn_mfma_f32_16x16x32_bf16(kA, qf0, a, 0, 0, 0);
            const bf16_8 kB = *(const bf16_8*)(Ksm + key * 128 + ((64 + lg * 16) ^ xo_p));
            a = __builtin_amdgcn_mfma_f32_16x16x32_bf16(kB, qf1, a, 0, 0, 0);
            sc[kf] = a;
        }

        // lane-local softmax
        float p[16];
        float tmax = -1e30f;
#pragma unroll
        for (int kf = 0; kf < 4; ++kf) {
            const float4 mk = *(const float4*)(mask + (size_t)b * S_ + t * 64 + kf * 16 + lg * 4);
#pragma unroll
            for (int r = 0; r < 4; ++r) {
                const float mkr = (r == 0) ? mk.x : (r == 1) ? mk.y : (r == 2) ? mk.z : mk.w;
                p[kf * 4 + r] = sc[kf][r] * 0.125f + mkr;
                tmax = fmaxf(tmax, p[kf * 4 + r]);
            }
        }
        tmax = fmaxf(tmax, __shfl_xor(tmax, 16));
        tmax = fmaxf(tmax, __shfl_xor(tmax, 32));

        const float mnew = fmaxf(m_r, tmax);
        const float scl  = __expf(m_r - mnew);
        m_r = mnew;

        float psum = 0.f;
#pragma unroll
        for (int i = 0; i < 16; ++i) {
            p[i] = __expf(p[i] - mnew);
            psum += p[i];
        }
        psum += __shfl_xor(psum, 16);
        psum += __shfl_xor(psum, 32);
        l_r = l_r * scl + psum;

#pragma unroll
        for (int fd = 0; fd < 4; ++fd)
#pragma unroll
            for (int r = 0; r < 4; ++r) ctx[fd][r] *= scl;

        // store P row q=l15 (8 x ushort2, swizzled)
#pragma unroll
        for (int kf = 0; kf < 4; ++kf)
#pragma unroll
            for (int rr = 0; rr < 2; ++rr) {
                ushort2 wv;
                wv.x = f2b(p[kf * 4 + 2 * rr]);
                wv.y = f2b(p[kf * 4 + 2 * rr + 1]);
                *(ushort2*)(Psm + l15 * 128 +
                            (((kf * 16 + lg * 4 + 2 * rr) * 2) ^ xo_p)) = wv;
            }
        asm volatile("s_waitcnt lgkmcnt(0)" ::: "memory");

        // ctx^T += V^T · P^T; V fragments via HW transpose-read
#pragma unroll
        for (int s = 0; s < 2; ++s) {
            const bf16_8 pf = *(const bf16_8*)(Psm + l15 * 128 +
                                ((s * 64 + lg * 16) ^ xo_p));
            const __attribute__((address_space(3))) char* a3 = vtr + s * 1024;
            u32x2 r0, r1, r2, r3, r4, r5, r6, r7;
            asm volatile(
                "ds_read_b64_tr_b16 %0, %8 offset:0\n\t"
                "ds_read_b64_tr_b16 %1, %8 offset:128\n\t"
                "ds_read_b64_tr_b16 %2, %8 offset:2048\n\t"
                "ds_read_b64_tr_b16 %3, %8 offset:2176\n\t"
                "ds_read_b64_tr_b16 %4, %8 offset:4096\n\t"
                "ds_read_b64_tr_b16 %5, %8 offset:4224\n\t"
                "ds_read_b64_tr_b16 %6, %8 offset:6144\n\t"
                "ds_read_b64_tr_b16 %7, %8 offset:6272\n\t"
                "s_waitcnt lgkmcnt(0)"
                : "=&v"(r0), "=&v"(r1), "=&v"(r2), "=&v"(r3),
                  "=&v"(r4), "=&v"(r5), "=&v"(r6), "=&v"(r7)
                : "v"(a3));
            union Cv { unsigned u[4]; bf16_8 v; };
            Cv c0; c0.u[0] = r0.x; c0.u[1] = r0.y; c0.u[2] = r1.x; c0.u[3] = r1.y;
            Cv c1; c1.u[0] = r2.x; c1.u[1] = r2.y; c1.u[2] = r3.x; c1.u[3] = r3.y;
            Cv c2; c2.u[0] = r4.x; c2.u[1] = r4.y; c2.u[2] = r5.x; c2.u[3] = r5.y;
            Cv c3; c3.u[0] = r6.x; c3.u[1] = r6.y; c3.u[2] = r7.x; c3.u[3] = r7.y;
            ctx[0] = __builtin_amdgcn_mfma_f32_16x16x32_bf16(c0.v, pf, ctx[0], 0, 0, 0);
            ctx[1] = __builtin_amdgcn_mfma_f32_16x16x32_bf16(c1.v, pf, ctx[1], 0, 0, 0);
            ctx[2] = __builtin_amdgcn_mfma_f32_16x16x32_bf16(c2.v, pf, ctx[2], 0, 0, 0);
            ctx[3] = __builtin_amdgcn_mfma_f32_16x16x32_bf16(c3.v, pf, ctx[3], 0, 0, 0);
        }
    }

    // normalize + write ctx^T: lane q=l15, d = fd*16+lg*4+r
    const float inv = 1.f / l_r;
    const size_t qrow = outhead + (size_t)(q0 + l15) * D_;
#pragma unroll
    for (int fd = 0; fd < 4; ++fd) {
        ushort4 o;
        o.x = f2b(ctx[fd][0] * inv);
        o.y = f2b(ctx[fd][1] * inv);
        o.z = f2b(ctx[fd][2] * inv);
        o.w = f2b(ctx[fd][3] * inv);
        *(ushort4*)(ctxb + qrow + fd * 16 + lg * 4) = o;
    }
}

// ---------------------------------------------------------------------------
extern "C" void kernel_launch(void* const* d_in, const int* in_sizes, int n_in,
                              void* d_out, int out_size, void* d_ws, size_t ws_size,
                              hipStream_t stream)
{
    const float* h    = (const float*)d_in[0];
    const float* mask = (const float*)d_in[1];
    const float* Wq   = (const float*)d_in[2];
    const float* bq   = (const float*)d_in[3];
    const float* Wk   = (const float*)d_in[4];
    const float* bk   = (const float*)d_in[5];
    const float* Wv   = (const float*)d_in[6];
    const float* bv   = (const float*)d_in[7];
    const float* Wo   = (const float*)d_in[8];
    const float* bo   = (const float*)d_in[9];
    const float* ln1g = (const float*)d_in[10];
    const float* ln1b = (const float*)d_in[11];
    const float* Wi   = (const float*)d_in[12];
    const float* bi   = (const float*)d_in[13];
    const float* Wout = (const float*)d_in[14];
    const float* bout = (const float*)d_in[15];
    const float* ln2g = (const float*)d_in[16];
    const float* ln2b = (const float*)d_in[17];
    float* out = (float*)d_out;

    char* w = (char*)d_ws;
    const size_t MiB = 1ull << 20;
    u16*   Woutt  = (u16*)(w + 0);             // [0,8)
    float* attnF  = (float*)(w + 8 * MiB);     // [8,24)  == Wo partial 0
    float* woP0   = attnF;
    float* woP1   = (float*)(w + 24 * MiB);    // [24,40) dead before interB
    u16*   interB = (u16*)(w + 24 * MiB);      // [24,56)
    u16*   hb     = (u16*)(w + 56 * MiB);      // [56,64) dead before ffP0
    float* ffP0   = (float*)(w + 56 * MiB);    // [56,72)
    u16*   Wqkvt  = (u16*)(w + 64 * MiB);      // [64,70)
    u16*   Wot    = (u16*)(w + 70 * MiB);      // [70,72)
    float* ffP1   = (float*)(w + 72 * MiB);    // [72,88)
    u16*   Wit    = (u16*)(w + 72 * MiB);      // [72,80) dead before ffP1
    float* ffP2   = (float*)(w + 88 * MiB);    // [88,104)
    u16*   QKVb   = (u16*)(w + 80 * MiB);      // [80,104) dead before ffP1/2
    u16*   ctxb   = (u16*)(w + 104 * MiB);     // [104,112)
    float* ffP3   = (float*)(w + 104 * MiB);   // [104,120)
    u16*   attnB  = (u16*)(w + 112 * MiB);     // [112,120) dead before ffP3

    const dim3 blk(256);
    P4 zp; zp.p[0] = zp.p[1] = zp.p[2] = zp.p[3] = nullptr;

    // prep: h -> bf16; weights -> bf16 [N][K]
    cvt_bf16<<<dim3((M_ * D_ / 4) / 256), blk, 0, stream>>>(
        (const float4*)h, (ushort4*)hb, M_ * D_ / 4);
    T4 t4;
    t4.s[0] = Wq; t4.s[1] = Wk; t4.s[2] = Wv; t4.s[3] = Wo;
    t4.d[0] = Wqkvt; t4.d[1] = Wqkvt + 1024 * 1024;
    t4.d[2] = Wqkvt + 2 * 1024 * 1024; t4.d[3] = Wot;
    transpose4_cvt<<<dim3(32, 32, 4), blk, 0, stream>>>(t4);
    transpose_cvt<<<dim3(128, 32), blk, 0, stream>>>(Wi,   Wit,   D_, I_);
    transpose_cvt<<<dim3(32, 128), blk, 0, stream>>>(Wout, Woutt, I_, D_);

    // fused QKV projection: 256^2 8-phase, grid (12,16)
    gemm256<0><<<dim3(12, 16, 1), dim3(512), 0, stream>>>(
        hb, Wqkvt, bq, bk, bv, QKVb, zp, 3072, 1024, 1024);

    // attention: 512 blocks x 512 threads, XCD-chunked swizzle
    attn_mfma<<<dim3(512), dim3(512), 0, stream>>>(
        QKVb, QKVb + 1024, QKVb + 2048, mask, ctxb, 3072);

    // Wo projection, split-K x2 -> partials; reduce+bias+res(h)+LN1
    P4 woP; woP.p[0] = woP0; woP.p[1] = woP1; woP.p[2] = nullptr; woP.p[3] = nullptr;
    gemm_splitk<<<dim3(8, 32, 2), blk, 0, stream>>>(ctxb, Wot, woP, D_, D_, 512);
    ln_reduce<2><<<dim3(M_), blk, 0, stream>>>(woP, bo, h, ln1g, ln1b, attnF, attnB);

    // FFN1: fast-GELU GEMM, 256^2 8-phase, grid (16,16)
    gemm256<1><<<dim3(16, 16, 1), dim3(512), 0, stream>>>(
        attnB, Wit, bi, nullptr, nullptr, interB, zp, 4096, 1024, 1024);

    // FFN2: 256^2 8-phase split-K x4 -> fp32 partials; reduce+bias+res+LN2 -> out
    P4 ffP; ffP.p[0] = ffP0; ffP.p[1] = ffP1; ffP.p[2] = ffP2; ffP.p[3] = ffP3;
    gemm256<2><<<dim3(4, 16, 4), dim3(512), 0, stream>>>(
        interB, Woutt, nullptr, nullptr, nullptr, nullptr, ffP, 1024, 4096, 4096);
    ln_reduce<4><<<dim3(M_), blk, 0, stream>>>(ffP, bout, attnF, ln2g, ln2b, out, nullptr);
}

// Round 7
// 213.741 us; speedup vs baseline: 11.3680x; 1.0261x over previous
//
#include <hip/hip_runtime.h>
#include <hip/hip_bf16.h>
#include <math.h>

#define B_ 4
#define S_ 1024
#define D_ 1024
#define NH_ 16
#define HD_ 64
#define I_ 4096
#define M_ (B_*S_)

typedef __bf16 bf16_8 __attribute__((ext_vector_type(8)));
typedef float f32x4 __attribute__((ext_vector_type(4)));
typedef unsigned int u32x2 __attribute__((ext_vector_type(2)));
typedef unsigned short u16;

struct PB { u16* p[4]; };
struct T4 { const float* s[4]; u16* d[4]; };

__device__ __forceinline__ u16 f2b(float x) {
    __hip_bfloat16 h = __float2bfloat16(x);
    return *reinterpret_cast<u16*>(&h);
}
__device__ __forceinline__ float b2f(u16 x) {
    return __uint_as_float(((unsigned)x) << 16);
}

__device__ __forceinline__ void gload16(const void* g, void* l) {
    __builtin_amdgcn_global_load_lds(
        (const __attribute__((address_space(1))) void*)g,
        (__attribute__((address_space(3))) void*)l, 16, 0, 0);
}

// exact-GELU via A&S 7.1.26 erf poly (max abs err 1.5e-7, no systematic bias)
__device__ __forceinline__ float gelu_f(float v) {
    const float z  = v * 0.70710678118654752f;
    const float az = fabsf(z);
    const float t  = __fdividef(1.0f, 1.0f + 0.3275911f * az);
    const float poly = t * (0.254829592f + t * (-0.284496736f +
                       t * (1.421413741f + t * (-1.453152027f + t * 1.061405429f))));
    const float erfa = 1.0f - poly * __expf(-z * z);
    const float erfv = copysignf(erfa, z);
    return 0.5f * v * (1.0f + erfv);
}

// ---------------------------------------------------------------------------
// fp32 -> bf16 elementwise convert
// ---------------------------------------------------------------------------
__global__ __launch_bounds__(256) void cvt_bf16(
    const float4* __restrict__ in, ushort4* __restrict__ out, int n4)
{
    int i = blockIdx.x * 256 + threadIdx.x;
    if (i < n4) {
        float4 v = in[i];
        ushort4 o;
        o.x = f2b(v.x); o.y = f2b(v.y); o.z = f2b(v.z); o.w = f2b(v.w);
        out[i] = o;
    }
}

// ---------------------------------------------------------------------------
// W[K][N] fp32 -> Wt[N][K] bf16, 32x32 LDS tile transpose.
// ---------------------------------------------------------------------------
__global__ __launch_bounds__(256) void transpose_cvt(
    const float* __restrict__ in, u16* __restrict__ out, int K, int N)
{
    __shared__ float t[32][33];
    const int tid = threadIdx.x;
    const int k0 = blockIdx.y * 32, n0 = blockIdx.x * 32;
#pragma unroll
    for (int i = 0; i < 4; ++i) {
        int idx = i * 256 + tid;
        int r = idx >> 5, c = idx & 31;
        t[r][c] = in[(size_t)(k0 + r) * N + n0 + c];
    }
    __syncthreads();
    const int rr = tid >> 3, cc0 = (tid & 7) * 4;
    ushort4 o;
    o.x = f2b(t[cc0 + 0][rr]);
    o.y = f2b(t[cc0 + 1][rr]);
    o.z = f2b(t[cc0 + 2][rr]);
    o.w = f2b(t[cc0 + 3][rr]);
    *(ushort4*)(out + (size_t)(n0 + rr) * K + k0 + cc0) = o;
}

// fused 4x (1024x1024) transpose: z selects src/dst
__global__ __launch_bounds__(256) void transpose4_cvt(T4 t4)
{
    __shared__ float t[32][33];
    const int tid = threadIdx.x;
    const int k0 = blockIdx.y * 32, n0 = blockIdx.x * 32;
    const float* in = t4.s[blockIdx.z];
    u16* out = t4.d[blockIdx.z];
#pragma unroll
    for (int i = 0; i < 4; ++i) {
        int idx = i * 256 + tid;
        int r = idx >> 5, c = idx & 31;
        t[r][c] = in[(size_t)(k0 + r) * D_ + n0 + c];
    }
    __syncthreads();
    const int rr = tid >> 3, cc0 = (tid & 7) * 4;
    ushort4 o;
    o.x = f2b(t[cc0 + 0][rr]);
    o.y = f2b(t[cc0 + 1][rr]);
    o.z = f2b(t[cc0 + 2][rr]);
    o.w = f2b(t[cc0 + 3][rr]);
    *(ushort4*)(out + (size_t)(n0 + rr) * D_ + k0 + cc0) = o;
}

// ---------------------------------------------------------------------------
// 256x256 8-phase bf16 MFMA GEMM. Compile-time strides SA/SB and N (NN).
// MODE 0: +bias(QKV-select) -> bf16.  MODE 1: +bias+erf-GELU -> bf16.
// MODE 2: split-K bf16 partial (blockIdx.z selects chunk+partial buffer).
// ---------------------------------------------------------------------------
#define NT_ 16

template<int MODE, int SA, int SB, int NN>
__global__ __launch_bounds__(512, 2) void gemm256(
    const u16* __restrict__ A, const u16* __restrict__ Bt,
    const float* __restrict__ b0, const float* __restrict__ b1,
    const float* __restrict__ b2,
    u16* __restrict__ outB, PB parts)
{
    __shared__ __align__(16) char sm[131072];

    const int tid  = threadIdx.x;
    const int lane = tid & 63, wid = tid >> 6;
    const int l15  = lane & 15, lg = lane >> 4;
    const int gm   = wid >> 2, gn = wid & 3;
    const int bm   = blockIdx.y * 256, bn = blockIdx.x * 256;
    const int koff = (MODE == 2) ? blockIdx.z * 1024 : 0;

    const int srow = (wid << 3) + (lane >> 3);
    const int skb  = ((lane & 7) << 4) ^ (((lane >> 3) & 7) << 4);
    const int scol = skb >> 1;
    const int xm   = (l15 & 7) << 4;

    f32x4 acc[8][4];
#pragma unroll
    for (int m = 0; m < 8; ++m)
#pragma unroll
        for (int j = 0; j < 4; ++j) {
            acc[m][j][0] = 0.f; acc[m][j][1] = 0.f;
            acc[m][j][2] = 0.f; acc[m][j][3] = 0.f;
        }

    auto stageA = [&](int v, int h) {
        const u16* src = A + (size_t)(bm + h * 128 + srow) * SA + koff + v * 64 + scol;
        char* dst = sm + ((v & 1) * 65536 + h * 16384 + wid * 1024);
        gload16(src, dst);
        gload16(src + (size_t)64 * SA, dst + 8192);
    };
    auto stageB = [&](int v, int h) {
        const u16* src = Bt + (size_t)(bn + h * 128 + srow) * SB + koff + v * 64 + scol;
        char* dst = sm + ((v & 1) * 65536 + 32768 + h * 16384 + wid * 1024);
        gload16(src, dst);
        gload16(src + (size_t)64 * SB, dst + 8192);
    };

    bf16_8 a[8], bb[2];
    auto loadA = [&](int vb, int s) {
        const char* base = sm + (vb * 65536 + gm * 16384);
#pragma unroll
        for (int m = 0; m < 8; ++m)
            a[m] = *(const bf16_8*)(base + (m * 16 + l15) * 128 +
                                    ((s * 64 + lg * 16) ^ xm));
    };
    auto loadB = [&](int vb, int s, int np) {
        const char* base = sm + (vb * 65536 + 32768 + (gn >> 1) * 16384);
#pragma unroll
        for (int j = 0; j < 2; ++j)
            bb[j] = *(const bf16_8*)(base + ((gn & 1) * 64 + (np * 2 + j) * 16 + l15) * 128 +
                                     ((s * 64 + lg * 16) ^ xm));
    };
    auto mfma16 = [&](int np) {
#pragma unroll
        for (int m = 0; m < 8; ++m)
#pragma unroll
            for (int j = 0; j < 2; ++j)
                acc[m][np * 2 + j] = __builtin_amdgcn_mfma_f32_16x16x32_bf16(
                    a[m], bb[j], acc[m][np * 2 + j], 0, 0, 0);
    };

    // prologue
    stageA(0, 0); stageA(0, 1);
    stageB(0, 0); stageB(0, 1);
    stageA(1, 0); stageA(1, 1);
    asm volatile("s_waitcnt vmcnt(4)" ::: "memory");
    __builtin_amdgcn_sched_barrier(0);
    __builtin_amdgcn_s_barrier();

    for (int v = 0; v < NT_ - 2; ++v) {
        const int vb = v & 1;
        loadA(vb, 0); loadB(vb, 0, 0);
        stageB(v + 1, 0); stageB(v + 1, 1);
        __builtin_amdgcn_s_barrier();
        asm volatile("s_waitcnt lgkmcnt(0)" ::: "memory");
        __builtin_amdgcn_s_setprio(1); mfma16(0); __builtin_amdgcn_s_setprio(0);
        __builtin_amdgcn_s_barrier();
        loadB(vb, 0, 1);
        __builtin_amdgcn_s_barrier();
        asm volatile("s_waitcnt lgkmcnt(0)" ::: "memory");
        __builtin_amdgcn_s_setprio(1); mfma16(1); __builtin_amdgcn_s_setprio(0);
        __builtin_amdgcn_s_barrier();
        loadA(vb, 1); loadB(vb, 1, 0);
        __builtin_amdgcn_s_barrier();
        asm volatile("s_waitcnt lgkmcnt(0)" ::: "memory");
        __builtin_amdgcn_s_setprio(1); mfma16(0); __builtin_amdgcn_s_setprio(0);
        __builtin_amdgcn_s_barrier();
        loadB(vb, 1, 1);
        stageA(v + 2, 0); stageA(v + 2, 1);
        __builtin_amdgcn_s_barrier();
        asm volatile("s_waitcnt lgkmcnt(0)" ::: "memory");
        __builtin_amdgcn_s_setprio(1); mfma16(1); __builtin_amdgcn_s_setprio(0);
        asm volatile("s_waitcnt vmcnt(4)" ::: "memory");
        __builtin_amdgcn_sched_barrier(0);
        __builtin_amdgcn_s_barrier();
    }
    {
        const int vb = (NT_ - 2) & 1;
        loadA(vb, 0); loadB(vb, 0, 0);
        stageB(NT_ - 1, 0); stageB(NT_ - 1, 1);
        __builtin_amdgcn_s_barrier();
        asm volatile("s_waitcnt lgkmcnt(0)" ::: "memory");
        __builtin_amdgcn_s_setprio(1); mfma16(0); __builtin_amdgcn_s_setprio(0);
        __builtin_amdgcn_s_barrier();
        loadB(vb, 0, 1);
        __builtin_amdgcn_s_barrier();
        asm volatile("s_waitcnt lgkmcnt(0)" ::: "memory");
        __builtin_amdgcn_s_setprio(1); mfma16(1); __builtin_amdgcn_s_setprio(0);
        __builtin_amdgcn_s_barrier();
        loadA(vb, 1); loadB(vb, 1, 0);
        __builtin_amdgcn_s_barrier();
        asm volatile("s_waitcnt lgkmcnt(0)" ::: "memory");
        __builtin_amdgcn_s_setprio(1); mfma16(0); __builtin_amdgcn_s_setprio(0);
        __builtin_amdgcn_s_barrier();
        loadB(vb, 1, 1);
        __builtin_amdgcn_s_barrier();
        asm volatile("s_waitcnt lgkmcnt(0)" ::: "memory");
        __builtin_amdgcn_s_setprio(1); mfma16(1); __builtin_amdgcn_s_setprio(0);
        asm volatile("s_waitcnt vmcnt(0)" ::: "memory");
        __builtin_amdgcn_sched_barrier(0);
        __builtin_amdgcn_s_barrier();
    }
    {
        const int vb = (NT_ - 1) & 1;
        loadA(vb, 0); loadB(vb, 0, 0); mfma16(0);
        loadB(vb, 0, 1);               mfma16(1);
        loadA(vb, 1); loadB(vb, 1, 0); mfma16(0);
        loadB(vb, 1, 1);               mfma16(1);
    }

    // epilogue
    if (MODE == 2) {
        u16* oP = parts.p[blockIdx.z];
#pragma unroll
        for (int m = 0; m < 8; ++m)
#pragma unroll
            for (int r = 0; r < 4; ++r) {
                const int row = bm + gm * 128 + m * 16 + lg * 4 + r;
#pragma unroll
                for (int j = 0; j < 4; ++j)
                    oP[(size_t)row * NN + bn + gn * 64 + j * 16 + l15] = f2b(acc[m][j][r]);
            }
    } else {
        const int cg = (bn + gn * 64) >> 10;
        const float* bp = (MODE == 0) ? (cg == 0 ? b0 : cg == 1 ? b1 : b2) : b0;
        const int cbase = (MODE == 0) ? ((bn + gn * 64) & 1023) : (bn + gn * 64);
        float bs[4];
#pragma unroll
        for (int j = 0; j < 4; ++j) bs[j] = bp[cbase + j * 16 + l15];
#pragma unroll
        for (int m = 0; m < 8; ++m)
#pragma unroll
            for (int r = 0; r < 4; ++r) {
                const int row = bm + gm * 128 + m * 16 + lg * 4 + r;
#pragma unroll
                for (int j = 0; j < 4; ++j) {
                    float v = acc[m][j][r] + bs[j];
                    if (MODE == 1) v = gelu_f(v);
                    outB[(size_t)row * NN + bn + gn * 64 + j * 16 + l15] = f2b(v);
                }
            }
    }
}

// ---------------------------------------------------------------------------
// Split-K bf16 GEMM (m97 128x128 structure) — Wo only; bf16 partials.
// ---------------------------------------------------------------------------
__global__ __launch_bounds__(256) void gemm_splitk(
    const u16* __restrict__ A, const u16* __restrict__ Bt,
    PB parts, int N, int K, int kchunk)
{
    __shared__ __align__(16) u16 As[128 * 32];
    __shared__ __align__(16) u16 Bs[128 * 32];

    const int tid  = threadIdx.x;
    const int lane = tid & 63, wid = tid >> 6;
    const int l15  = lane & 15, lg = lane >> 4;
    const int wm   = (wid >> 1) * 64, wn = (wid & 1) * 64;
    const int bm   = blockIdx.y * 128, bn = blockIdx.x * 128;
    const int wbase16 = (tid & ~63) * 16;
    const int kt0 = blockIdx.z * kchunk, kt1 = kt0 + kchunk;
    u16* outP = parts.p[blockIdx.z];

    const int r0 = tid >> 2;
    const int c0 = (tid & 3) * 8;

    f32x4 acc[4][4];
#pragma unroll
    for (int i = 0; i < 4; ++i)
#pragma unroll
        for (int j = 0; j < 4; ++j) {
            acc[i][j][0] = 0.f; acc[i][j][1] = 0.f;
            acc[i][j][2] = 0.f; acc[i][j][3] = 0.f;
        }

    for (int kt = kt0; kt < kt1; kt += 32) {
        __syncthreads();
        gload16(A  + (size_t)(bm + r0)      * K + kt + c0, (char*)As + wbase16);
        gload16(A  + (size_t)(bm + r0 + 64) * K + kt + c0, (char*)As + wbase16 + 4096);
        gload16(Bt + (size_t)(bn + r0)      * K + kt + c0, (char*)Bs + wbase16);
        gload16(Bt + (size_t)(bn + r0 + 64) * K + kt + c0, (char*)Bs + wbase16 + 4096);
        __syncthreads();

        bf16_8 af[4], bfr[4];
#pragma unroll
        for (int f = 0; f < 4; ++f) {
            af[f]  = *(const bf16_8*)((const char*)As + (wm + f * 16 + l15) * 64 + lg * 16);
            bfr[f] = *(const bf16_8*)((const char*)Bs + (wn + f * 16 + l15) * 64 + lg * 16);
        }
#pragma unroll
        for (int i = 0; i < 4; ++i)
#pragma unroll
            for (int j = 0; j < 4; ++j)
                acc[i][j] = __builtin_amdgcn_mfma_f32_16x16x32_bf16(
                    af[i], bfr[j], acc[i][j], 0, 0, 0);
    }

#pragma unroll
    for (int i = 0; i < 4; ++i)
#pragma unroll
        for (int r = 0; r < 4; ++r) {
            const int row = bm + wm + i * 16 + lg * 4 + r;
#pragma unroll
            for (int j = 0; j < 4; ++j)
                outP[(size_t)row * N + bn + wn + j * 16 + l15] = f2b(acc[i][j][r]);
        }
}

// ---------------------------------------------------------------------------
// Reduce NPART bf16 partials + bias + residual, then LayerNorm over D=1024.
// ---------------------------------------------------------------------------
template<int NPART>
__global__ __launch_bounds__(256) void ln_reduce(
    PB parts, const float* __restrict__ bias, const float* __restrict__ res,
    const float* __restrict__ g, const float* __restrict__ b,
    float* __restrict__ O, u16* __restrict__ OB)
{
    const int row = blockIdx.x;
    const int tid = threadIdx.x;
    const size_t off = (size_t)row * D_ + tid * 4;

    float4 v = *(const float4*)(res + off);
    const float4 bi = *(const float4*)(bias + tid * 4);
    v.x += bi.x; v.y += bi.y; v.z += bi.z; v.w += bi.w;
#pragma unroll
    for (int p = 0; p < NPART; ++p) {
        const ushort4 t = *(const ushort4*)(parts.p[p] + off);
        v.x += b2f(t.x); v.y += b2f(t.y); v.z += b2f(t.z); v.w += b2f(t.w);
    }

    float s  = v.x + v.y + v.z + v.w;
    float sq = v.x * v.x + v.y * v.y + v.z * v.z + v.w * v.w;
#pragma unroll
    for (int o = 32; o; o >>= 1) {
        s  += __shfl_down(s, o);
        sq += __shfl_down(sq, o);
    }
    __shared__ float red[8];
    const int wid = tid >> 6, lane = tid & 63;
    if (lane == 0) { red[wid] = s; red[4 + wid] = sq; }
    __syncthreads();
    const float ts = red[0] + red[1] + red[2] + red[3];
    const float tq = red[4] + red[5] + red[6] + red[7];
    const float mu  = ts * (1.0f / D_);
    const float var = tq * (1.0f / D_) - mu * mu;
    const float rs  = rsqrtf(var + 1e-12f);

    const float4 gv = *(const float4*)(g + tid * 4);
    const float4 bv = *(const float4*)(b + tid * 4);
    float4 o;
    o.x = (v.x - mu) * rs * gv.x + bv.x;
    o.y = (v.y - mu) * rs * gv.y + bv.y;
    o.z = (v.z - mu) * rs * gv.z + bv.z;
    o.w = (v.w - mu) * rs * gv.w + bv.w;
    *(float4*)(O + off) = o;
    if (OB) {
        ushort4 ob;
        ob.x = f2b(o.x); ob.y = f2b(o.y); ob.z = f2b(o.z); ob.w = f2b(o.w);
        *(ushort4*)(OB + off) = ob;
    }
}

// ---------------------------------------------------------------------------
// Flash attention, bf16 MFMA, swapped-QK^T. Unchanged from R6.
// ---------------------------------------------------------------------------
__global__ __launch_bounds__(512) void attn_mfma(
    const u16* __restrict__ Qb, const u16* __restrict__ Kb,
    const u16* __restrict__ Vb, const float* __restrict__ mask,
    u16* __restrict__ ctxb, int qs)
{
    __shared__ __align__(16) char sm[32768];
    char* Ksm = sm;
    char* Vsm = sm + 8192;

    const int tid  = threadIdx.x;
    const int lane = tid & 63, wid = tid >> 6;
    char* Psm = sm + 16384 + wid * 2048;
    const int l15 = lane & 15, lg = lane >> 4;

    const int wg  = blockIdx.x;
    const int swz = (wg & 7) * 64 + (wg >> 3);
    const int b   = swz >> 7;
    const int h   = (swz >> 3) & 15;
    const int qb  = swz & 7;

    const int q0 = qb * 128 + wid * 16;
    const size_t inhead  = ((size_t)b * S_) * qs + (size_t)h * 64;
    const size_t outhead = ((size_t)b * S_) * D_ + (size_t)h * 64;

    const u16* Qrow = Qb + inhead + (size_t)(q0 + l15) * qs;
    const bf16_8 qf0 = *(const bf16_8*)(Qrow + lg * 8);
    const bf16_8 qf1 = *(const bf16_8*)(Qrow + 32 + lg * 8);

    f32x4 ctx[4];
#pragma unroll
    for (int i = 0; i < 4; ++i) { ctx[i][0]=0.f; ctx[i][1]=0.f; ctx[i][2]=0.f; ctx[i][3]=0.f; }
    float m_r = -1e30f, l_r = 0.f;

    const int skey = tid >> 3;
    const int sd0  = (tid & 7) * 8;
    const int xo_p = (l15 & 7) << 4;
    const int kwoff = skey * 128 + ((sd0 * 2) ^ ((skey & 7) << 4));
    const int vwoff = (sd0 >> 4) * 2048 + skey * 32 + ((sd0 & 8) << 1);

    const __attribute__((address_space(3))) char* vtr =
        (const __attribute__((address_space(3))) char*)(Vsm + lg * 256 + l15 * 2);

    bf16_8 kreg = *(const bf16_8*)(Kb + inhead + (size_t)skey * qs + sd0);
    bf16_8 vreg = *(const bf16_8*)(Vb + inhead + (size_t)skey * qs + sd0);

    for (int t = 0; t < S_ / 64; ++t) {
        __syncthreads();
        *(bf16_8*)(Ksm + kwoff) = kreg;
        *(bf16_8*)(Vsm + vwoff) = vreg;
        __syncthreads();
        if (t < S_ / 64 - 1) {
            const size_t noff = inhead + (size_t)((t + 1) * 64 + skey) * qs + sd0;
            kreg = *(const bf16_8*)(Kb + noff);
            vreg = *(const bf16_8*)(Vb + noff);
        }

        f32x4 sc[4];
#pragma unroll
        for (int kf = 0; kf < 4; ++kf) {
            const int key = kf * 16 + l15;
            f32x4 a; a[0]=0.f; a[1]=0.f; a[2]=0.f; a[3]=0.f;
            const bf16_8 kA = *(const bf16_8*)(Ksm + key * 128 + ((lg * 16)      ^ xo_p));
            a = __builtin_amdgcn_mfma_f32_16x16x32_bf16(kA, qf0, a, 0, 0, 0);
            const bf16_8 kB = *(const bf16_8*)(Ksm + key * 128 + ((64 + lg * 16) ^ xo_p));
            a = __builtin_amdgcn_mfma_f32_16x16x32_bf16(kB, qf1, a, 0, 0, 0);
            sc[kf] = a;
        }

        float p[16];
        float tmax = -1e30f;
#pragma unroll
        for (int kf = 0; kf < 4; ++kf) {
            const float4 mk = *(const float4*)(mask + (size_t)b * S_ + t * 64 + kf * 16 + lg * 4);
#pragma unroll
            for (int r = 0; r < 4; ++r) {
                const float mkr = (r == 0) ? mk.x : (r == 1) ? mk.y : (r == 2) ? mk.z : mk.w;
                p[kf * 4 + r] = sc[kf][r] * 0.125f + mkr;
                tmax = fmaxf(tmax, p[kf * 4 + r]);
            }
        }
        tmax = fmaxf(tmax, __shfl_xor(tmax, 16));
        tmax = fmaxf(tmax, __shfl_xor(tmax, 32));

        const float mnew = fmaxf(m_r, tmax);
        const float scl  = __expf(m_r - mnew);
        m_r = mnew;

        float psum = 0.f;
#pragma unroll
        for (int i = 0; i < 16; ++i) {
            p[i] = __expf(p[i] - mnew);
            psum += p[i];
        }
        psum += __shfl_xor(psum, 16);
        psum += __shfl_xor(psum, 32);
        l_r = l_r * scl + psum;

#pragma unroll
        for (int fd = 0; fd < 4; ++fd)
#pragma unroll
            for (int r = 0; r < 4; ++r) ctx[fd][r] *= scl;

#pragma unroll
        for (int kf = 0; kf < 4; ++kf)
#pragma unroll
            for (int rr = 0; rr < 2; ++rr) {
                ushort2 wv;
                wv.x = f2b(p[kf * 4 + 2 * rr]);
                wv.y = f2b(p[kf * 4 + 2 * rr + 1]);
                *(ushort2*)(Psm + l15 * 128 +
                            (((kf * 16 + lg * 4 + 2 * rr) * 2) ^ xo_p)) = wv;
            }
        asm volatile("s_waitcnt lgkmcnt(0)" ::: "memory");

#pragma unroll
        for (int s = 0; s < 2; ++s) {
            const bf16_8 pf = *(const bf16_8*)(Psm + l15 * 128 +
                                ((s * 64 + lg * 16) ^ xo_p));
            const __attribute__((address_space(3))) char* a3 = vtr + s * 1024;
            u32x2 r0, r1, r2, r3, r4, r5, r6, r7;
            asm volatile(
                "ds_read_b64_tr_b16 %0, %8 offset:0\n\t"
                "ds_read_b64_tr_b16 %1, %8 offset:128\n\t"
                "ds_read_b64_tr_b16 %2, %8 offset:2048\n\t"
                "ds_read_b64_tr_b16 %3, %8 offset:2176\n\t"
                "ds_read_b64_tr_b16 %4, %8 offset:4096\n\t"
                "ds_read_b64_tr_b16 %5, %8 offset:4224\n\t"
                "ds_read_b64_tr_b16 %6, %8 offset:6144\n\t"
                "ds_read_b64_tr_b16 %7, %8 offset:6272\n\t"
                "s_waitcnt lgkmcnt(0)"
                : "=&v"(r0), "=&v"(r1), "=&v"(r2), "=&v"(r3),
                  "=&v"(r4), "=&v"(r5), "=&v"(r6), "=&v"(r7)
                : "v"(a3));
            union Cv { unsigned u[4]; bf16_8 v; };
            Cv c0; c0.u[0] = r0.x; c0.u[1] = r0.y; c0.u[2] = r1.x; c0.u[3] = r1.y;
            Cv c1; c1.u[0] = r2.x; c1.u[1] = r2.y; c1.u[2] = r3.x; c1.u[3] = r3.y;
            Cv c2; c2.u[0] = r4.x; c2.u[1] = r4.y; c2.u[2] = r5.x; c2.u[3] = r5.y;
            Cv c3; c3.u[0] = r6.x; c3.u[1] = r6.y; c3.u[2] = r7.x; c3.u[3] = r7.y;
            ctx[0] = __builtin_amdgcn_mfma_f32_16x16x32_bf16(c0.v, pf, ctx[0], 0, 0, 0);
            ctx[1] = __builtin_amdgcn_mfma_f32_16x16x32_bf16(c1.v, pf, ctx[1], 0, 0, 0);
            ctx[2] = __builtin_amdgcn_mfma_f32_16x16x32_bf16(c2.v, pf, ctx[2], 0, 0, 0);
            ctx[3] = __builtin_amdgcn_mfma_f32_16x16x32_bf16(c3.v, pf, ctx[3], 0, 0, 0);
        }
    }

    const float inv = 1.f / l_r;
    const size_t qrow = outhead + (size_t)(q0 + l15) * D_;
#pragma unroll
    for (int fd = 0; fd < 4; ++fd) {
        ushort4 o;
        o.x = f2b(ctx[fd][0] * inv);
        o.y = f2b(ctx[fd][1] * inv);
        o.z = f2b(ctx[fd][2] * inv);
        o.w = f2b(ctx[fd][3] * inv);
        *(ushort4*)(ctxb + qrow + fd * 16 + lg * 4) = o;
    }
}

// ---------------------------------------------------------------------------
extern "C" void kernel_launch(void* const* d_in, const int* in_sizes, int n_in,
                              void* d_out, int out_size, void* d_ws, size_t ws_size,
                              hipStream_t stream)
{
    const float* h    = (const float*)d_in[0];
    const float* mask = (const float*)d_in[1];
    const float* Wq   = (const float*)d_in[2];
    const float* bq   = (const float*)d_in[3];
    const float* Wk   = (const float*)d_in[4];
    const float* bk   = (const float*)d_in[5];
    const float* Wv   = (const float*)d_in[6];
    const float* bv   = (const float*)d_in[7];
    const float* Wo   = (const float*)d_in[8];
    const float* bo   = (const float*)d_in[9];
    const float* ln1g = (const float*)d_in[10];
    const float* ln1b = (const float*)d_in[11];
    const float* Wi   = (const float*)d_in[12];
    const float* bi   = (const float*)d_in[13];
    const float* Wout = (const float*)d_in[14];
    const float* bout = (const float*)d_in[15];
    const float* ln2g = (const float*)d_in[16];
    const float* ln2b = (const float*)d_in[17];
    float* out = (float*)d_out;

    char* w = (char*)d_ws;
    const size_t MiB = 1ull << 20;
    // liveness-packed layout, peak 104 MiB:
    u16*   Woutt  = (u16*)(w + 0);             // [0,8)   live to FFN2
    u16*   Wit    = (u16*)(w + 8 * MiB);       // [8,16)  live to FFN1
    u16*   hb     = (u16*)(w + 16 * MiB);      // [16,24) dead after QKV
    u16*   woP0   = (u16*)(w + 16 * MiB);      //   then Wo partial 0 (bf16)
    u16*   ffP1   = (u16*)(w + 16 * MiB);      //   then FFN2 partial 1
    u16*   Wqkvt  = (u16*)(w + 24 * MiB);      // [24,30) dead after QKV
    u16*   ffP2   = (u16*)(w + 24 * MiB);      //   then FFN2 partial 2
    u16*   Wot    = (u16*)(w + 30 * MiB);      // [30,32) dead after Wo-splitk
    u16*   QKVb   = (u16*)(w + 32 * MiB);      // [32,56) dead after attn
    u16*   woP1   = (u16*)(w + 32 * MiB);      //   then Wo partial 1
    u16*   ffP3   = (u16*)(w + 32 * MiB);      //   then FFN2 partial 3
    float* attnF  = (float*)(w + 40 * MiB);    // [40,56) live to ln2
    u16*   attnB  = (u16*)(w + 56 * MiB);      // [56,64) dead after FFN1
    u16*   interB = (u16*)(w + 64 * MiB);      // [64,96) dead after FFN2
    u16*   ctxb   = (u16*)(w + 96 * MiB);      // [96,104) dead after Wo-splitk
    u16*   ffP0   = (u16*)(w + 96 * MiB);      //   then FFN2 partial 0

    const dim3 blk(256);
    PB zp; zp.p[0] = zp.p[1] = zp.p[2] = zp.p[3] = nullptr;

    // prep: h -> bf16; weights -> bf16 [N][K]
    cvt_bf16<<<dim3((M_ * D_ / 4) / 256), blk, 0, stream>>>(
        (const float4*)h, (ushort4*)hb, M_ * D_ / 4);
    T4 t4;
    t4.s[0] = Wq; t4.s[1] = Wk; t4.s[2] = Wv; t4.s[3] = Wo;
    t4.d[0] = Wqkvt; t4.d[1] = Wqkvt + 1024 * 1024;
    t4.d[2] = Wqkvt + 2 * 1024 * 1024; t4.d[3] = Wot;
    transpose4_cvt<<<dim3(32, 32, 4), blk, 0, stream>>>(t4);
    transpose_cvt<<<dim3(128, 32), blk, 0, stream>>>(Wi,   Wit,   D_, I_);
    transpose_cvt<<<dim3(32, 128), blk, 0, stream>>>(Wout, Woutt, I_, D_);

    // fused QKV projection: 256^2 8-phase, grid (12,16)
    gemm256<0, 1024, 1024, 3072><<<dim3(12, 16, 1), dim3(512), 0, stream>>>(
        hb, Wqkvt, bq, bk, bv, QKVb, zp);

    // attention: 512 blocks x 512 threads, XCD-chunked swizzle
    attn_mfma<<<dim3(512), dim3(512), 0, stream>>>(
        QKVb, QKVb + 1024, QKVb + 2048, mask, ctxb, 3072);

    // Wo projection, split-K x2 -> bf16 partials; reduce+bias+res(h)+LN1
    PB woP; woP.p[0] = woP0; woP.p[1] = woP1; woP.p[2] = nullptr; woP.p[3] = nullptr;
    gemm_splitk<<<dim3(8, 32, 2), blk, 0, stream>>>(ctxb, Wot, woP, D_, D_, 512);
    ln_reduce<2><<<dim3(M_), blk, 0, stream>>>(woP, bo, h, ln1g, ln1b, attnF, attnB);

    // FFN1: erf-GELU GEMM, 256^2 8-phase, grid (16,16)
    gemm256<1, 1024, 1024, 4096><<<dim3(16, 16, 1), dim3(512), 0, stream>>>(
        attnB, Wit, bi, nullptr, nullptr, interB, zp);

    // FFN2: 256^2 8-phase split-K x4 -> bf16 partials; reduce+bias+res+LN2 -> out
    PB ffP; ffP.p[0] = ffP0; ffP.p[1] = ffP1; ffP.p[2] = ffP2; ffP.p[3] = ffP3;
    gemm256<2, 4096, 4096, 1024><<<dim3(4, 16, 4), dim3(512), 0, stream>>>(
        interB, Woutt, nullptr, nullptr, nullptr, nullptr, ffP);
    ln_reduce<4><<<dim3(M_), blk, 0, stream>>>(ffP, bout, attnF, ln2g, ln2b, out, nullptr);
}

// Round 8
// 212.042 us; speedup vs baseline: 11.4591x; 1.0080x over previous
//
#include <hip/hip_runtime.h>
#include <hip/hip_bf16.h>
#include <math.h>

#define B_ 4
#define S_ 1024
#define D_ 1024
#define NH_ 16
#define HD_ 64
#define I_ 4096
#define M_ (B_*S_)

typedef __bf16 bf16_8 __attribute__((ext_vector_type(8)));
typedef float f32x4 __attribute__((ext_vector_type(4)));
typedef unsigned int u32x2 __attribute__((ext_vector_type(2)));
typedef unsigned short u16;

struct PB { u16* p[4]; };
struct Prep {
    const float* s[6]; u16* d[6]; int K[6]; int N[6];
    const float4* cin; ushort4* cout;
};

__device__ __forceinline__ u16 f2b(float x) {
    __hip_bfloat16 h = __float2bfloat16(x);
    return *reinterpret_cast<u16*>(&h);
}
__device__ __forceinline__ float b2f(u16 x) {
    return __uint_as_float(((unsigned)x) << 16);
}

__device__ __forceinline__ void gload16(const void* g, void* l) {
    __builtin_amdgcn_global_load_lds(
        (const __attribute__((address_space(1))) void*)g,
        (__attribute__((address_space(3))) void*)l, 16, 0, 0);
}

// exact-GELU via A&S 7.1.26 erf poly (max abs err 1.5e-7, no systematic bias)
__device__ __forceinline__ float gelu_f(float v) {
    const float z  = v * 0.70710678118654752f;
    const float az = fabsf(z);
    const float t  = __fdividef(1.0f, 1.0f + 0.3275911f * az);
    const float poly = t * (0.254829592f + t * (-0.284496736f +
                       t * (1.421413741f + t * (-1.453152027f + t * 1.061405429f))));
    const float erfa = 1.0f - poly * __expf(-z * z);
    const float erfv = copysignf(erfa, z);
    return 0.5f * v * (1.0f + erfv);
}

// ---------------------------------------------------------------------------
// Fused prep: z=0..5 -> W[K][N] fp32 -> Wt[N][K] bf16 transposes;
// z=6 -> h fp32 -> bf16 convert. Grid (128, 32, 7); surplus tiles early-exit.
// ---------------------------------------------------------------------------
__global__ __launch_bounds__(256) void prep_all(Prep p)
{
    const int tid = threadIdx.x;
    const int z = blockIdx.z;
    const int tile = blockIdx.y * 128 + blockIdx.x;

    if (z == 6) {
        const int i = tile * 256 + tid;           // 4096 tiles x 256 = 1M float4
        float4 v = p.cin[i];
        ushort4 o;
        o.x = f2b(v.x); o.y = f2b(v.y); o.z = f2b(v.z); o.w = f2b(v.w);
        p.cout[i] = o;
        return;
    }

    const int K = p.K[z], N = p.N[z];
    const int ntile = N >> 5;
    if (tile >= (K >> 5) * ntile) return;
    const int k0 = (tile / ntile) * 32, n0 = (tile % ntile) * 32;
    const float* in = p.s[z];
    u16* out = p.d[z];

    __shared__ float t[32][33];
#pragma unroll
    for (int i = 0; i < 4; ++i) {
        int idx = i * 256 + tid;
        int r = idx >> 5, c = idx & 31;
        t[r][c] = in[(size_t)(k0 + r) * N + n0 + c];
    }
    __syncthreads();
    const int rr = tid >> 3, cc0 = (tid & 7) * 4;
    ushort4 o;
    o.x = f2b(t[cc0 + 0][rr]);
    o.y = f2b(t[cc0 + 1][rr]);
    o.z = f2b(t[cc0 + 2][rr]);
    o.w = f2b(t[cc0 + 3][rr]);
    *(ushort4*)(out + (size_t)(n0 + rr) * K + k0 + cc0) = o;
}

// ---------------------------------------------------------------------------
// 256x256 8-phase bf16 MFMA GEMM (runtime strides — R6 codegen).
// MODE 0: +bias(QKV-select) -> bf16.  MODE 1: +bias+erf-GELU -> bf16.
// MODE 2: split-K bf16 partial (blockIdx.z selects chunk+partial buffer).
// ---------------------------------------------------------------------------
#define NT_ 16

template<int MODE>
__global__ __launch_bounds__(512, 2) void gemm256(
    const u16* __restrict__ A, const u16* __restrict__ Bt,
    const float* __restrict__ b0, const float* __restrict__ b1,
    const float* __restrict__ b2,
    u16* __restrict__ outB, PB parts, int N, int sA, int sB)
{
    __shared__ __align__(16) char sm[131072];

    const int tid  = threadIdx.x;
    const int lane = tid & 63, wid = tid >> 6;
    const int l15  = lane & 15, lg = lane >> 4;
    const int gm   = wid >> 2, gn = wid & 3;
    const int bm   = blockIdx.y * 256, bn = blockIdx.x * 256;
    const int koff = (MODE == 2) ? blockIdx.z * 1024 : 0;

    const int srow = (wid << 3) + (lane >> 3);
    const int skb  = ((lane & 7) << 4) ^ (((lane >> 3) & 7) << 4);
    const int scol = skb >> 1;
    const int xm   = (l15 & 7) << 4;

    f32x4 acc[8][4];
#pragma unroll
    for (int m = 0; m < 8; ++m)
#pragma unroll
        for (int j = 0; j < 4; ++j) {
            acc[m][j][0] = 0.f; acc[m][j][1] = 0.f;
            acc[m][j][2] = 0.f; acc[m][j][3] = 0.f;
        }

    auto stageA = [&](int v, int h) {
        const u16* src = A + (size_t)(bm + h * 128 + srow) * sA + koff + v * 64 + scol;
        char* dst = sm + ((v & 1) * 65536 + h * 16384 + wid * 1024);
        gload16(src, dst);
        gload16(src + (size_t)64 * sA, dst + 8192);
    };
    auto stageB = [&](int v, int h) {
        const u16* src = Bt + (size_t)(bn + h * 128 + srow) * sB + koff + v * 64 + scol;
        char* dst = sm + ((v & 1) * 65536 + 32768 + h * 16384 + wid * 1024);
        gload16(src, dst);
        gload16(src + (size_t)64 * sB, dst + 8192);
    };

    bf16_8 a[8], bb[2];
    auto loadA = [&](int vb, int s) {
        const char* base = sm + (vb * 65536 + gm * 16384);
#pragma unroll
        for (int m = 0; m < 8; ++m)
            a[m] = *(const bf16_8*)(base + (m * 16 + l15) * 128 +
                                    ((s * 64 + lg * 16) ^ xm));
    };
    auto loadB = [&](int vb, int s, int np) {
        const char* base = sm + (vb * 65536 + 32768 + (gn >> 1) * 16384);
#pragma unroll
        for (int j = 0; j < 2; ++j)
            bb[j] = *(const bf16_8*)(base + ((gn & 1) * 64 + (np * 2 + j) * 16 + l15) * 128 +
                                     ((s * 64 + lg * 16) ^ xm));
    };
    auto mfma16 = [&](int np) {
#pragma unroll
        for (int m = 0; m < 8; ++m)
#pragma unroll
            for (int j = 0; j < 2; ++j)
                acc[m][np * 2 + j] = __builtin_amdgcn_mfma_f32_16x16x32_bf16(
                    a[m], bb[j], acc[m][np * 2 + j], 0, 0, 0);
    };

    // prologue
    stageA(0, 0); stageA(0, 1);
    stageB(0, 0); stageB(0, 1);
    stageA(1, 0); stageA(1, 1);
    asm volatile("s_waitcnt vmcnt(4)" ::: "memory");
    __builtin_amdgcn_sched_barrier(0);
    __builtin_amdgcn_s_barrier();

    for (int v = 0; v < NT_ - 2; ++v) {
        const int vb = v & 1;
        loadA(vb, 0); loadB(vb, 0, 0);
        stageB(v + 1, 0); stageB(v + 1, 1);
        __builtin_amdgcn_s_barrier();
        asm volatile("s_waitcnt lgkmcnt(0)" ::: "memory");
        __builtin_amdgcn_s_setprio(1); mfma16(0); __builtin_amdgcn_s_setprio(0);
        __builtin_amdgcn_s_barrier();
        loadB(vb, 0, 1);
        __builtin_amdgcn_s_barrier();
        asm volatile("s_waitcnt lgkmcnt(0)" ::: "memory");
        __builtin_amdgcn_s_setprio(1); mfma16(1); __builtin_amdgcn_s_setprio(0);
        __builtin_amdgcn_s_barrier();
        loadA(vb, 1); loadB(vb, 1, 0);
        __builtin_amdgcn_s_barrier();
        asm volatile("s_waitcnt lgkmcnt(0)" ::: "memory");
        __builtin_amdgcn_s_setprio(1); mfma16(0); __builtin_amdgcn_s_setprio(0);
        __builtin_amdgcn_s_barrier();
        loadB(vb, 1, 1);
        stageA(v + 2, 0); stageA(v + 2, 1);
        __builtin_amdgcn_s_barrier();
        asm volatile("s_waitcnt lgkmcnt(0)" ::: "memory");
        __builtin_amdgcn_s_setprio(1); mfma16(1); __builtin_amdgcn_s_setprio(0);
        asm volatile("s_waitcnt vmcnt(4)" ::: "memory");
        __builtin_amdgcn_sched_barrier(0);
        __builtin_amdgcn_s_barrier();
    }
    {
        const int vb = (NT_ - 2) & 1;
        loadA(vb, 0); loadB(vb, 0, 0);
        stageB(NT_ - 1, 0); stageB(NT_ - 1, 1);
        __builtin_amdgcn_s_barrier();
        asm volatile("s_waitcnt lgkmcnt(0)" ::: "memory");
        __builtin_amdgcn_s_setprio(1); mfma16(0); __builtin_amdgcn_s_setprio(0);
        __builtin_amdgcn_s_barrier();
        loadB(vb, 0, 1);
        __builtin_amdgcn_s_barrier();
        asm volatile("s_waitcnt lgkmcnt(0)" ::: "memory");
        __builtin_amdgcn_s_setprio(1); mfma16(1); __builtin_amdgcn_s_setprio(0);
        __builtin_amdgcn_s_barrier();
        loadA(vb, 1); loadB(vb, 1, 0);
        __builtin_amdgcn_s_barrier();
        asm volatile("s_waitcnt lgkmcnt(0)" ::: "memory");
        __builtin_amdgcn_s_setprio(1); mfma16(0); __builtin_amdgcn_s_setprio(0);
        __builtin_amdgcn_s_barrier();
        loadB(vb, 1, 1);
        __builtin_amdgcn_s_barrier();
        asm volatile("s_waitcnt lgkmcnt(0)" ::: "memory");
        __builtin_amdgcn_s_setprio(1); mfma16(1); __builtin_amdgcn_s_setprio(0);
        asm volatile("s_waitcnt vmcnt(0)" ::: "memory");
        __builtin_amdgcn_sched_barrier(0);
        __builtin_amdgcn_s_barrier();
    }
    {
        const int vb = (NT_ - 1) & 1;
        loadA(vb, 0); loadB(vb, 0, 0); mfma16(0);
        loadB(vb, 0, 1);               mfma16(1);
        loadA(vb, 1); loadB(vb, 1, 0); mfma16(0);
        loadB(vb, 1, 1);               mfma16(1);
    }

    // epilogue
    if (MODE == 2) {
        u16* oP = parts.p[blockIdx.z];
#pragma unroll
        for (int m = 0; m < 8; ++m)
#pragma unroll
            for (int r = 0; r < 4; ++r) {
                const int row = bm + gm * 128 + m * 16 + lg * 4 + r;
#pragma unroll
                for (int j = 0; j < 4; ++j)
                    oP[(size_t)row * N + bn + gn * 64 + j * 16 + l15] = f2b(acc[m][j][r]);
            }
    } else {
        const int cg = (bn + gn * 64) >> 10;
        const float* bp = (MODE == 0) ? (cg == 0 ? b0 : cg == 1 ? b1 : b2) : b0;
        const int cbase = (MODE == 0) ? ((bn + gn * 64) & 1023) : (bn + gn * 64);
        float bs[4];
#pragma unroll
        for (int j = 0; j < 4; ++j) bs[j] = bp[cbase + j * 16 + l15];
#pragma unroll
        for (int m = 0; m < 8; ++m)
#pragma unroll
            for (int r = 0; r < 4; ++r) {
                const int row = bm + gm * 128 + m * 16 + lg * 4 + r;
#pragma unroll
                for (int j = 0; j < 4; ++j) {
                    float v = acc[m][j][r] + bs[j];
                    if (MODE == 1) v = gelu_f(v);
                    outB[(size_t)row * N + bn + gn * 64 + j * 16 + l15] = f2b(v);
                }
            }
    }
}

// ---------------------------------------------------------------------------
// Split-K bf16 GEMM (m97 128x128 structure) — Wo only; bf16 partials.
// ---------------------------------------------------------------------------
__global__ __launch_bounds__(256) void gemm_splitk(
    const u16* __restrict__ A, const u16* __restrict__ Bt,
    PB parts, int N, int K, int kchunk)
{
    __shared__ __align__(16) u16 As[128 * 32];
    __shared__ __align__(16) u16 Bs[128 * 32];

    const int tid  = threadIdx.x;
    const int lane = tid & 63, wid = tid >> 6;
    const int l15  = lane & 15, lg = lane >> 4;
    const int wm   = (wid >> 1) * 64, wn = (wid & 1) * 64;
    const int bm   = blockIdx.y * 128, bn = blockIdx.x * 128;
    const int wbase16 = (tid & ~63) * 16;
    const int kt0 = blockIdx.z * kchunk, kt1 = kt0 + kchunk;
    u16* outP = parts.p[blockIdx.z];

    const int r0 = tid >> 2;
    const int c0 = (tid & 3) * 8;

    f32x4 acc[4][4];
#pragma unroll
    for (int i = 0; i < 4; ++i)
#pragma unroll
        for (int j = 0; j < 4; ++j) {
            acc[i][j][0] = 0.f; acc[i][j][1] = 0.f;
            acc[i][j][2] = 0.f; acc[i][j][3] = 0.f;
        }

    for (int kt = kt0; kt < kt1; kt += 32) {
        __syncthreads();
        gload16(A  + (size_t)(bm + r0)      * K + kt + c0, (char*)As + wbase16);
        gload16(A  + (size_t)(bm + r0 + 64) * K + kt + c0, (char*)As + wbase16 + 4096);
        gload16(Bt + (size_t)(bn + r0)      * K + kt + c0, (char*)Bs + wbase16);
        gload16(Bt + (size_t)(bn + r0 + 64) * K + kt + c0, (char*)Bs + wbase16 + 4096);
        __syncthreads();

        bf16_8 af[4], bfr[4];
#pragma unroll
        for (int f = 0; f < 4; ++f) {
            af[f]  = *(const bf16_8*)((const char*)As + (wm + f * 16 + l15) * 64 + lg * 16);
            bfr[f] = *(const bf16_8*)((const char*)Bs + (wn + f * 16 + l15) * 64 + lg * 16);
        }
#pragma unroll
        for (int i = 0; i < 4; ++i)
#pragma unroll
            for (int j = 0; j < 4; ++j)
                acc[i][j] = __builtin_amdgcn_mfma_f32_16x16x32_bf16(
                    af[i], bfr[j], acc[i][j], 0, 0, 0);
    }

#pragma unroll
    for (int i = 0; i < 4; ++i)
#pragma unroll
        for (int r = 0; r < 4; ++r) {
            const int row = bm + wm + i * 16 + lg * 4 + r;
#pragma unroll
            for (int j = 0; j < 4; ++j)
                outP[(size_t)row * N + bn + wn + j * 16 + l15] = f2b(acc[i][j][r]);
        }
}

// ---------------------------------------------------------------------------
// Reduce NPART bf16 partials + bias + residual, then LayerNorm over D=1024.
// ---------------------------------------------------------------------------
template<int NPART>
__global__ __launch_bounds__(256) void ln_reduce(
    PB parts, const float* __restrict__ bias, const float* __restrict__ res,
    const float* __restrict__ g, const float* __restrict__ b,
    float* __restrict__ O, u16* __restrict__ OB)
{
    const int row = blockIdx.x;
    const int tid = threadIdx.x;
    const size_t off = (size_t)row * D_ + tid * 4;

    float4 v = *(const float4*)(res + off);
    const float4 bi = *(const float4*)(bias + tid * 4);
    v.x += bi.x; v.y += bi.y; v.z += bi.z; v.w += bi.w;
#pragma unroll
    for (int p = 0; p < NPART; ++p) {
        const ushort4 t = *(const ushort4*)(parts.p[p] + off);
        v.x += b2f(t.x); v.y += b2f(t.y); v.z += b2f(t.z); v.w += b2f(t.w);
    }

    float s  = v.x + v.y + v.z + v.w;
    float sq = v.x * v.x + v.y * v.y + v.z * v.z + v.w * v.w;
#pragma unroll
    for (int o = 32; o; o >>= 1) {
        s  += __shfl_down(s, o);
        sq += __shfl_down(sq, o);
    }
    __shared__ float red[8];
    const int wid = tid >> 6, lane = tid & 63;
    if (lane == 0) { red[wid] = s; red[4 + wid] = sq; }
    __syncthreads();
    const float ts = red[0] + red[1] + red[2] + red[3];
    const float tq = red[4] + red[5] + red[6] + red[7];
    const float mu  = ts * (1.0f / D_);
    const float var = tq * (1.0f / D_) - mu * mu;
    const float rs  = rsqrtf(var + 1e-12f);

    const float4 gv = *(const float4*)(g + tid * 4);
    const float4 bv = *(const float4*)(b + tid * 4);
    float4 o;
    o.x = (v.x - mu) * rs * gv.x + bv.x;
    o.y = (v.y - mu) * rs * gv.y + bv.y;
    o.z = (v.z - mu) * rs * gv.z + bv.z;
    o.w = (v.w - mu) * rs * gv.w + bv.w;
    *(float4*)(O + off) = o;
    if (OB) {
        ushort4 ob;
        ob.x = f2b(o.x); ob.y = f2b(o.y); ob.z = f2b(o.z); ob.w = f2b(o.w);
        *(ushort4*)(OB + off) = ob;
    }
}

// ---------------------------------------------------------------------------
// Flash attention, bf16 MFMA, swapped-QK^T. Unchanged from R6.
// ---------------------------------------------------------------------------
__global__ __launch_bounds__(512) void attn_mfma(
    const u16* __restrict__ Qb, const u16* __restrict__ Kb,
    const u16* __restrict__ Vb, const float* __restrict__ mask,
    u16* __restrict__ ctxb, int qs)
{
    __shared__ __align__(16) char sm[32768];
    char* Ksm = sm;
    char* Vsm = sm + 8192;

    const int tid  = threadIdx.x;
    const int lane = tid & 63, wid = tid >> 6;
    char* Psm = sm + 16384 + wid * 2048;
    const int l15 = lane & 15, lg = lane >> 4;

    const int wg  = blockIdx.x;
    const int swz = (wg & 7) * 64 + (wg >> 3);
    const int b   = swz >> 7;
    const int h   = (swz >> 3) & 15;
    const int qb  = swz & 7;

    const int q0 = qb * 128 + wid * 16;
    const size_t inhead  = ((size_t)b * S_) * qs + (size_t)h * 64;
    const size_t outhead = ((size_t)b * S_) * D_ + (size_t)h * 64;

    const u16* Qrow = Qb + inhead + (size_t)(q0 + l15) * qs;
    const bf16_8 qf0 = *(const bf16_8*)(Qrow + lg * 8);
    const bf16_8 qf1 = *(const bf16_8*)(Qrow + 32 + lg * 8);

    f32x4 ctx[4];
#pragma unroll
    for (int i = 0; i < 4; ++i) { ctx[i][0]=0.f; ctx[i][1]=0.f; ctx[i][2]=0.f; ctx[i][3]=0.f; }
    float m_r = -1e30f, l_r = 0.f;

    const int skey = tid >> 3;
    const int sd0  = (tid & 7) * 8;
    const int xo_p = (l15 & 7) << 4;
    const int kwoff = skey * 128 + ((sd0 * 2) ^ ((skey & 7) << 4));
    const int vwoff = (sd0 >> 4) * 2048 + skey * 32 + ((sd0 & 8) << 1);

    const __attribute__((address_space(3))) char* vtr =
        (const __attribute__((address_space(3))) char*)(Vsm + lg * 256 + l15 * 2);

    bf16_8 kreg = *(const bf16_8*)(Kb + inhead + (size_t)skey * qs + sd0);
    bf16_8 vreg = *(const bf16_8*)(Vb + inhead + (size_t)skey * qs + sd0);

    for (int t = 0; t < S_ / 64; ++t) {
        __syncthreads();
        *(bf16_8*)(Ksm + kwoff) = kreg;
        *(bf16_8*)(Vsm + vwoff) = vreg;
        __syncthreads();
        if (t < S_ / 64 - 1) {
            const size_t noff = inhead + (size_t)((t + 1) * 64 + skey) * qs + sd0;
            kreg = *(const bf16_8*)(Kb + noff);
            vreg = *(const bf16_8*)(Vb + noff);
        }

        f32x4 sc[4];
#pragma unroll
        for (int kf = 0; kf < 4; ++kf) {
            const int key = kf * 16 + l15;
            f32x4 a; a[0]=0.f; a[1]=0.f; a[2]=0.f; a[3]=0.f;
            const bf16_8 kA = *(const bf16_8*)(Ksm + key * 128 + ((lg * 16)      ^ xo_p));
            a = __builtin_amdgcn_mfma_f32_16x16x32_bf16(kA, qf0, a, 0, 0, 0);
            const bf16_8 kB = *(const bf16_8*)(Ksm + key * 128 + ((64 + lg * 16) ^ xo_p));
            a = __builtin_amdgcn_mfma_f32_16x16x32_bf16(kB, qf1, a, 0, 0, 0);
            sc[kf] = a;
        }

        float p[16];
        float tmax = -1e30f;
#pragma unroll
        for (int kf = 0; kf < 4; ++kf) {
            const float4 mk = *(const float4*)(mask + (size_t)b * S_ + t * 64 + kf * 16 + lg * 4);
#pragma unroll
            for (int r = 0; r < 4; ++r) {
                const float mkr = (r == 0) ? mk.x : (r == 1) ? mk.y : (r == 2) ? mk.z : mk.w;
                p[kf * 4 + r] = sc[kf][r] * 0.125f + mkr;
                tmax = fmaxf(tmax, p[kf * 4 + r]);
            }
        }
        tmax = fmaxf(tmax, __shfl_xor(tmax, 16));
        tmax = fmaxf(tmax, __shfl_xor(tmax, 32));

        const float mnew = fmaxf(m_r, tmax);
        const float scl  = __expf(m_r - mnew);
        m_r = mnew;

        float psum = 0.f;
#pragma unroll
        for (int i = 0; i < 16; ++i) {
            p[i] = __expf(p[i] - mnew);
            psum += p[i];
        }
        psum += __shfl_xor(psum, 16);
        psum += __shfl_xor(psum, 32);
        l_r = l_r * scl + psum;

#pragma unroll
        for (int fd = 0; fd < 4; ++fd)
#pragma unroll
            for (int r = 0; r < 4; ++r) ctx[fd][r] *= scl;

#pragma unroll
        for (int kf = 0; kf < 4; ++kf)
#pragma unroll
            for (int rr = 0; rr < 2; ++rr) {
                ushort2 wv;
                wv.x = f2b(p[kf * 4 + 2 * rr]);
                wv.y = f2b(p[kf * 4 + 2 * rr + 1]);
                *(ushort2*)(Psm + l15 * 128 +
                            (((kf * 16 + lg * 4 + 2 * rr) * 2) ^ xo_p)) = wv;
            }
        asm volatile("s_waitcnt lgkmcnt(0)" ::: "memory");

#pragma unroll
        for (int s = 0; s < 2; ++s) {
            const bf16_8 pf = *(const bf16_8*)(Psm + l15 * 128 +
                                ((s * 64 + lg * 16) ^ xo_p));
            const __attribute__((address_space(3))) char* a3 = vtr + s * 1024;
            u32x2 r0, r1, r2, r3, r4, r5, r6, r7;
            asm volatile(
                "ds_read_b64_tr_b16 %0, %8 offset:0\n\t"
                "ds_read_b64_tr_b16 %1, %8 offset:128\n\t"
                "ds_read_b64_tr_b16 %2, %8 offset:2048\n\t"
                "ds_read_b64_tr_b16 %3, %8 offset:2176\n\t"
                "ds_read_b64_tr_b16 %4, %8 offset:4096\n\t"
                "ds_read_b64_tr_b16 %5, %8 offset:4224\n\t"
                "ds_read_b64_tr_b16 %6, %8 offset:6144\n\t"
                "ds_read_b64_tr_b16 %7, %8 offset:6272\n\t"
                "s_waitcnt lgkmcnt(0)"
                : "=&v"(r0), "=&v"(r1), "=&v"(r2), "=&v"(r3),
                  "=&v"(r4), "=&v"(r5), "=&v"(r6), "=&v"(r7)
                : "v"(a3));
            union Cv { unsigned u[4]; bf16_8 v; };
            Cv c0; c0.u[0] = r0.x; c0.u[1] = r0.y; c0.u[2] = r1.x; c0.u[3] = r1.y;
            Cv c1; c1.u[0] = r2.x; c1.u[1] = r2.y; c1.u[2] = r3.x; c1.u[3] = r3.y;
            Cv c2; c2.u[0] = r4.x; c2.u[1] = r4.y; c2.u[2] = r5.x; c2.u[3] = r5.y;
            Cv c3; c3.u[0] = r6.x; c3.u[1] = r6.y; c3.u[2] = r7.x; c3.u[3] = r7.y;
            ctx[0] = __builtin_amdgcn_mfma_f32_16x16x32_bf16(c0.v, pf, ctx[0], 0, 0, 0);
            ctx[1] = __builtin_amdgcn_mfma_f32_16x16x32_bf16(c1.v, pf, ctx[1], 0, 0, 0);
            ctx[2] = __builtin_amdgcn_mfma_f32_16x16x32_bf16(c2.v, pf, ctx[2], 0, 0, 0);
            ctx[3] = __builtin_amdgcn_mfma_f32_16x16x32_bf16(c3.v, pf, ctx[3], 0, 0, 0);
        }
    }

    const float inv = 1.f / l_r;
    const size_t qrow = outhead + (size_t)(q0 + l15) * D_;
#pragma unroll
    for (int fd = 0; fd < 4; ++fd) {
        ushort4 o;
        o.x = f2b(ctx[fd][0] * inv);
        o.y = f2b(ctx[fd][1] * inv);
        o.z = f2b(ctx[fd][2] * inv);
        o.w = f2b(ctx[fd][3] * inv);
        *(ushort4*)(ctxb + qrow + fd * 16 + lg * 4) = o;
    }
}

// ---------------------------------------------------------------------------
extern "C" void kernel_launch(void* const* d_in, const int* in_sizes, int n_in,
                              void* d_out, int out_size, void* d_ws, size_t ws_size,
                              hipStream_t stream)
{
    const float* h    = (const float*)d_in[0];
    const float* mask = (const float*)d_in[1];
    const float* Wq   = (const float*)d_in[2];
    const float* bq   = (const float*)d_in[3];
    const float* Wk   = (const float*)d_in[4];
    const float* bk   = (const float*)d_in[5];
    const float* Wv   = (const float*)d_in[6];
    const float* bv   = (const float*)d_in[7];
    const float* Wo   = (const float*)d_in[8];
    const float* bo   = (const float*)d_in[9];
    const float* ln1g = (const float*)d_in[10];
    const float* ln1b = (const float*)d_in[11];
    const float* Wi   = (const float*)d_in[12];
    const float* bi   = (const float*)d_in[13];
    const float* Wout = (const float*)d_in[14];
    const float* bout = (const float*)d_in[15];
    const float* ln2g = (const float*)d_in[16];
    const float* ln2b = (const float*)d_in[17];
    float* out = (float*)d_out;

    char* w = (char*)d_ws;
    const size_t MiB = 1ull << 20;
    // liveness-packed layout, peak 104 MiB:
    u16*   Woutt  = (u16*)(w + 0);             // [0,8)   live to FFN2
    u16*   Wit    = (u16*)(w + 8 * MiB);       // [8,16)  live to FFN1
    u16*   hb     = (u16*)(w + 16 * MiB);      // [16,24) dead after QKV
    u16*   woP0   = (u16*)(w + 16 * MiB);      //   then Wo partial 0 (bf16)
    u16*   ffP1   = (u16*)(w + 16 * MiB);      //   then FFN2 partial 1
    u16*   Wqkvt  = (u16*)(w + 24 * MiB);      // [24,30) dead after QKV
    u16*   ffP2   = (u16*)(w + 24 * MiB);      //   then FFN2 partial 2
    u16*   Wot    = (u16*)(w + 30 * MiB);      // [30,32) dead after Wo-splitk
    u16*   QKVb   = (u16*)(w + 32 * MiB);      // [32,56) dead after attn
    u16*   woP1   = (u16*)(w + 32 * MiB);      //   then Wo partial 1
    u16*   ffP3   = (u16*)(w + 32 * MiB);      //   then FFN2 partial 3
    float* attnF  = (float*)(w + 40 * MiB);    // [40,56) live to ln2
    u16*   attnB  = (u16*)(w + 56 * MiB);      // [56,64) dead after FFN1
    u16*   interB = (u16*)(w + 64 * MiB);      // [64,96) dead after FFN2
    u16*   ctxb   = (u16*)(w + 96 * MiB);      // [96,104) dead after Wo-splitk
    u16*   ffP0   = (u16*)(w + 96 * MiB);      //   then FFN2 partial 0

    const dim3 blk(256);
    PB zp; zp.p[0] = zp.p[1] = zp.p[2] = zp.p[3] = nullptr;

    // fused prep: h -> bf16 + 6 weight transposes, one dispatch
    Prep pp;
    pp.s[0] = Wq;   pp.d[0] = Wqkvt;                 pp.K[0] = D_; pp.N[0] = D_;
    pp.s[1] = Wk;   pp.d[1] = Wqkvt + 1024 * 1024;   pp.K[1] = D_; pp.N[1] = D_;
    pp.s[2] = Wv;   pp.d[2] = Wqkvt + 2 * 1024 * 1024; pp.K[2] = D_; pp.N[2] = D_;
    pp.s[3] = Wo;   pp.d[3] = Wot;                   pp.K[3] = D_; pp.N[3] = D_;
    pp.s[4] = Wi;   pp.d[4] = Wit;                   pp.K[4] = D_; pp.N[4] = I_;
    pp.s[5] = Wout; pp.d[5] = Woutt;                 pp.K[5] = I_; pp.N[5] = D_;
    pp.cin  = (const float4*)h;
    pp.cout = (ushort4*)hb;
    prep_all<<<dim3(128, 32, 7), blk, 0, stream>>>(pp);

    // fused QKV projection: 256^2 8-phase, grid (12,16)
    gemm256<0><<<dim3(12, 16, 1), dim3(512), 0, stream>>>(
        hb, Wqkvt, bq, bk, bv, QKVb, zp, 3072, 1024, 1024);

    // attention: 512 blocks x 512 threads, XCD-chunked swizzle
    attn_mfma<<<dim3(512), dim3(512), 0, stream>>>(
        QKVb, QKVb + 1024, QKVb + 2048, mask, ctxb, 3072);

    // Wo projection, split-K x2 -> bf16 partials; reduce+bias+res(h)+LN1
    PB woP; woP.p[0] = woP0; woP.p[1] = woP1; woP.p[2] = nullptr; woP.p[3] = nullptr;
    gemm_splitk<<<dim3(8, 32, 2), blk, 0, stream>>>(ctxb, Wot, woP, D_, D_, 512);
    ln_reduce<2><<<dim3(M_), blk, 0, stream>>>(woP, bo, h, ln1g, ln1b, attnF, attnB);

    // FFN1: erf-GELU GEMM, 256^2 8-phase, grid (16,16)
    gemm256<1><<<dim3(16, 16, 1), dim3(512), 0, stream>>>(
        attnB, Wit, bi, nullptr, nullptr, interB, zp, 4096, 1024, 1024);

    // FFN2: 256^2 8-phase split-K x4 -> bf16 partials; reduce+bias+res+LN2 -> out
    PB ffP; ffP.p[0] = ffP0; ffP.p[1] = ffP1; ffP.p[2] = ffP2; ffP.p[3] = ffP3;
    gemm256<2><<<dim3(4, 16, 4), dim3(512), 0, stream>>>(
        interB, Woutt, nullptr, nullptr, nullptr, nullptr, ffP, 1024, 4096, 4096);
    ln_reduce<4><<<dim3(M_), blk, 0, stream>>>(ffP, bout, attnF, ln2g, ln2b, out, nullptr);
}